// Round 2
// baseline (7998.184 us; speedup 1.0000x reference)
//
#include <hip/hip_runtime.h>
#include <hip/hip_bf16.h>

#define B_   32
#define N_   207
#define T_   12
#define D_   128
#define H_   8
#define HD_  16
#define L_   4
#define FF_  512
#define PL_  12
#define TOK  (B_*N_*T_)      // 79488
#define ROWS2 (B_*N_)        // 6624
#define SCALE_ 0.25f
#define NEG_  -1e9f

typedef __hip_bfloat16 bf16;

__device__ __forceinline__ float b2f(bf16 x){ return __bfloat162float(x); }
__device__ __forceinline__ bf16  f2b(float x){ return __float2bfloat16(x); }

// ---- diagnostic sentinel: if later kernels never run, absmax ~= 2.0 tells us launches work ----
__global__ void sentinel_k(unsigned int* out32, int nwords){
  int i = blockIdx.x*256 + threadIdx.x;
  if (i < nwords) out32[i] = 0x40004000u;   // two bf16 2.0s (or fp32 ~2.0078)
}

// ---- dtype detection: flag=1 if input bits look like bf16, 0 if fp32 ----
__global__ void detect_k(const void* x, int* flag){
  __shared__ int cnt[256];
  const unsigned short* u = (const unsigned short*)x;
  int ok = 0;
  for (int i = threadIdx.x; i < 4096; i += 256){
    unsigned int bits = ((unsigned int)u[i]) << 16;
    float f = __uint_as_float(bits);
    float a = fabsf(f);
    if (f == 0.0f || (a > 1e-4f && a < 64.0f)) ok++;
  }
  cnt[threadIdx.x] = ok;
  __syncthreads();
  for (int s = 128; s > 0; s >>= 1){
    if (threadIdx.x < s) cnt[threadIdx.x] += cnt[threadIdx.x + s];
    __syncthreads();
  }
  if (threadIdx.x == 0) *flag = (cnt[0] > 3686) ? 1 : 0;   // >90% plausible
}

// ---- convert one tensor (bf16 passthrough or fp32->bf16) into canonical ws region ----
__global__ void cvt_k(const void* src, bf16* dst, int n, const int* flag){
  int i = blockIdx.x*256 + threadIdx.x;
  if (i >= n) return;
  if (*flag) dst[i] = ((const bf16*)src)[i];
  else       dst[i] = f2b(((const float*)src)[i]);
}

// ---- embed: h[tok,d] = x[tok]*Wi[d] + bi[d]  (IN==1) ----
__global__ void embed_k(const bf16* x, const bf16* Wi, const bf16* bi, float* h){
  int i = blockIdx.x*256 + threadIdx.x;
  if (i >= TOK*D_) return;
  int tok = i >> 7, d = i & 127;
  h[i] = b2f(x[tok]) * b2f(Wi[d]) + b2f(bi[d]);
}

// ---- LayerNorm over D=128, one wave per token ----
__global__ void ln_k(const float* h, const bf16* g, const bf16* bta, bf16* out){
  int wave = threadIdx.x >> 6, lane = threadIdx.x & 63;
  int tok = blockIdx.x*4 + wave;
  if (tok >= TOK) return;
  const float* hp = h + (size_t)tok*D_;
  float v0 = hp[lane], v1 = hp[lane+64];
  float s = v0 + v1;
  for (int off = 32; off >= 1; off >>= 1) s += __shfl_xor(s, off, 64);
  float m = s * (1.0f/128.0f);
  float d0 = v0 - m, d1 = v1 - m;
  float vv = d0*d0 + d1*d1;
  for (int off = 32; off >= 1; off >>= 1) vv += __shfl_xor(vv, off, 64);
  float r = rsqrtf(vv*(1.0f/128.0f) + 1e-5f);
  bf16* op = out + (size_t)tok*D_;
  op[lane]    = f2b(d0*r*b2f(g[lane])    + b2f(bta[lane]));
  op[lane+64] = f2b(d1*r*b2f(g[lane+64]) + b2f(bta[lane+64]));
}

// ---- GEMM: out = [relu]( A(MxK) @ W(KxN) + bias ); acc!=0 -> fp32 out += ----
__global__ void gemm_k(const bf16* A, int lda, const bf16* W, const bf16* bias,
                       void* outp, int ldo, int M, int Ncols, int K, int relu, int acc){
  __shared__ float Ast[16*68];
  __shared__ float Ws [16*68];
  int tx = threadIdx.x & 15, ty = threadIdx.x >> 4;
  int rowBase = blockIdx.y * 64, colBase = blockIdx.x * 64;
  float accr[4][4];
  for (int i = 0; i < 4; i++) for (int j = 0; j < 4; j++) accr[i][j] = 0.0f;
  for (int kk = 0; kk < K; kk += 16){
    int kq = threadIdx.x & 15, r0 = threadIdx.x >> 4;
    for (int it = 0; it < 4; it++){
      int r = r0 + it*16, row = rowBase + r;
      float v = 0.0f;
      if (row < M) v = b2f(A[(size_t)row*lda + kk + kq]);
      Ast[kq*68 + r] = v;
    }
    int c = threadIdx.x & 63, w0 = threadIdx.x >> 6;
    for (int it = 0; it < 4; it++){
      int kr = w0 + it*4;
      Ws[kr*68 + c] = b2f(W[(size_t)(kk+kr)*Ncols + colBase + c]);
    }
    __syncthreads();
    for (int k = 0; k < 16; k++){
      float av[4], wv[4];
      for (int i = 0; i < 4; i++) av[i] = Ast[k*68 + ty*4 + i];
      for (int j = 0; j < 4; j++) wv[j] = Ws[k*68 + tx*4 + j];
      for (int i = 0; i < 4; i++)
        for (int j = 0; j < 4; j++) accr[i][j] += av[i]*wv[j];
    }
    __syncthreads();
  }
  for (int i = 0; i < 4; i++){
    int row = rowBase + ty*4 + i;
    if (row >= M) continue;
    for (int j = 0; j < 4; j++){
      int col = colBase + tx*4 + j;
      float v = accr[i][j];
      if (bias) v += b2f(bias[col]);
      if (relu) v = fmaxf(v, 0.0f);
      if (acc) ((float*)outp)[(size_t)row*ldo + col] += v;
      else     ((bf16*)outp)[(size_t)row*ldo + col] = f2b(v);
    }
  }
}

// ---- spatial attention: one block per (b,t,head) over N=207 nodes ----
__global__ void sattn_k(const bf16* qb, const bf16* kb, const bf16* vb,
                        const int* adj, bf16* ob){
  int bid = blockIdx.x;
  int b = bid / (T_*H_); int rem = bid % (T_*H_); int t = rem / H_; int hh = rem % H_;
  __shared__ float qs[N_*17];
  __shared__ float ks[N_*17];
  __shared__ float vs[N_*17];
  __shared__ float aw[4*208];
  size_t base = ((size_t)(b*N_)*T_ + t)*D_ + hh*HD_;
  for (int idx = threadIdx.x; idx < N_*HD_; idx += 256){
    int n = idx >> 4, d = idx & 15;
    size_t gidx = base + (size_t)n*T_*D_ + d;
    qs[n*17+d] = b2f(qb[gidx]);
    ks[n*17+d] = b2f(kb[gidx]);
    vs[n*17+d] = b2f(vb[gidx]);
  }
  __syncthreads();
  int wave = threadIdx.x >> 6, lane = threadIdx.x & 63;
  for (int n = wave; n < N_; n += 4){
    const int* arow = adj + n*N_;
    float sv[4]; float smax = -3.4e38f;
    for (int j = 0; j < 4; j++){
      int m = lane + 64*j;
      float sres = -3.4e38f;
      if (m < N_){
        float a = 0.0f;
        for (int d = 0; d < 16; d++) a += ks[m*17+d]*qs[n*17+d];
        sres = a * SCALE_;
        if (arow[m] == 0) sres = NEG_;
      }
      sv[j] = sres;
      smax = fmaxf(smax, sres);
    }
    for (int off = 32; off >= 1; off >>= 1) smax = fmaxf(smax, __shfl_xor(smax, off, 64));
    float ssum = 0.0f;
    for (int j = 0; j < 4; j++){
      int m = lane + 64*j;
      float p = (m < N_) ? __expf(sv[j]-smax) : 0.0f;
      sv[j] = p; ssum += p;
    }
    for (int off = 32; off >= 1; off >>= 1) ssum += __shfl_xor(ssum, off, 64);
    float inv = 1.0f/ssum;
    for (int j = 0; j < 4; j++){ int m = lane+64*j; if (m < N_) aw[wave*208+m] = sv[j]*inv; }
    __threadfence_block();   // same-wave LDS write->read ordering (compiler fence)
    int mc = lane >> 4, d = lane & 15;
    float acc = 0.0f;
    for (int m = mc; m < N_; m += 4) acc += aw[wave*208+m]*vs[m*17+d];
    acc += __shfl_xor(acc, 16, 64);
    acc += __shfl_xor(acc, 32, 64);
    if (lane < 16) ob[base + (size_t)n*T_*D_ + d] = f2b(acc);
    __threadfence_block();   // WAR ordering for aw across n-iterations
  }
}

// ---- temporal attention: one block (128 thr) per (b,n); qkv rows of 384 ----
__global__ void tattn_k(const bf16* qkv, bf16* ob){
  int bid = blockIdx.x; int b = bid / N_, n = bid % N_;
  __shared__ float qs[T_*D_];
  __shared__ float ks[T_*D_];
  __shared__ float vs[T_*D_];
  size_t rowb = ((size_t)(b*N_+n)*T_)*384;
  for (int idx = threadIdx.x; idx < T_*384; idx += 128){
    int tt = idx / 384, c = idx - tt*384;
    float v = b2f(qkv[rowb + (size_t)tt*384 + c]);
    if (c < 128)      qs[tt*128 + c]       = v;
    else if (c < 256) ks[tt*128 + (c-128)] = v;
    else              vs[tt*128 + (c-256)] = v;
  }
  __syncthreads();
  int p = threadIdx.x;
  if (p < H_*T_){
    int hh = p / T_, t = p - hh*T_;
    float qreg[16];
    for (int d = 0; d < 16; d++) qreg[d] = qs[t*128 + hh*16 + d];
    float sc[12]; float mx = -3.4e38f;
    for (int s = 0; s < 12; s++){
      float a = 0.0f;
      for (int d = 0; d < 16; d++) a += qreg[d]*ks[s*128 + hh*16 + d];
      a = (s <= t) ? a*SCALE_ : -3.4e38f;
      sc[s] = a; mx = fmaxf(mx, a);
    }
    float ssum = 0.0f;
    for (int s = 0; s < 12; s++){
      float e = (s <= t) ? __expf(sc[s]-mx) : 0.0f;
      sc[s] = e; ssum += e;
    }
    float inv = 1.0f/ssum;
    size_t obase = ((size_t)(b*N_+n)*T_ + t)*D_ + hh*16;
    for (int d = 0; d < 16; d++){
      float acc = 0.0f;
      for (int s = 0; s < 12; s++) acc += sc[s]*vs[s*128 + hh*16 + d];
      ob[obase + d] = f2b(acc*inv);
    }
  }
}

__global__ void gather_k(const float* h, bf16* hlb){
  int i = blockIdx.x*256 + threadIdx.x;
  if (i >= ROWS2*D_) return;
  int r = i >> 7, d = i & 127;
  hlb[i] = f2b(h[((size_t)r*T_ + (T_-1))*D_ + d]);
}

// ---- final 128->12 projection; output dtype per detected flag ----
__global__ void head3_k(const bf16* z2, const bf16* P3, const bf16* Pb3,
                        void* out, int out_n, const int* flag){
  int i = blockIdx.x*256 + threadIdx.x;
  if (i >= out_n) return;
  int r = i / PL_, j = i - r*PL_;
  float acc = b2f(Pb3[j]);
  for (int d = 0; d < 128; d++) acc += b2f(z2[(size_t)r*128 + d]) * b2f(P3[d*PL_ + j]);
  if (*flag) ((bf16*)out)[i] = f2b(acc);
  else       ((float*)out)[i] = acc;
}

extern "C" void kernel_launch(void* const* d_in, const int* in_sizes, int n_in,
                              void* d_out, int out_size, void* d_ws, size_t ws_size,
                              hipStream_t stream){
  // ---- ws layout ----
  size_t HB = (size_t)TOK*D_*4;      // fp32 residual h
  size_t XB = (size_t)TOK*D_*2;      // bf16 xn
  size_t RB = (size_t)TOK*D_*8;      // bf16 q|k|v|o  (aliases ff-hidden / qkv / head scratch)
  float* h    = (float*)d_ws;
  bf16*  xnb  = (bf16*)((char*)d_ws + HB);
  bf16*  reg_ = (bf16*)((char*)d_ws + HB + XB);
  bf16*  cvt  = (bf16*)((char*)d_ws + HB + XB + RB);
  // converted-tensor table (all float inputs, in d_in order, skipping adj at idx 1)
  const int FIDX[34] = {0,2,3,4,5,6,7,8,9,10,11,12,13,14,15,16,17,18,19,20,
                        21,22,23,24,25,26,27,28,29,30,31,32,33,34};
  bf16* cp[34];
  size_t off = 0;
  for (int i = 0; i < 34; i++){ cp[i] = cvt + off; off += (size_t)in_sizes[FIDX[i]]; }
  int* flag = (int*)((char*)d_ws + HB + XB + RB + ((off*2 + 255) & ~(size_t)255));

  const bf16 *x_c=cp[0], *Wi_c=cp[1], *bi_c=cp[2], *Wq_c=cp[3], *Wk_c=cp[4], *Wv_c=cp[5],
             *Wo_c=cp[6], *bo_c=cp[7], *sW1_c=cp[8], *sB1_c=cp[9], *sW2_c=cp[10], *sB2_c=cp[11],
             *sg1_c=cp[12], *sh1_c=cp[13], *sg2_c=cp[14], *sh2_c=cp[15], *Win_c=cp[16], *Bin_c=cp[17],
             *Wout_c=cp[18], *Bout_c=cp[19], *tW1_c=cp[20], *tB1_c=cp[21], *tW2_c=cp[22], *tB2_c=cp[23],
             *tg1_c=cp[24], *th1_c=cp[25], *tg2_c=cp[26], *th2_c=cp[27], *P1_c=cp[28], *Pb1_c=cp[29],
             *P2_c=cp[30], *Pb2_c=cp[31], *P3_c=cp[32], *Pb3_c=cp[33];
  const int* adj = (const int*)d_in[1];

  bf16* qb   = reg_;
  bf16* kb   = reg_ + (size_t)TOK*D_;
  bf16* vb   = reg_ + (size_t)2*TOK*D_;
  bf16* ob   = reg_ + (size_t)3*TOK*D_;
  bf16* ffb  = reg_;    // TOK*FF, only live during FFN
  bf16* qkvb = reg_;    // TOK*384 packed; ob untouched

  // 0) sentinel (diagnostic; fully overwritten by head3_k at the end)
  int nwords = out_size/2;
  sentinel_k<<<(nwords+255)/256, 256, 0, stream>>>((unsigned int*)d_out, nwords);
  // 1) dtype detect + convert everything to canonical bf16
  detect_k<<<1, 256, 0, stream>>>(d_in[0], flag);
  for (int i = 0; i < 34; i++){
    int n = in_sizes[FIDX[i]];
    cvt_k<<<(n+255)/256, 256, 0, stream>>>(d_in[FIDX[i]], cp[i], n, flag);
  }
  // 2) embed
  embed_k<<<(TOK*D_)/256, 256, 0, stream>>>(x_c, Wi_c, bi_c, h);

  const dim3 gP (D_/64,  TOK/64);
  const dim3 gF1(FF_/64, TOK/64);
  const dim3 gQKV(384/64, TOK/64);

  for (int l = 0; l < L_; l++){
    // spatial attention
    ln_k<<<TOK/4, 256, 0, stream>>>(h, sg1_c + l*D_, sh1_c + l*D_, xnb);
    gemm_k<<<gP, 256, 0, stream>>>(xnb, D_, Wq_c + (size_t)l*D_*D_, nullptr, qb, D_, TOK, D_, D_, 0, 0);
    gemm_k<<<gP, 256, 0, stream>>>(xnb, D_, Wk_c + (size_t)l*D_*D_, nullptr, kb, D_, TOK, D_, D_, 0, 0);
    gemm_k<<<gP, 256, 0, stream>>>(xnb, D_, Wv_c + (size_t)l*D_*D_, nullptr, vb, D_, TOK, D_, D_, 0, 0);
    sattn_k<<<B_*T_*H_, 256, 0, stream>>>(qb, kb, vb, adj, ob);
    gemm_k<<<gP, 256, 0, stream>>>(ob, D_, Wo_c + (size_t)l*D_*D_, bo_c + l*D_, h, D_, TOK, D_, D_, 0, 1);
    // FFN 1
    ln_k<<<TOK/4, 256, 0, stream>>>(h, sg2_c + l*D_, sh2_c + l*D_, xnb);
    gemm_k<<<gF1, 256, 0, stream>>>(xnb, D_, sW1_c + (size_t)l*D_*FF_, sB1_c + l*FF_, ffb, FF_, TOK, FF_, D_, 1, 0);
    gemm_k<<<gP , 256, 0, stream>>>(ffb, FF_, sW2_c + (size_t)l*FF_*D_, sB2_c + l*D_, h, D_, TOK, D_, FF_, 0, 1);
    // temporal attention
    ln_k<<<TOK/4, 256, 0, stream>>>(h, tg1_c + l*D_, th1_c + l*D_, xnb);
    gemm_k<<<gQKV, 256, 0, stream>>>(xnb, D_, Win_c + (size_t)l*D_*384, Bin_c + l*384, qkvb, 384, TOK, 384, D_, 0, 0);
    tattn_k<<<B_*N_, 128, 0, stream>>>(qkvb, ob);
    gemm_k<<<gP, 256, 0, stream>>>(ob, D_, Wout_c + (size_t)l*D_*D_, Bout_c + l*D_, h, D_, TOK, D_, D_, 0, 1);
    // FFN 2
    ln_k<<<TOK/4, 256, 0, stream>>>(h, tg2_c + l*D_, th2_c + l*D_, xnb);
    gemm_k<<<gF1, 256, 0, stream>>>(xnb, D_, tW1_c + (size_t)l*D_*FF_, tB1_c + l*FF_, ffb, FF_, TOK, FF_, D_, 1, 0);
    gemm_k<<<gP , 256, 0, stream>>>(ffb, FF_, tW2_c + (size_t)l*FF_*D_, tB2_c + l*D_, h, D_, TOK, D_, FF_, 0, 1);
  }

  // head
  bf16* hlb = reg_;
  bf16* z1  = reg_ + (size_t)ROWS2*128;
  bf16* z2  = z1   + (size_t)ROWS2*256;
  gather_k<<<(ROWS2*D_)/256, 256, 0, stream>>>(h, hlb);
  gemm_k<<<dim3(256/64, (ROWS2+63)/64), 256, 0, stream>>>(hlb, 128, P1_c, Pb1_c, z1, 256, ROWS2, 256, 128, 1, 0);
  gemm_k<<<dim3(128/64, (ROWS2+63)/64), 256, 0, stream>>>(z1, 256, P2_c, Pb2_c, z2, 128, ROWS2, 128, 256, 1, 0);
  head3_k<<<(out_size+255)/256, 256, 0, stream>>>(z2, P3_c, Pb3_c, d_out, out_size, flag);
}

// Round 4
// 2981.542 us; speedup vs baseline: 2.6826x; 2.6826x over previous
//
#include <hip/hip_runtime.h>
#include <hip/hip_bf16.h>

#define B_   32
#define N_   207
#define T_   12
#define D_   128
#define H_   8
#define HD_  16
#define L_   4
#define FF_  512
#define PL_  12
#define TOK  (B_*N_*T_)      // 79488 = 621*128
#define ROWS2 (B_*N_)        // 6624
#define SCALE_ 0.25f
#define NEG_  -1e9f
#define NPAD 208             // 13*16
#define KQ  40               // K LDS row stride (bf16): k 0..15 data, 16..31 zero, 32..39 pad
#define KV  232              // Vt LDS row stride (bf16): kv 0..206 data, 207..223 zero, pad
#define KVF 236              // P LDS row stride (fp32): 0..206 data, 207..223 zero, pad

typedef __hip_bfloat16 bf16;
typedef unsigned int u32;
typedef __attribute__((ext_vector_type(4))) unsigned int u32x4;
typedef __attribute__((ext_vector_type(8))) short bf16x8;   // 8 bf16 = 4 VGPRs (MFMA A/B frag)
typedef __attribute__((ext_vector_type(4))) float f32x4;    // MFMA C/D frag

__device__ __forceinline__ float b2f(bf16 x){ return __bfloat162float(x); }
__device__ __forceinline__ bf16  f2b(float x){ return __float2bfloat16(x); }
__device__ __forceinline__ short bbits(bf16 x){ union{bf16 b; short s;} c; c.b = x; return c.s; }

// ---- dtype detection: flag=1 if input bits look like bf16, 0 if fp32 ----
__global__ void detect_k(const void* x, int* flag){
  __shared__ int cnt[256];
  const unsigned short* u = (const unsigned short*)x;
  int ok = 0;
  for (int i = threadIdx.x; i < 4096; i += 256){
    unsigned int bits = ((unsigned int)u[i]) << 16;
    float f = __uint_as_float(bits);
    float a = fabsf(f);
    if (f == 0.0f || (a > 1e-4f && a < 64.0f)) ok++;
  }
  cnt[threadIdx.x] = ok;
  __syncthreads();
  for (int s = 128; s > 0; s >>= 1){
    if (threadIdx.x < s) cnt[threadIdx.x] += cnt[threadIdx.x + s];
    __syncthreads();
  }
  if (threadIdx.x == 0) *flag = (cnt[0] > 3686) ? 1 : 0;
}

// ---- flat convert ----
__global__ void cvt_k(const void* src, bf16* dst, int n, const int* flag){
  int i = blockIdx.x*256 + threadIdx.x;
  if (i >= n) return;
  if (*flag) dst[i] = ((const bf16*)src)[i];
  else       dst[i] = f2b(((const float*)src)[i]);
}

// ---- transpose convert: src[l][k][n] -> dst[l*Lstr + (rowOff+n)*K + k] ----
__global__ void cvt_t_k(const void* src, bf16* dst, int Lr, int K, int Nc,
                        int Lstr, int rowOff, const int* flag){
  int i = blockIdx.x*256 + threadIdx.x;
  int tot = Lr*K*Nc;
  if (i >= tot) return;
  int l = i / (K*Nc); int rm = i - l*(K*Nc); int k = rm / Nc; int n = rm - k*Nc;
  float v = (*flag) ? b2f(((const bf16*)src)[i]) : ((const float*)src)[i];
  dst[(size_t)l*Lstr + (size_t)(rowOff+n)*K + k] = f2b(v);
}

// ---- pack adjacency to bitmask: out[208][8] u32, bit m of row n = (adj[n][m]!=0) ----
__global__ void abits_k(const int* adj, u32* out){
  int i = blockIdx.x*256 + threadIdx.x;
  if (i >= NPAD*8) return;
  int n = i >> 3, wj = i & 7;
  u32 v = 0;
  if (n < N_ && wj < 7){
    for (int bit = 0; bit < 32; bit++){
      int m = wj*32 + bit;
      if (m < N_ && adj[n*N_ + m] != 0) v |= (1u << bit);
    }
  }
  out[i] = v;
}

// ---- embed: h[tok,d] = x[tok]*Wi[d] + bi[d]  (IN==1) ----
__global__ void embed_k(const bf16* x, const bf16* Wi, const bf16* bi, float* h){
  int i = blockIdx.x*256 + threadIdx.x;
  if (i >= TOK*D_) return;
  int tok = i >> 7, d = i & 127;
  h[i] = b2f(x[tok]) * b2f(Wi[d]) + b2f(bi[d]);
}

// ---- LayerNorm over D=128, one wave per token ----
__global__ void ln_k(const float* h, const bf16* g, const bf16* bta, bf16* out){
  int wave = threadIdx.x >> 6, lane = threadIdx.x & 63;
  int tok = blockIdx.x*4 + wave;
  if (tok >= TOK) return;
  const float* hp = h + (size_t)tok*D_;
  float v0 = hp[lane], v1 = hp[lane+64];
  float s = v0 + v1;
  for (int off = 32; off >= 1; off >>= 1) s += __shfl_xor(s, off, 64);
  float m = s * (1.0f/128.0f);
  float d0 = v0 - m, d1 = v1 - m;
  float vv = d0*d0 + d1*d1;
  for (int off = 32; off >= 1; off >>= 1) vv += __shfl_xor(vv, off, 64);
  float r = rsqrtf(vv*(1.0f/128.0f) + 1e-5f);
  bf16* op = out + (size_t)tok*D_;
  op[lane]    = f2b(d0*r*b2f(g[lane])    + b2f(bta[lane]));
  op[lane+64] = f2b(d1*r*b2f(g[lane+64]) + b2f(bta[lane+64]));
}

// ---- MFMA GEMM: C[M,N] = A[M,K] * Wt[N,K]^T (+bias,relu,acc-into-fp32) ----
// 128x128 tile, BK=32, 256 threads (4 waves, 2x2 of 64x64), 16x16x32 bf16 MFMA.
__global__ __launch_bounds__(256) void mgemm_k(const bf16* __restrict__ A,
    const bf16* __restrict__ Wt, const bf16* __restrict__ bias,
    void* __restrict__ outp, int ldo, int Ktot, int relu, int acc){
  __shared__ bf16 As[128*32];
  __shared__ bf16 Bs[128*32];
  int tid = threadIdx.x;
  int rowBase = blockIdx.y * 128, colBase = blockIdx.x * 128;
  int w = tid >> 6, lane = tid & 63, quad = lane >> 4, cl = lane & 15;
  int waveM = w >> 1, waveN = w & 1;
  f32x4 accr[4][4];
  #pragma unroll
  for (int i = 0; i < 4; i++)
    #pragma unroll
    for (int j = 0; j < 4; j++) accr[i][j] = (f32x4){0.f,0.f,0.f,0.f};
  int lr = tid >> 2, kc = tid & 3;
  const bf16* Ap = A  + (size_t)(rowBase + lr)*Ktot + kc*8;
  const bf16* Bp = Wt + (size_t)(colBase + lr)*Ktot + kc*8;
  bf16* AsW = As + lr*32 + kc*8;
  bf16* BsW = Bs + lr*32 + kc*8;
  for (int kk = 0; kk < Ktot; kk += 32){
    u32x4 a0 = *(const u32x4*)(Ap + kk);
    u32x4 a1 = *(const u32x4*)(Ap + (size_t)64*Ktot + kk);
    u32x4 b0 = *(const u32x4*)(Bp + kk);
    u32x4 b1 = *(const u32x4*)(Bp + (size_t)64*Ktot + kk);
    __syncthreads();
    *(u32x4*)AsW = a0; *(u32x4*)(AsW + 64*32) = a1;
    *(u32x4*)BsW = b0; *(u32x4*)(BsW + 64*32) = b1;
    __syncthreads();
    bf16x8 af[4], bfr[4];
    #pragma unroll
    for (int mi = 0; mi < 4; mi++)
      af[mi] = *(const bf16x8*)(As + (waveM*64 + mi*16 + cl)*32 + quad*8);
    #pragma unroll
    for (int nj = 0; nj < 4; nj++)
      bfr[nj] = *(const bf16x8*)(Bs + (waveN*64 + nj*16 + cl)*32 + quad*8);
    #pragma unroll
    for (int mi = 0; mi < 4; mi++)
      #pragma unroll
      for (int nj = 0; nj < 4; nj++)
        accr[mi][nj] = __builtin_amdgcn_mfma_f32_16x16x32_bf16(af[mi], bfr[nj], accr[mi][nj], 0,0,0);
  }
  float bv[4];
  #pragma unroll
  for (int nj = 0; nj < 4; nj++)
    bv[nj] = bias ? b2f(bias[colBase + waveN*64 + nj*16 + cl]) : 0.0f;
  #pragma unroll
  for (int mi = 0; mi < 4; mi++){
    int row0 = rowBase + waveM*64 + mi*16 + quad*4;
    #pragma unroll
    for (int nj = 0; nj < 4; nj++){
      int col = colBase + waveN*64 + nj*16 + cl;
      #pragma unroll
      for (int r = 0; r < 4; r++){
        float v = accr[mi][nj][r] + bv[nj];
        if (relu) v = fmaxf(v, 0.0f);
        if (acc) ((float*)outp)[(size_t)(row0+r)*ldo + col] += v;
        else     ((bf16*)outp)[(size_t)(row0+r)*ldo + col] = f2b(v);
      }
    }
  }
}

// ---- MFMA spatial attention: one block per (b,t,h); qkv packed [TOK][384] ----
// P kept in fp32 LDS; PV uses hi/lo bf16 split (2 MFMAs) for ~fp32 precision.
__global__ __launch_bounds__(256) void sattn_k(const bf16* __restrict__ qkv,
    const u32* __restrict__ abg, bf16* __restrict__ ob){
  __shared__ bf16  Ks[NPAD*KQ];
  __shared__ bf16  Vt[16*KV];
  __shared__ float Psf[4*16*KVF];
  __shared__ u32   abs_[NPAD*8];
  int tid = threadIdx.x;
  int bid = blockIdx.x;
  int b = bid / (T_*H_); int rem = bid % (T_*H_); int t = rem / H_; int hh = rem % H_;
  // zero-fill
  for (int i = tid; i < NPAD*KQ/2; i += 256) ((u32*)Ks)[i] = 0;
  for (int i = tid; i < 16*KV/2;   i += 256) ((u32*)Vt)[i] = 0;
  for (int i = tid; i < 4*16*KVF;  i += 256) Psf[i] = 0.0f;
  __syncthreads();
  // stage K, V^T, adjacency bits
  for (int i = tid; i < N_*16; i += 256){
    int n = i >> 4, d = i & 15;
    size_t rowb = ((size_t)((b*N_ + n)*T_ + t))*384 + hh*HD_;
    Ks[n*KQ + d] = qkv[rowb + 128 + d];
    Vt[d*KV + n] = qkv[rowb + 256 + d];
  }
  for (int i = tid; i < NPAD*8; i += 256) abs_[i] = abg[i];
  __syncthreads();

  int w = tid >> 6, lane = tid & 63, quad = lane >> 4, cl = lane & 15;
  int nstripes = (w == 0) ? 4 : 3;
  for (int si = 0; si < nstripes; si++){
    int mi = w + si*4;          // 0..12
    // ---- Q fragment direct from global (no reuse across stripes) ----
    bf16x8 aq = (bf16x8){0,0,0,0,0,0,0,0};
    {
      int n = mi*16 + cl; if (n > N_-1) n = N_-1;   // clamp pad row (row 207 output never stored)
      size_t rowb = ((size_t)((b*N_ + n)*T_ + t))*384 + hh*HD_;
      if (quad < 2) aq = *(const bf16x8*)(qkv + rowb + quad*8);
    }
    // ---- QK^T: S stripe [16 x 208] in registers ----
    f32x4 s[13];
    #pragma unroll
    for (int nj = 0; nj < 13; nj++){
      bf16x8 bk = *(const bf16x8*)(Ks + (nj*16 + cl)*KQ + quad*8);
      f32x4 z = {0.f,0.f,0.f,0.f};
      s[nj] = __builtin_amdgcn_mfma_f32_16x16x32_bf16(aq, bk, z, 0,0,0);
    }
    // ---- mask + softmax per row; write fp32 P ----
    int row0 = mi*16 + quad*4;
    float* Pw = Psf + w*16*KVF;
    #pragma unroll
    for (int r = 0; r < 4; r++){
      const u32* ab = abs_ + (row0 + r)*8;
      float mx = -3.4e38f;
      #pragma unroll
      for (int nj = 0; nj < 13; nj++){
        int cg = nj*16 + cl;
        float v = s[nj][r] * SCALE_;
        if (cg > 206) v = -3.4e38f;
        else if (!((ab[cg >> 5] >> (cg & 31)) & 1)) v = NEG_;
        s[nj][r] = v;
        mx = fmaxf(mx, v);
      }
      for (int off = 1; off < 16; off <<= 1) mx = fmaxf(mx, __shfl_xor(mx, off, 64));
      float sum = 0.0f;
      #pragma unroll
      for (int nj = 0; nj < 13; nj++){
        float e = __expf(s[nj][r] - mx);
        s[nj][r] = e; sum += e;
      }
      for (int off = 1; off < 16; off <<= 1) sum += __shfl_xor(sum, off, 64);
      float inv = 1.0f/sum;
      float* Pr = Pw + (quad*4 + r)*KVF;
      #pragma unroll
      for (int nj = 0; nj < 13; nj++) Pr[nj*16 + cl] = s[nj][r]*inv;
    }
    __threadfence_block();   // order P writes before same-wave PV reads
    // ---- PV: O stripe [16 x 16], hi/lo split for fp32-class P precision ----
    f32x4 o = {0.f,0.f,0.f,0.f};
    const float* Prow = Pw + cl*KVF;
    #pragma unroll
    for (int kt = 0; kt < 7; kt++){
      union { bf16x8 v; short s[8]; } hi, lo;
      const float* pp = Prow + kt*32 + quad*8;
      #pragma unroll
      for (int j = 0; j < 8; j++){
        float p = pp[j];
        bf16 h1 = f2b(p);
        hi.s[j] = bbits(h1);
        lo.s[j] = bbits(f2b(p - b2f(h1)));
      }
      bf16x8 bv = *(const bf16x8*)(Vt + cl*KV + kt*32 + quad*8);
      o = __builtin_amdgcn_mfma_f32_16x16x32_bf16(hi.v, bv, o, 0,0,0);
      o = __builtin_amdgcn_mfma_f32_16x16x32_bf16(lo.v, bv, o, 0,0,0);
    }
    #pragma unroll
    for (int r = 0; r < 4; r++){
      int rg = row0 + r;
      if (rg < N_)
        ob[((size_t)((b*N_ + rg)*T_ + t))*D_ + hh*HD_ + cl] = f2b(o[r]);
    }
    __threadfence_block();   // order PV reads before next stripe's P writes
  }
}

// ---- temporal attention: one block (128 thr) per (b,n); qkv rows of 384 ----
__global__ void tattn_k(const bf16* qkv, bf16* ob){
  int bid = blockIdx.x; int b = bid / N_, n = bid % N_;
  __shared__ float qs[T_*D_];
  __shared__ float ks[T_*D_];
  __shared__ float vs[T_*D_];
  size_t rowb = ((size_t)(b*N_+n)*T_)*384;
  for (int idx = threadIdx.x; idx < T_*384; idx += 128){
    int tt = idx / 384, c = idx - tt*384;
    float v = b2f(qkv[rowb + (size_t)tt*384 + c]);
    if (c < 128)      qs[tt*128 + c]       = v;
    else if (c < 256) ks[tt*128 + (c-128)] = v;
    else              vs[tt*128 + (c-256)] = v;
  }
  __syncthreads();
  int p = threadIdx.x;
  if (p < H_*T_){
    int hh = p / T_, t = p - hh*T_;
    float qreg[16];
    for (int d = 0; d < 16; d++) qreg[d] = qs[t*128 + hh*16 + d];
    float sc[12]; float mx = -3.4e38f;
    for (int s = 0; s < 12; s++){
      float a = 0.0f;
      for (int d = 0; d < 16; d++) a += qreg[d]*ks[s*128 + hh*16 + d];
      a = (s <= t) ? a*SCALE_ : -3.4e38f;
      sc[s] = a; mx = fmaxf(mx, a);
    }
    float ssum = 0.0f;
    for (int s = 0; s < 12; s++){
      float e = (s <= t) ? __expf(sc[s]-mx) : 0.0f;
      sc[s] = e; ssum += e;
    }
    float inv = 1.0f/ssum;
    size_t obase = ((size_t)(b*N_+n)*T_ + t)*D_ + hh*16;
    for (int d = 0; d < 16; d++){
      float acc = 0.0f;
      for (int s = 0; s < 12; s++) acc += sc[s]*vs[s*128 + hh*16 + d];
      ob[obase + d] = f2b(acc*inv);
    }
  }
}

// ---- VALU GEMM kept for the small head GEMMs ----
__global__ void gemm_k(const bf16* A, int lda, const bf16* W, const bf16* bias,
                       void* outp, int ldo, int M, int Ncols, int K, int relu, int acc){
  __shared__ float Ast[16*68];
  __shared__ float Ws [16*68];
  int tx = threadIdx.x & 15, ty = threadIdx.x >> 4;
  int rowBase = blockIdx.y * 64, colBase = blockIdx.x * 64;
  float accr[4][4];
  for (int i = 0; i < 4; i++) for (int j = 0; j < 4; j++) accr[i][j] = 0.0f;
  for (int kk = 0; kk < K; kk += 16){
    int kq = threadIdx.x & 15, r0 = threadIdx.x >> 4;
    for (int it = 0; it < 4; it++){
      int r = r0 + it*16, row = rowBase + r;
      float v = 0.0f;
      if (row < M) v = b2f(A[(size_t)row*lda + kk + kq]);
      Ast[kq*68 + r] = v;
    }
    int c = threadIdx.x & 63, w0 = threadIdx.x >> 6;
    for (int it = 0; it < 4; it++){
      int kr = w0 + it*4;
      Ws[kr*68 + c] = b2f(W[(size_t)(kk+kr)*Ncols + colBase + c]);
    }
    __syncthreads();
    for (int k = 0; k < 16; k++){
      float av[4], wv[4];
      for (int i = 0; i < 4; i++) av[i] = Ast[k*68 + ty*4 + i];
      for (int j = 0; j < 4; j++) wv[j] = Ws[k*68 + tx*4 + j];
      for (int i = 0; i < 4; i++)
        for (int j = 0; j < 4; j++) accr[i][j] += av[i]*wv[j];
    }
    __syncthreads();
  }
  for (int i = 0; i < 4; i++){
    int row = rowBase + ty*4 + i;
    if (row >= M) continue;
    for (int j = 0; j < 4; j++){
      int col = colBase + tx*4 + j;
      float v = accr[i][j];
      if (bias) v += b2f(bias[col]);
      if (relu) v = fmaxf(v, 0.0f);
      if (acc) ((float*)outp)[(size_t)row*ldo + col] += v;
      else     ((bf16*)outp)[(size_t)row*ldo + col] = f2b(v);
    }
  }
}

__global__ void gather_k(const float* h, bf16* hlb){
  int i = blockIdx.x*256 + threadIdx.x;
  if (i >= ROWS2*D_) return;
  int r = i >> 7, d = i & 127;
  hlb[i] = f2b(h[((size_t)r*T_ + (T_-1))*D_ + d]);
}

__global__ void head3_k(const bf16* z2, const bf16* P3, const bf16* Pb3,
                        void* out, int out_n, const int* flag){
  int i = blockIdx.x*256 + threadIdx.x;
  if (i >= out_n) return;
  int r = i / PL_, j = i - r*PL_;
  float acc = b2f(Pb3[j]);
  for (int d = 0; d < 128; d++) acc += b2f(z2[(size_t)r*128 + d]) * b2f(P3[d*PL_ + j]);
  if (*flag) ((bf16*)out)[i] = f2b(acc);
  else       ((float*)out)[i] = acc;
}

extern "C" void kernel_launch(void* const* d_in, const int* in_sizes, int n_in,
                              void* d_out, int out_size, void* d_ws, size_t ws_size,
                              hipStream_t stream){
  // ws layout
  size_t HB = (size_t)TOK*D_*4;      // fp32 residual h
  size_t XB = (size_t)TOK*D_*2;      // bf16 xn
  size_t RB = (size_t)TOK*D_*8;      // bf16 qkv(384)+ob(128), aliases ffb(512)
  float* h    = (float*)d_ws;
  bf16*  xnb  = (bf16*)((char*)d_ws + HB);
  bf16*  reg_ = (bf16*)((char*)d_ws + HB + XB);
  bf16*  cvt  = (bf16*)((char*)d_ws + HB + XB + RB);
  const int FIDX[34] = {0,2,3,4,5,6,7,8,9,10,11,12,13,14,15,16,17,18,19,20,
                        21,22,23,24,25,26,27,28,29,30,31,32,33,34};
  bf16* cp[34];
  size_t off = 0;
  for (int i = 0; i < 34; i++){ cp[i] = cvt + off; off += (size_t)in_sizes[FIDX[i]]; }
  char* tail   = (char*)d_ws + HB + XB + RB + ((off*2 + 255) & ~(size_t)255);
  u32*  abg    = (u32*)tail;                        // 208*8 u32
  bf16* qkvw   = (bf16*)(tail + 8192);              // packed QKV weights [L][384][128]
  int*  flag   = (int*)(tail + 8192 + (size_t)L_*384*128*2);

  const bf16 *x_c=cp[0], *Wi_c=cp[1], *bi_c=cp[2],
             *Wo_t=cp[6], *bo_c=cp[7], *sW1_t=cp[8], *sB1_c=cp[9], *sW2_t=cp[10], *sB2_c=cp[11],
             *sg1_c=cp[12], *sh1_c=cp[13], *sg2_c=cp[14], *sh2_c=cp[15], *Win_t=cp[16], *Bin_c=cp[17],
             *Wout_t=cp[18], *Bout_c=cp[19], *tW1_t=cp[20], *tB1_c=cp[21], *tW2_t=cp[22], *tB2_c=cp[23],
             *tg1_c=cp[24], *th1_c=cp[25], *tg2_c=cp[26], *th2_c=cp[27], *P1_c=cp[28], *Pb1_c=cp[29],
             *P2_c=cp[30], *Pb2_c=cp[31], *P3_c=cp[32], *Pb3_c=cp[33];
  const int* adj = (const int*)d_in[1];

  bf16* qkvb = reg_;                       // [TOK][384]
  bf16* ob   = reg_ + (size_t)TOK*384;     // [TOK][128]
  bf16* ffb  = reg_;                       // [TOK][512] (aliases qkvb+ob, disjoint lifetime)

  detect_k<<<1, 256, 0, stream>>>(d_in[0], flag);
  const int FLAT[24] = {0,1,2,7,9,11,12,13,14,15,17,19,21,23,24,25,26,27,28,29,30,31,32,33};
  for (int ii = 0; ii < 24; ii++){
    int ci = FLAT[ii]; int n = in_sizes[FIDX[ci]];
    cvt_k<<<(n+255)/256, 256, 0, stream>>>(d_in[FIDX[ci]], cp[ci], n, flag);
  }
  // packed QKV weight transpose: Wq->rows 0..127, Wk->128..255, Wv->256..383
  {
    int n = L_*D_*D_;
    cvt_t_k<<<(n+255)/256, 256, 0, stream>>>(d_in[4], qkvw, L_, D_, D_, 384*128, 0,   flag);
    cvt_t_k<<<(n+255)/256, 256, 0, stream>>>(d_in[5], qkvw, L_, D_, D_, 384*128, 128, flag);
    cvt_t_k<<<(n+255)/256, 256, 0, stream>>>(d_in[6], qkvw, L_, D_, D_, 384*128, 256, flag);
  }
  // transposed weights into their own slots
  { int n=L_*D_*D_;   cvt_t_k<<<(n+255)/256,256,0,stream>>>(d_in[7],  cp[6],  L_, D_,  D_,  D_*D_,   0, flag); }  // Wo
  { int n=L_*D_*FF_;  cvt_t_k<<<(n+255)/256,256,0,stream>>>(d_in[9],  cp[8],  L_, D_,  FF_, D_*FF_,  0, flag); }  // sW1
  { int n=L_*FF_*D_;  cvt_t_k<<<(n+255)/256,256,0,stream>>>(d_in[11], cp[10], L_, FF_, D_,  FF_*D_,  0, flag); }  // sW2
  { int n=L_*D_*384;  cvt_t_k<<<(n+255)/256,256,0,stream>>>(d_in[17], cp[16], L_, D_,  384, D_*384,  0, flag); }  // Win
  { int n=L_*D_*D_;   cvt_t_k<<<(n+255)/256,256,0,stream>>>(d_in[19], cp[18], L_, D_,  D_,  D_*D_,   0, flag); }  // Wout
  { int n=L_*D_*FF_;  cvt_t_k<<<(n+255)/256,256,0,stream>>>(d_in[21], cp[20], L_, D_,  FF_, D_*FF_,  0, flag); }  // tW1
  { int n=L_*FF_*D_;  cvt_t_k<<<(n+255)/256,256,0,stream>>>(d_in[23], cp[22], L_, FF_, D_,  FF_*D_,  0, flag); }  // tW2
  abits_k<<<(NPAD*8+255)/256, 256, 0, stream>>>(adj, abg);
  embed_k<<<(TOK*D_)/256, 256, 0, stream>>>(x_c, Wi_c, bi_c, h);

  const dim3 gP  (1, TOK/128);
  const dim3 gF1 (4, TOK/128);
  const dim3 gQKV(3, TOK/128);

  for (int l = 0; l < L_; l++){
    // spatial attention
    ln_k<<<TOK/4, 256, 0, stream>>>(h, sg1_c + l*D_, sh1_c + l*D_, xnb);
    mgemm_k<<<gQKV, 256, 0, stream>>>(xnb, qkvw + (size_t)l*384*128, nullptr, qkvb, 384, D_, 0, 0);
    sattn_k<<<B_*T_*H_, 256, 0, stream>>>(qkvb, abg, ob);
    mgemm_k<<<gP, 256, 0, stream>>>(ob, Wo_t + (size_t)l*D_*D_, bo_c + l*D_, h, D_, D_, 0, 1);
    // FFN 1
    ln_k<<<TOK/4, 256, 0, stream>>>(h, sg2_c + l*D_, sh2_c + l*D_, xnb);
    mgemm_k<<<gF1, 256, 0, stream>>>(xnb, sW1_t + (size_t)l*D_*FF_, sB1_c + l*FF_, ffb, FF_, D_, 1, 0);
    mgemm_k<<<gP , 256, 0, stream>>>(ffb, sW2_t + (size_t)l*FF_*D_, sB2_c + l*D_, h, D_, FF_, 0, 1);
    // temporal attention
    ln_k<<<TOK/4, 256, 0, stream>>>(h, tg1_c + l*D_, th1_c + l*D_, xnb);
    mgemm_k<<<gQKV, 256, 0, stream>>>(xnb, Win_t + (size_t)l*D_*384, Bin_c + l*384, qkvb, 384, D_, 0, 0);
    tattn_k<<<B_*N_, 128, 0, stream>>>(qkvb, ob);
    mgemm_k<<<gP, 256, 0, stream>>>(ob, Wout_t + (size_t)l*D_*D_, Bout_c + l*D_, h, D_, D_, 0, 1);
    // FFN 2
    ln_k<<<TOK/4, 256, 0, stream>>>(h, tg2_c + l*D_, th2_c + l*D_, xnb);
    mgemm_k<<<gF1, 256, 0, stream>>>(xnb, tW1_t + (size_t)l*D_*FF_, tB1_c + l*FF_, ffb, FF_, D_, 1, 0);
    mgemm_k<<<gP , 256, 0, stream>>>(ffb, tW2_t + (size_t)l*FF_*D_, tB2_c + l*D_, h, D_, FF_, 0, 1);
  }

  // head
  bf16* hlb = reg_;
  bf16* z1  = reg_ + (size_t)ROWS2*128;
  bf16* z2  = z1   + (size_t)ROWS2*256;
  gather_k<<<(ROWS2*D_)/256, 256, 0, stream>>>(h, hlb);
  gemm_k<<<dim3(256/64, (ROWS2+63)/64), 256, 0, stream>>>(hlb, 128, P1_c, Pb1_c, z1, 256, ROWS2, 256, 128, 1, 0);
  gemm_k<<<dim3(128/64, (ROWS2+63)/64), 256, 0, stream>>>(z1, 256, P2_c, Pb2_c, z2, 128, ROWS2, 128, 256, 1, 0);
  head3_k<<<(out_size+255)/256, 256, 0, stream>>>(z2, P3_c, Pb3_c, d_out, out_size, flag);
}

// Round 5
// 2084.992 us; speedup vs baseline: 3.8361x; 1.4300x over previous
//
#include <hip/hip_runtime.h>
#include <hip/hip_bf16.h>

#define B_   32
#define N_   207
#define T_   12
#define D_   128
#define H_   8
#define HD_  16
#define L_   4
#define FF_  512
#define PL_  12
#define TOK  (B_*N_*T_)      // 79488 = 621*128
#define ROWS2 (B_*N_)        // 6624
#define SCALE_ 0.25f
#define NEG_  -1e9f
#define NPAD 208             // 13*16
#define KQ2  24              // K LDS row stride (bf16): 16 data + 8 pad (quads>=2 predicated off)
#define KV2  232             // Vt row stride (bf16): 0..206 data, 207..231 zero (16B-aligned rows)
#define KVF2 226             // P row stride (fp32): 0..207 data, 208..225 zero

typedef __hip_bfloat16 bf16;
typedef unsigned int u32;
typedef __attribute__((ext_vector_type(4))) unsigned int u32x4;
typedef __attribute__((ext_vector_type(8))) short bf16x8;   // 8 bf16 = 4 VGPRs (MFMA A/B frag)
typedef __attribute__((ext_vector_type(4))) float f32x4;    // MFMA C/D frag

__device__ __forceinline__ float b2f(bf16 x){ return __bfloat162float(x); }
__device__ __forceinline__ bf16  f2b(float x){ return __float2bfloat16(x); }
__device__ __forceinline__ short bbits(bf16 x){ union{bf16 b; short s;} c; c.b = x; return c.s; }

// ---- dtype detection: flag=1 if input bits look like bf16, 0 if fp32 ----
__global__ void detect_k(const void* x, int* flag){
  __shared__ int cnt[256];
  const unsigned short* u = (const unsigned short*)x;
  int ok = 0;
  for (int i = threadIdx.x; i < 4096; i += 256){
    unsigned int bits = ((unsigned int)u[i]) << 16;
    float f = __uint_as_float(bits);
    float a = fabsf(f);
    if (f == 0.0f || (a > 1e-4f && a < 64.0f)) ok++;
  }
  cnt[threadIdx.x] = ok;
  __syncthreads();
  for (int s = 128; s > 0; s >>= 1){
    if (threadIdx.x < s) cnt[threadIdx.x] += cnt[threadIdx.x + s];
    __syncthreads();
  }
  if (threadIdx.x == 0) *flag = (cnt[0] > 3686) ? 1 : 0;
}

// ---- flat convert ----
__global__ void cvt_k(const void* src, bf16* dst, int n, const int* flag){
  int i = blockIdx.x*256 + threadIdx.x;
  if (i >= n) return;
  if (*flag) dst[i] = ((const bf16*)src)[i];
  else       dst[i] = f2b(((const float*)src)[i]);
}

// ---- transpose convert: src[l][k][n] -> dst[l*Lstr + (rowOff+n)*K + k] ----
__global__ void cvt_t_k(const void* src, bf16* dst, int Lr, int K, int Nc,
                        int Lstr, int rowOff, const int* flag){
  int i = blockIdx.x*256 + threadIdx.x;
  int tot = Lr*K*Nc;
  if (i >= tot) return;
  int l = i / (K*Nc); int rm = i - l*(K*Nc); int k = rm / Nc; int n = rm - k*Nc;
  float v = (*flag) ? b2f(((const bf16*)src)[i]) : ((const float*)src)[i];
  dst[(size_t)l*Lstr + (size_t)(rowOff+n)*K + k] = f2b(v);
}

// ---- pack adjacency to bitmask: out[208][7] u32, bit m of row n = (adj[n][m]!=0) ----
__global__ void abits_k(const int* adj, u32* out){
  int i = blockIdx.x*256 + threadIdx.x;
  if (i >= NPAD*7) return;
  int n = i / 7, wj = i % 7;
  u32 v = 0;
  if (n < N_){
    for (int bit = 0; bit < 32; bit++){
      int m = wj*32 + bit;
      if (m < N_ && adj[n*N_ + m] != 0) v |= (1u << bit);
    }
  }
  out[i] = v;
}

// ---- embed + fused LN (layer 0): h = x*Wi + bi; xnb = LN(h, sg1[0], sh1[0]) ----
__global__ void embed_ln_k(const bf16* x, const bf16* Wi, const bf16* bi,
                           const bf16* g, const bf16* bta, float* h, bf16* xnb){
  int wave = threadIdx.x >> 6, lane = threadIdx.x & 63;
  int tok = blockIdx.x*4 + wave;
  if (tok >= TOK) return;
  float xv = b2f(x[tok]);
  float v0 = xv*b2f(Wi[lane])    + b2f(bi[lane]);
  float v1 = xv*b2f(Wi[lane+64]) + b2f(bi[lane+64]);
  float* hp = h + (size_t)tok*D_;
  hp[lane] = v0; hp[lane+64] = v1;
  float s = v0 + v1;
  for (int off = 32; off >= 1; off >>= 1) s += __shfl_xor(s, off, 64);
  float m = s * (1.0f/128.0f);
  float d0 = v0 - m, d1 = v1 - m;
  float vv = d0*d0 + d1*d1;
  for (int off = 32; off >= 1; off >>= 1) vv += __shfl_xor(vv, off, 64);
  float r = rsqrtf(vv*(1.0f/128.0f) + 1e-5f);
  bf16* op = xnb + (size_t)tok*D_;
  op[lane]    = f2b(d0*r*b2f(g[lane])    + b2f(bta[lane]));
  op[lane+64] = f2b(d1*r*b2f(g[lane+64]) + b2f(bta[lane+64]));
}

// ---- MFMA GEMM (non-acc): out = [relu](A[M,K] @ Wt[N,K]^T + bias), bf16 out ----
__global__ __launch_bounds__(256) void mgemm_k(const bf16* __restrict__ A,
    const bf16* __restrict__ Wt, const bf16* __restrict__ bias,
    bf16* __restrict__ outp, int ldo, int Ktot, int relu){
  __shared__ bf16 As[128*32];
  __shared__ bf16 Bs[128*32];
  int tid = threadIdx.x;
  int rowBase = blockIdx.y * 128, colBase = blockIdx.x * 128;
  int w = tid >> 6, lane = tid & 63, quad = lane >> 4, cl = lane & 15;
  int waveM = w >> 1, waveN = w & 1;
  f32x4 accr[4][4];
  #pragma unroll
  for (int i = 0; i < 4; i++)
    #pragma unroll
    for (int j = 0; j < 4; j++) accr[i][j] = (f32x4){0.f,0.f,0.f,0.f};
  int lr = tid >> 2, kc = tid & 3;
  const bf16* Ap = A  + (size_t)(rowBase + lr)*Ktot + kc*8;
  const bf16* Bp = Wt + (size_t)(colBase + lr)*Ktot + kc*8;
  bf16* AsW = As + lr*32 + kc*8;
  bf16* BsW = Bs + lr*32 + kc*8;
  for (int kk = 0; kk < Ktot; kk += 32){
    u32x4 a0 = *(const u32x4*)(Ap + kk);
    u32x4 a1 = *(const u32x4*)(Ap + (size_t)64*Ktot + kk);
    u32x4 b0 = *(const u32x4*)(Bp + kk);
    u32x4 b1 = *(const u32x4*)(Bp + (size_t)64*Ktot + kk);
    __syncthreads();
    *(u32x4*)AsW = a0; *(u32x4*)(AsW + 64*32) = a1;
    *(u32x4*)BsW = b0; *(u32x4*)(BsW + 64*32) = b1;
    __syncthreads();
    bf16x8 af[4], bfr[4];
    #pragma unroll
    for (int mi = 0; mi < 4; mi++)
      af[mi] = *(const bf16x8*)(As + (waveM*64 + mi*16 + cl)*32 + quad*8);
    #pragma unroll
    for (int nj = 0; nj < 4; nj++)
      bfr[nj] = *(const bf16x8*)(Bs + (waveN*64 + nj*16 + cl)*32 + quad*8);
    #pragma unroll
    for (int mi = 0; mi < 4; mi++)
      #pragma unroll
      for (int nj = 0; nj < 4; nj++)
        accr[mi][nj] = __builtin_amdgcn_mfma_f32_16x16x32_bf16(af[mi], bfr[nj], accr[mi][nj], 0,0,0);
  }
  float bv[4];
  #pragma unroll
  for (int nj = 0; nj < 4; nj++)
    bv[nj] = bias ? b2f(bias[colBase + waveN*64 + nj*16 + cl]) : 0.0f;
  #pragma unroll
  for (int mi = 0; mi < 4; mi++){
    int row0 = rowBase + waveM*64 + mi*16 + quad*4;
    #pragma unroll
    for (int nj = 0; nj < 4; nj++){
      int col = colBase + waveN*64 + nj*16 + cl;
      #pragma unroll
      for (int r = 0; r < 4; r++){
        float v = accr[mi][nj][r] + bv[nj];
        if (relu) v = fmaxf(v, 0.0f);
        outp[(size_t)(row0+r)*ldo + col] = f2b(v);
      }
    }
  }
}

// ---- MFMA GEMM + residual-acc + fused LayerNorm ----
// h[row] += A@Wt^T + bias; if g: xnb[row] = LN(h[row])*g + b. N=128 (grid.x=1).
__global__ __launch_bounds__(256) void mgemm_ln_k(const bf16* __restrict__ A,
    const bf16* __restrict__ Wt, const bf16* __restrict__ bias,
    float* __restrict__ hout, int Ktot,
    const bf16* __restrict__ g, const bf16* __restrict__ bta,
    bf16* __restrict__ xnb){
  __shared__ bf16 As[128*32];
  __shared__ bf16 Bs[128*32];
  __shared__ float red[2][128][2];
  int tid = threadIdx.x;
  int rowBase = blockIdx.y * 128;
  int w = tid >> 6, lane = tid & 63, quad = lane >> 4, cl = lane & 15;
  int waveM = w >> 1, waveN = w & 1;
  f32x4 accr[4][4];
  #pragma unroll
  for (int i = 0; i < 4; i++)
    #pragma unroll
    for (int j = 0; j < 4; j++) accr[i][j] = (f32x4){0.f,0.f,0.f,0.f};
  int lr = tid >> 2, kc = tid & 3;
  const bf16* Ap = A  + (size_t)(rowBase + lr)*Ktot + kc*8;
  const bf16* Bp = Wt + (size_t)lr*Ktot + kc*8;
  bf16* AsW = As + lr*32 + kc*8;
  bf16* BsW = Bs + lr*32 + kc*8;
  for (int kk = 0; kk < Ktot; kk += 32){
    u32x4 a0 = *(const u32x4*)(Ap + kk);
    u32x4 a1 = *(const u32x4*)(Ap + (size_t)64*Ktot + kk);
    u32x4 b0 = *(const u32x4*)(Bp + kk);
    u32x4 b1 = *(const u32x4*)(Bp + (size_t)64*Ktot + kk);
    __syncthreads();
    *(u32x4*)AsW = a0; *(u32x4*)(AsW + 64*32) = a1;
    *(u32x4*)BsW = b0; *(u32x4*)(BsW + 64*32) = b1;
    __syncthreads();
    bf16x8 af[4], bfr[4];
    #pragma unroll
    for (int mi = 0; mi < 4; mi++)
      af[mi] = *(const bf16x8*)(As + (waveM*64 + mi*16 + cl)*32 + quad*8);
    #pragma unroll
    for (int nj = 0; nj < 4; nj++)
      bfr[nj] = *(const bf16x8*)(Bs + (waveN*64 + nj*16 + cl)*32 + quad*8);
    #pragma unroll
    for (int mi = 0; mi < 4; mi++)
      #pragma unroll
      for (int nj = 0; nj < 4; nj++)
        accr[mi][nj] = __builtin_amdgcn_mfma_f32_16x16x32_bf16(af[mi], bfr[nj], accr[mi][nj], 0,0,0);
  }
  int colW = waveN*64;
  float bv[4];
  #pragma unroll
  for (int nj = 0; nj < 4; nj++)
    bv[nj] = bias ? b2f(bias[colW + nj*16 + cl]) : 0.0f;
  float hv[4][4][4];             // [mi][nj][r]
  float psum[4][4], psq[4][4];   // [mi][r]
  #pragma unroll
  for (int mi = 0; mi < 4; mi++)
    #pragma unroll
    for (int r = 0; r < 4; r++){ psum[mi][r] = 0.f; psq[mi][r] = 0.f; }
  #pragma unroll
  for (int mi = 0; mi < 4; mi++){
    #pragma unroll
    for (int r = 0; r < 4; r++){
      int row = rowBase + waveM*64 + mi*16 + quad*4 + r;
      #pragma unroll
      for (int nj = 0; nj < 4; nj++){
        int col = colW + nj*16 + cl;
        size_t idx = (size_t)row*D_ + col;
        float v = hout[idx] + accr[mi][nj][r] + bv[nj];
        hout[idx] = v;
        hv[mi][nj][r] = v;
        psum[mi][r] += v; psq[mi][r] += v*v;
      }
    }
  }
  if (g){
    #pragma unroll
    for (int off = 1; off <= 8; off <<= 1)
      #pragma unroll
      for (int mi = 0; mi < 4; mi++)
        #pragma unroll
        for (int r = 0; r < 4; r++){
          psum[mi][r] += __shfl_xor(psum[mi][r], off, 64);
          psq[mi][r]  += __shfl_xor(psq[mi][r],  off, 64);
        }
    if (cl == 0){
      #pragma unroll
      for (int mi = 0; mi < 4; mi++)
        #pragma unroll
        for (int r = 0; r < 4; r++){
          int rl = waveM*64 + mi*16 + quad*4 + r;
          red[waveN][rl][0] = psum[mi][r];
          red[waveN][rl][1] = psq[mi][r];
        }
    }
    __syncthreads();
    float gv[4], btv[4];
    #pragma unroll
    for (int nj = 0; nj < 4; nj++){
      int col = colW + nj*16 + cl;
      gv[nj] = b2f(g[col]); btv[nj] = b2f(bta[col]);
    }
    #pragma unroll
    for (int mi = 0; mi < 4; mi++){
      #pragma unroll
      for (int r = 0; r < 4; r++){
        int rl = waveM*64 + mi*16 + quad*4 + r;
        float s = red[0][rl][0] + red[1][rl][0];
        float q = red[0][rl][1] + red[1][rl][1];
        float mean = s*(1.0f/128.0f);
        float var  = q*(1.0f/128.0f) - mean*mean;
        float rstd = rsqrtf(var + 1e-5f);
        int row = rowBase + rl;
        #pragma unroll
        for (int nj = 0; nj < 4; nj++){
          int col = colW + nj*16 + cl;
          xnb[(size_t)row*D_ + col] = f2b((hv[mi][nj][r]-mean)*rstd*gv[nj] + btv[nj]);
        }
      }
    }
  }
}

// ---- MFMA spatial attention: one block per (b,t,h); qkv packed [TOK][384] ----
// fp32 P in LDS; PV via hi/lo bf16 split. LDS trimmed to 81 KB -> 2 blocks/CU.
__global__ __launch_bounds__(256,2) void sattn_k(const bf16* __restrict__ qkv,
    const u32* __restrict__ abg, bf16* __restrict__ ob){
  __shared__ bf16  Ks[NPAD*KQ2];       // 9984 B (no zero-fill; quads>=2 predicated)
  __shared__ bf16  Vt[16*KV2];         // 7424 B
  __shared__ float Psf[4*16*KVF2];     // 57856 B
  __shared__ u32   abs_[NPAD*7];       // 5824 B
  int tid = threadIdx.x;
  int bid = blockIdx.x;
  int b = bid / (T_*H_); int rem = bid % (T_*H_); int t = rem / H_; int hh = rem % H_;
  // zero only the pad columns that are read but never written
  for (int i = tid; i < 16*25; i += 256){ int d = i/25, c = i%25 + 207; Vt[d*KV2 + c] = 0; }
  for (int i = tid; i < 4*16*18; i += 256){
    int w_ = i/(16*18); int rm2 = i - w_*(16*18); int row = rm2/18, c = rm2%18 + 208;
    Psf[(w_*16 + row)*KVF2 + c] = 0.0f;
  }
  // stage K, V^T, adjacency bits
  for (int i = tid; i < N_*16; i += 256){
    int n = i >> 4, d = i & 15;
    size_t rowb = ((size_t)((b*N_ + n)*T_ + t))*384 + hh*HD_;
    Ks[n*KQ2 + d] = qkv[rowb + 128 + d];
    Vt[d*KV2 + n] = qkv[rowb + 256 + d];
  }
  for (int i = tid; i < NPAD*7; i += 256) abs_[i] = abg[i];
  __syncthreads();

  int w = tid >> 6, lane = tid & 63, quad = lane >> 4, cl = lane & 15;
  int nstripes = (w == 0) ? 4 : 3;
  for (int si = 0; si < nstripes; si++){
    int mi = w + si*4;          // 0..12
    // ---- Q fragment direct from global (no reuse across stripes) ----
    bf16x8 aq = (bf16x8){0,0,0,0,0,0,0,0};
    {
      int n = mi*16 + cl; if (n > N_-1) n = N_-1;   // clamp pad row (never stored)
      size_t rowb = ((size_t)((b*N_ + n)*T_ + t))*384 + hh*HD_;
      if (quad < 2) aq = *(const bf16x8*)(qkv + rowb + quad*8);
    }
    // ---- QK^T: S stripe [16 x 208] in registers ----
    f32x4 s[13];
    #pragma unroll
    for (int nj = 0; nj < 13; nj++){
      bf16x8 bk = (bf16x8){0,0,0,0,0,0,0,0};
      if (quad < 2) bk = *(const bf16x8*)(Ks + (nj*16 + cl)*KQ2 + quad*8);
      f32x4 z = {0.f,0.f,0.f,0.f};
      s[nj] = __builtin_amdgcn_mfma_f32_16x16x32_bf16(aq, bk, z, 0,0,0);
    }
    // ---- mask + softmax per row; write fp32 P ----
    int row0 = mi*16 + quad*4;
    float* Pw = Psf + w*16*KVF2;
    #pragma unroll
    for (int r = 0; r < 4; r++){
      const u32* ab = abs_ + (row0 + r)*7;
      float mx = -3.4e38f;
      #pragma unroll
      for (int nj = 0; nj < 13; nj++){
        int cg = nj*16 + cl;
        float v = s[nj][r] * SCALE_;
        if (cg > 206) v = -3.4e38f;
        else if (!((ab[cg >> 5] >> (cg & 31)) & 1)) v = NEG_;
        s[nj][r] = v;
        mx = fmaxf(mx, v);
      }
      for (int off = 1; off < 16; off <<= 1) mx = fmaxf(mx, __shfl_xor(mx, off, 64));
      float sum = 0.0f;
      #pragma unroll
      for (int nj = 0; nj < 13; nj++){
        float e = __expf(s[nj][r] - mx);
        s[nj][r] = e; sum += e;
      }
      for (int off = 1; off < 16; off <<= 1) sum += __shfl_xor(sum, off, 64);
      float inv = 1.0f/sum;
      float* Pr = Pw + (quad*4 + r)*KVF2;
      #pragma unroll
      for (int nj = 0; nj < 13; nj++) Pr[nj*16 + cl] = s[nj][r]*inv;
    }
    __threadfence_block();   // order P writes before same-wave PV reads
    // ---- PV: O stripe [16 x 16], hi/lo split for fp32-class P precision ----
    f32x4 o = {0.f,0.f,0.f,0.f};
    const float* Prow = Pw + cl*KVF2;
    #pragma unroll
    for (int kt = 0; kt < 7; kt++){
      union { bf16x8 v; short s[8]; } hi, lo;
      const float* pp = Prow + kt*32 + quad*8;
      #pragma unroll
      for (int j = 0; j < 8; j++){
        float p = pp[j];
        bf16 h1 = f2b(p);
        hi.s[j] = bbits(h1);
        lo.s[j] = bbits(f2b(p - b2f(h1)));
      }
      bf16x8 bv = *(const bf16x8*)(Vt + cl*KV2 + kt*32 + quad*8);
      o = __builtin_amdgcn_mfma_f32_16x16x32_bf16(hi.v, bv, o, 0,0,0);
      o = __builtin_amdgcn_mfma_f32_16x16x32_bf16(lo.v, bv, o, 0,0,0);
    }
    #pragma unroll
    for (int r = 0; r < 4; r++){
      int rg = row0 + r;
      if (rg < N_)
        ob[((size_t)((b*N_ + rg)*T_ + t))*D_ + hh*HD_ + cl] = f2b(o[r]);
    }
    __threadfence_block();   // order PV reads before next stripe's P writes
  }
}

// ---- temporal attention: one block (128 thr) per (b,n); qkv rows of 384 ----
__global__ void tattn_k(const bf16* qkv, bf16* ob){
  int bid = blockIdx.x; int b = bid / N_, n = bid % N_;
  __shared__ float qs[T_*D_];
  __shared__ float ks[T_*D_];
  __shared__ float vs[T_*D_];
  size_t rowb = ((size_t)(b*N_+n)*T_)*384;
  for (int idx = threadIdx.x; idx < T_*384; idx += 128){
    int tt = idx / 384, c = idx - tt*384;
    float v = b2f(qkv[rowb + (size_t)tt*384 + c]);
    if (c < 128)      qs[tt*128 + c]       = v;
    else if (c < 256) ks[tt*128 + (c-128)] = v;
    else              vs[tt*128 + (c-256)] = v;
  }
  __syncthreads();
  int p = threadIdx.x;
  if (p < H_*T_){
    int hh = p / T_, t = p - hh*T_;
    float qreg[16];
    for (int d = 0; d < 16; d++) qreg[d] = qs[t*128 + hh*16 + d];
    float sc[12]; float mx = -3.4e38f;
    for (int s = 0; s < 12; s++){
      float a = 0.0f;
      for (int d = 0; d < 16; d++) a += qreg[d]*ks[s*128 + hh*16 + d];
      a = (s <= t) ? a*SCALE_ : -3.4e38f;
      sc[s] = a; mx = fmaxf(mx, a);
    }
    float ssum = 0.0f;
    for (int s = 0; s < 12; s++){
      float e = (s <= t) ? __expf(sc[s]-mx) : 0.0f;
      sc[s] = e; ssum += e;
    }
    float inv = 1.0f/ssum;
    size_t obase = ((size_t)(b*N_+n)*T_ + t)*D_ + hh*16;
    for (int d = 0; d < 16; d++){
      float acc = 0.0f;
      for (int s = 0; s < 12; s++) acc += sc[s]*vs[s*128 + hh*16 + d];
      ob[obase + d] = f2b(acc*inv);
    }
  }
}

// ---- VALU GEMM kept for the small head GEMMs ----
__global__ void gemm_k(const bf16* A, int lda, const bf16* W, const bf16* bias,
                       void* outp, int ldo, int M, int Ncols, int K, int relu, int acc){
  __shared__ float Ast[16*68];
  __shared__ float Ws [16*68];
  int tx = threadIdx.x & 15, ty = threadIdx.x >> 4;
  int rowBase = blockIdx.y * 64, colBase = blockIdx.x * 64;
  float accr[4][4];
  for (int i = 0; i < 4; i++) for (int j = 0; j < 4; j++) accr[i][j] = 0.0f;
  for (int kk = 0; kk < K; kk += 16){
    int kq = threadIdx.x & 15, r0 = threadIdx.x >> 4;
    for (int it = 0; it < 4; it++){
      int r = r0 + it*16, row = rowBase + r;
      float v = 0.0f;
      if (row < M) v = b2f(A[(size_t)row*lda + kk + kq]);
      Ast[kq*68 + r] = v;
    }
    int c = threadIdx.x & 63, w0 = threadIdx.x >> 6;
    for (int it = 0; it < 4; it++){
      int kr = w0 + it*4;
      Ws[kr*68 + c] = b2f(W[(size_t)(kk+kr)*Ncols + colBase + c]);
    }
    __syncthreads();
    for (int k = 0; k < 16; k++){
      float av[4], wv[4];
      for (int i = 0; i < 4; i++) av[i] = Ast[k*68 + ty*4 + i];
      for (int j = 0; j < 4; j++) wv[j] = Ws[k*68 + tx*4 + j];
      for (int i = 0; i < 4; i++)
        for (int j = 0; j < 4; j++) accr[i][j] += av[i]*wv[j];
    }
    __syncthreads();
  }
  for (int i = 0; i < 4; i++){
    int row = rowBase + ty*4 + i;
    if (row >= M) continue;
    for (int j = 0; j < 4; j++){
      int col = colBase + tx*4 + j;
      float v = accr[i][j];
      if (bias) v += b2f(bias[col]);
      if (relu) v = fmaxf(v, 0.0f);
      if (acc) ((float*)outp)[(size_t)row*ldo + col] += v;
      else     ((bf16*)outp)[(size_t)row*ldo + col] = f2b(v);
    }
  }
}

__global__ void gather_k(const float* h, bf16* hlb){
  int i = blockIdx.x*256 + threadIdx.x;
  if (i >= ROWS2*D_) return;
  int r = i >> 7, d = i & 127;
  hlb[i] = f2b(h[((size_t)r*T_ + (T_-1))*D_ + d]);
}

__global__ void head3_k(const bf16* z2, const bf16* P3, const bf16* Pb3,
                        void* out, int out_n, const int* flag){
  int i = blockIdx.x*256 + threadIdx.x;
  if (i >= out_n) return;
  int r = i / PL_, j = i - r*PL_;
  float acc = b2f(Pb3[j]);
  for (int d = 0; d < 128; d++) acc += b2f(z2[(size_t)r*128 + d]) * b2f(P3[d*PL_ + j]);
  if (*flag) ((bf16*)out)[i] = f2b(acc);
  else       ((float*)out)[i] = acc;
}

extern "C" void kernel_launch(void* const* d_in, const int* in_sizes, int n_in,
                              void* d_out, int out_size, void* d_ws, size_t ws_size,
                              hipStream_t stream){
  // ws layout
  size_t HB = (size_t)TOK*D_*4;      // fp32 residual h
  size_t XB = (size_t)TOK*D_*2;      // bf16 xn
  size_t RB = (size_t)TOK*D_*8;      // bf16 qkv(384)+ob(128), aliases ffb(512)
  float* h    = (float*)d_ws;
  bf16*  xnb  = (bf16*)((char*)d_ws + HB);
  bf16*  reg_ = (bf16*)((char*)d_ws + HB + XB);
  bf16*  cvt  = (bf16*)((char*)d_ws + HB + XB + RB);
  const int FIDX[34] = {0,2,3,4,5,6,7,8,9,10,11,12,13,14,15,16,17,18,19,20,
                        21,22,23,24,25,26,27,28,29,30,31,32,33,34};
  bf16* cp[34];
  size_t off = 0;
  for (int i = 0; i < 34; i++){ cp[i] = cvt + off; off += (size_t)in_sizes[FIDX[i]]; }
  char* tail   = (char*)d_ws + HB + XB + RB + ((off*2 + 255) & ~(size_t)255);
  u32*  abg    = (u32*)tail;                        // 208*7 u32
  bf16* qkvw   = (bf16*)(tail + 8192);              // packed QKV weights [L][384][128]
  int*  flag   = (int*)(tail + 8192 + (size_t)L_*384*128*2);

  const bf16 *x_c=cp[0], *Wi_c=cp[1], *bi_c=cp[2],
             *Wo_t=cp[6], *bo_c=cp[7], *sW1_t=cp[8], *sB1_c=cp[9], *sW2_t=cp[10], *sB2_c=cp[11],
             *sg1_c=cp[12], *sh1_c=cp[13], *sg2_c=cp[14], *sh2_c=cp[15], *Win_t=cp[16], *Bin_c=cp[17],
             *Wout_t=cp[18], *Bout_c=cp[19], *tW1_t=cp[20], *tB1_c=cp[21], *tW2_t=cp[22], *tB2_c=cp[23],
             *tg1_c=cp[24], *th1_c=cp[25], *tg2_c=cp[26], *th2_c=cp[27], *P1_c=cp[28], *Pb1_c=cp[29],
             *P2_c=cp[30], *Pb2_c=cp[31], *P3_c=cp[32], *Pb3_c=cp[33];
  const int* adj = (const int*)d_in[1];

  bf16* qkvb = reg_;                       // [TOK][384]
  bf16* ob   = reg_ + (size_t)TOK*384;     // [TOK][128]
  bf16* ffb  = reg_;                       // [TOK][512] (aliases qkvb+ob, disjoint lifetime)

  detect_k<<<1, 256, 0, stream>>>(d_in[0], flag);
  const int FLAT[24] = {0,1,2,7,9,11,12,13,14,15,17,19,21,23,24,25,26,27,28,29,30,31,32,33};
  for (int ii = 0; ii < 24; ii++){
    int ci = FLAT[ii]; int n = in_sizes[FIDX[ci]];
    cvt_k<<<(n+255)/256, 256, 0, stream>>>(d_in[FIDX[ci]], cp[ci], n, flag);
  }
  // packed QKV weight transpose: Wq->rows 0..127, Wk->128..255, Wv->256..383
  {
    int n = L_*D_*D_;
    cvt_t_k<<<(n+255)/256, 256, 0, stream>>>(d_in[4], qkvw, L_, D_, D_, 384*128, 0,   flag);
    cvt_t_k<<<(n+255)/256, 256, 0, stream>>>(d_in[5], qkvw, L_, D_, D_, 384*128, 128, flag);
    cvt_t_k<<<(n+255)/256, 256, 0, stream>>>(d_in[6], qkvw, L_, D_, D_, 384*128, 256, flag);
  }
  // transposed weights into their own slots
  { int n=L_*D_*D_;   cvt_t_k<<<(n+255)/256,256,0,stream>>>(d_in[7],  cp[6],  L_, D_,  D_,  D_*D_,   0, flag); }  // Wo
  { int n=L_*D_*FF_;  cvt_t_k<<<(n+255)/256,256,0,stream>>>(d_in[9],  cp[8],  L_, D_,  FF_, D_*FF_,  0, flag); }  // sW1
  { int n=L_*FF_*D_;  cvt_t_k<<<(n+255)/256,256,0,stream>>>(d_in[11], cp[10], L_, FF_, D_,  FF_*D_,  0, flag); }  // sW2
  { int n=L_*D_*384;  cvt_t_k<<<(n+255)/256,256,0,stream>>>(d_in[17], cp[16], L_, D_,  384, D_*384,  0, flag); }  // Win
  { int n=L_*D_*D_;   cvt_t_k<<<(n+255)/256,256,0,stream>>>(d_in[19], cp[18], L_, D_,  D_,  D_*D_,   0, flag); }  // Wout
  { int n=L_*D_*FF_;  cvt_t_k<<<(n+255)/256,256,0,stream>>>(d_in[21], cp[20], L_, D_,  FF_, D_*FF_,  0, flag); }  // tW1
  { int n=L_*FF_*D_;  cvt_t_k<<<(n+255)/256,256,0,stream>>>(d_in[23], cp[22], L_, FF_, D_,  FF_*D_,  0, flag); }  // tW2
  abits_k<<<(NPAD*7+255)/256, 256, 0, stream>>>(adj, abg);
  embed_ln_k<<<TOK/4, 256, 0, stream>>>(x_c, Wi_c, bi_c, sg1_c, sh1_c, h, xnb);

  const dim3 gP  (1, TOK/128);
  const dim3 gF1 (4, TOK/128);
  const dim3 gQKV(3, TOK/128);

  for (int l = 0; l < L_; l++){
    // spatial attention
    mgemm_k<<<gQKV, 256, 0, stream>>>(xnb, qkvw + (size_t)l*384*128, nullptr, qkvb, 384, D_, 0);
    sattn_k<<<B_*T_*H_, 256, 0, stream>>>(qkvb, abg, ob);
    mgemm_ln_k<<<gP, 256, 0, stream>>>(ob, Wo_t + (size_t)l*D_*D_, bo_c + l*D_, h, D_,
                                       sg2_c + l*D_, sh2_c + l*D_, xnb);
    // FFN 1
    mgemm_k<<<gF1, 256, 0, stream>>>(xnb, sW1_t + (size_t)l*D_*FF_, sB1_c + l*FF_, ffb, FF_, D_, 1);
    mgemm_ln_k<<<gP, 256, 0, stream>>>(ffb, sW2_t + (size_t)l*FF_*D_, sB2_c + l*D_, h, FF_,
                                       tg1_c + l*D_, th1_c + l*D_, xnb);
    // temporal attention
    mgemm_k<<<gQKV, 256, 0, stream>>>(xnb, Win_t + (size_t)l*D_*384, Bin_c + l*384, qkvb, 384, D_, 0);
    tattn_k<<<B_*N_, 128, 0, stream>>>(qkvb, ob);
    mgemm_ln_k<<<gP, 256, 0, stream>>>(ob, Wout_t + (size_t)l*D_*D_, Bout_c + l*D_, h, D_,
                                       tg2_c + l*D_, th2_c + l*D_, xnb);
    // FFN 2
    mgemm_k<<<gF1, 256, 0, stream>>>(xnb, tW1_t + (size_t)l*D_*FF_, tB1_c + l*FF_, ffb, FF_, D_, 1);
    const bf16* gnext = (l < L_-1) ? (sg1_c + (l+1)*D_) : nullptr;
    const bf16* bnext = (l < L_-1) ? (sh1_c + (l+1)*D_) : nullptr;
    mgemm_ln_k<<<gP, 256, 0, stream>>>(ffb, tW2_t + (size_t)l*FF_*D_, tB2_c + l*D_, h, FF_,
                                       gnext, bnext, xnb);
  }

  // head
  bf16* hlb = reg_;
  bf16* z1  = reg_ + (size_t)ROWS2*128;
  bf16* z2  = z1   + (size_t)ROWS2*256;
  gather_k<<<(ROWS2*D_)/256, 256, 0, stream>>>(h, hlb);
  gemm_k<<<dim3(256/64, (ROWS2+63)/64), 256, 0, stream>>>(hlb, 128, P1_c, Pb1_c, z1, 256, ROWS2, 256, 128, 1, 0);
  gemm_k<<<dim3(128/64, (ROWS2+63)/64), 256, 0, stream>>>(z1, 256, P2_c, Pb2_c, z2, 128, ROWS2, 128, 256, 1, 0);
  head3_k<<<(out_size+255)/256, 256, 0, stream>>>(z2, P3_c, Pb3_c, d_out, out_size, flag);
}

// Round 6
// 1766.861 us; speedup vs baseline: 4.5268x; 1.1801x over previous
//
#include <hip/hip_runtime.h>
#include <hip/hip_bf16.h>

#define B_   32
#define N_   207
#define T_   12
#define D_   128
#define H_   8
#define HD_  16
#define L_   4
#define FF_  512
#define PL_  12
#define TOK  (B_*N_*T_)      // 79488 = 621*128
#define ROWS2 (B_*N_)        // 6624
#define SCALE_ 0.25f
#define NEG_  -1e9f
#define NPAD 208             // 13*16
#define KQ2  24              // K LDS row stride (bf16): 16 data + 8 pad (quads>=2 predicated)
#define KVH  232             // Vt/P row stride (fp16): 0..206 data, 207..231 zero; 464B = 29*16

typedef __hip_bfloat16 bf16;
typedef unsigned int u32;
typedef __attribute__((ext_vector_type(8))) short bf16x8;     // 8 bf16 (MFMA A/B frag)
typedef __attribute__((ext_vector_type(8))) _Float16 f16x8;   // 8 fp16 (MFMA A/B frag)
typedef __attribute__((ext_vector_type(4))) float f32x4;      // MFMA C/D frag

__device__ __forceinline__ float b2f(bf16 x){ return __bfloat162float(x); }
__device__ __forceinline__ bf16  f2b(float x){ return __float2bfloat16(x); }

// async global->LDS 16B per lane (dest must be wave-uniform base + lane*16)
__device__ __forceinline__ void gll16(const bf16* g, bf16* l){
  __builtin_amdgcn_global_load_lds((const __attribute__((address_space(1))) void*)g,
                                   (__attribute__((address_space(3))) void*)l, 16, 0, 0);
}

// ---- dtype detection: flag=1 if input bits look like bf16, 0 if fp32 ----
__global__ void detect_k(const void* x, int* flag){
  __shared__ int cnt[256];
  const unsigned short* u = (const unsigned short*)x;
  int ok = 0;
  for (int i = threadIdx.x; i < 4096; i += 256){
    unsigned int bits = ((unsigned int)u[i]) << 16;
    float f = __uint_as_float(bits);
    float a = fabsf(f);
    if (f == 0.0f || (a > 1e-4f && a < 64.0f)) ok++;
  }
  cnt[threadIdx.x] = ok;
  __syncthreads();
  for (int s = 128; s > 0; s >>= 1){
    if (threadIdx.x < s) cnt[threadIdx.x] += cnt[threadIdx.x + s];
    __syncthreads();
  }
  if (threadIdx.x == 0) *flag = (cnt[0] > 3686) ? 1 : 0;
}

// ---- batched flat convert: 24 segments in one launch ----
struct FlatArgs {
  const void* src[24];
  long long dst[24];     // element offset from ws base
  int cum[25];
};
__global__ void cvt_flat_k(FlatArgs a, bf16* base, const int* flag, int total){
  int i = blockIdx.x*256 + threadIdx.x;
  if (i >= total) return;
  int j = 0;
  while (i >= a.cum[j+1]) j++;
  int loc = i - a.cum[j];
  float v = (*flag) ? b2f(((const bf16*)a.src[j])[loc]) : ((const float*)a.src[j])[loc];
  base[a.dst[j] + loc] = f2b(v);
}

// ---- batched transpose convert: src[l][k][n] -> base[dst + l*Lstr + (ro+n)*K + k] ----
struct TArgs {
  const void* src[10];
  long long dst[10];
  int K[10], Nc[10], Lstr[10], ro[10];
  int cum[11];
};
__global__ void cvt_t_k(TArgs a, bf16* base, const int* flag, int total){
  int i = blockIdx.x*256 + threadIdx.x;
  if (i >= total) return;
  int j = 0;
  while (i >= a.cum[j+1]) j++;
  int loc = i - a.cum[j];
  int KN = a.K[j]*a.Nc[j];
  int l = loc / KN; int rm = loc - l*KN; int k = rm / a.Nc[j]; int n = rm - k*a.Nc[j];
  float v = (*flag) ? b2f(((const bf16*)a.src[j])[loc]) : ((const float*)a.src[j])[loc];
  base[a.dst[j] + (long long)l*a.Lstr[j] + (long long)(a.ro[j]+n)*a.K[j] + k] = f2b(v);
}

// ---- pack adjacency to bitmask: out[208][7] u32 ----
__global__ void abits_k(const int* adj, u32* out){
  int i = blockIdx.x*256 + threadIdx.x;
  if (i >= NPAD*7) return;
  int n = i / 7, wj = i % 7;
  u32 v = 0;
  if (n < N_){
    for (int bit = 0; bit < 32; bit++){
      int m = wj*32 + bit;
      if (m < N_ && adj[n*N_ + m] != 0) v |= (1u << bit);
    }
  }
  out[i] = v;
}

// ---- embed + fused LN (layer 0) ----
__global__ void embed_ln_k(const bf16* x, const bf16* Wi, const bf16* bi,
                           const bf16* g, const bf16* bta, float* h, bf16* xnb){
  int wave = threadIdx.x >> 6, lane = threadIdx.x & 63;
  int tok = blockIdx.x*4 + wave;
  if (tok >= TOK) return;
  float xv = b2f(x[tok]);
  float v0 = xv*b2f(Wi[lane])    + b2f(bi[lane]);
  float v1 = xv*b2f(Wi[lane+64]) + b2f(bi[lane+64]);
  float* hp = h + (size_t)tok*D_;
  hp[lane] = v0; hp[lane+64] = v1;
  float s = v0 + v1;
  for (int off = 32; off >= 1; off >>= 1) s += __shfl_xor(s, off, 64);
  float m = s * (1.0f/128.0f);
  float d0 = v0 - m, d1 = v1 - m;
  float vv = d0*d0 + d1*d1;
  for (int off = 32; off >= 1; off >>= 1) vv += __shfl_xor(vv, off, 64);
  float r = rsqrtf(vv*(1.0f/128.0f) + 1e-5f);
  bf16* op = xnb + (size_t)tok*D_;
  op[lane]    = f2b(d0*r*b2f(g[lane])    + b2f(bta[lane]));
  op[lane+64] = f2b(d1*r*b2f(g[lane+64]) + b2f(bta[lane+64]));
}

// ---- MFMA GEMM (non-acc), global_load_lds staging ----
__global__ __launch_bounds__(256) void mgemm_k(const bf16* __restrict__ A,
    const bf16* __restrict__ Wt, const bf16* __restrict__ bias,
    bf16* __restrict__ outp, int ldo, int Ktot, int relu){
  __shared__ __align__(16) bf16 As[128*32];
  __shared__ __align__(16) bf16 Bs[128*32];
  int tid = threadIdx.x;
  int rowBase = blockIdx.y * 128, colBase = blockIdx.x * 128;
  int w = tid >> 6, lane = tid & 63, quad = lane >> 4, cl = lane & 15;
  int waveM = w >> 1, waveN = w & 1;
  f32x4 accr[4][4];
  #pragma unroll
  for (int i = 0; i < 4; i++)
    #pragma unroll
    for (int j = 0; j < 4; j++) accr[i][j] = (f32x4){0.f,0.f,0.f,0.f};
  int lr = tid >> 2, kc = tid & 3;
  const bf16* Ap = A  + (size_t)(rowBase + lr)*Ktot + kc*8;
  const bf16* Bp = Wt + (size_t)(colBase + lr)*Ktot + kc*8;
  bf16* AsW = As + tid*8;
  bf16* BsW = Bs + tid*8;
  for (int kk = 0; kk < Ktot; kk += 32){
    __syncthreads();
    gll16(Ap + kk, AsW);
    gll16(Ap + (size_t)64*Ktot + kk, AsW + 64*32);
    gll16(Bp + kk, BsW);
    gll16(Bp + (size_t)64*Ktot + kk, BsW + 64*32);
    __syncthreads();
    bf16x8 af[4], bfr[4];
    #pragma unroll
    for (int mi = 0; mi < 4; mi++)
      af[mi] = *(const bf16x8*)(As + (waveM*64 + mi*16 + cl)*32 + quad*8);
    #pragma unroll
    for (int nj = 0; nj < 4; nj++)
      bfr[nj] = *(const bf16x8*)(Bs + (waveN*64 + nj*16 + cl)*32 + quad*8);
    #pragma unroll
    for (int mi = 0; mi < 4; mi++)
      #pragma unroll
      for (int nj = 0; nj < 4; nj++)
        accr[mi][nj] = __builtin_amdgcn_mfma_f32_16x16x32_bf16(af[mi], bfr[nj], accr[mi][nj], 0,0,0);
  }
  float bv[4];
  #pragma unroll
  for (int nj = 0; nj < 4; nj++)
    bv[nj] = bias ? b2f(bias[colBase + waveN*64 + nj*16 + cl]) : 0.0f;
  #pragma unroll
  for (int mi = 0; mi < 4; mi++){
    int row0 = rowBase + waveM*64 + mi*16 + quad*4;
    #pragma unroll
    for (int nj = 0; nj < 4; nj++){
      int col = colBase + waveN*64 + nj*16 + cl;
      #pragma unroll
      for (int r = 0; r < 4; r++){
        float v = accr[mi][nj][r] + bv[nj];
        if (relu) v = fmaxf(v, 0.0f);
        outp[(size_t)(row0+r)*ldo + col] = f2b(v);
      }
    }
  }
}

// ---- MFMA GEMM + residual-acc + fused LayerNorm (N=128, grid.x=1) ----
__global__ __launch_bounds__(256) void mgemm_ln_k(const bf16* __restrict__ A,
    const bf16* __restrict__ Wt, const bf16* __restrict__ bias,
    float* __restrict__ hout, int Ktot,
    const bf16* __restrict__ g, const bf16* __restrict__ bta,
    bf16* __restrict__ xnb){
  __shared__ __align__(16) bf16 As[128*32];
  __shared__ __align__(16) bf16 Bs[128*32];
  __shared__ float red[2][128][2];
  int tid = threadIdx.x;
  int rowBase = blockIdx.y * 128;
  int w = tid >> 6, lane = tid & 63, quad = lane >> 4, cl = lane & 15;
  int waveM = w >> 1, waveN = w & 1;
  f32x4 accr[4][4];
  #pragma unroll
  for (int i = 0; i < 4; i++)
    #pragma unroll
    for (int j = 0; j < 4; j++) accr[i][j] = (f32x4){0.f,0.f,0.f,0.f};
  int lr = tid >> 2, kc = tid & 3;
  const bf16* Ap = A  + (size_t)(rowBase + lr)*Ktot + kc*8;
  const bf16* Bp = Wt + (size_t)lr*Ktot + kc*8;
  bf16* AsW = As + tid*8;
  bf16* BsW = Bs + tid*8;
  for (int kk = 0; kk < Ktot; kk += 32){
    __syncthreads();
    gll16(Ap + kk, AsW);
    gll16(Ap + (size_t)64*Ktot + kk, AsW + 64*32);
    gll16(Bp + kk, BsW);
    gll16(Bp + (size_t)64*Ktot + kk, BsW + 64*32);
    __syncthreads();
    bf16x8 af[4], bfr[4];
    #pragma unroll
    for (int mi = 0; mi < 4; mi++)
      af[mi] = *(const bf16x8*)(As + (waveM*64 + mi*16 + cl)*32 + quad*8);
    #pragma unroll
    for (int nj = 0; nj < 4; nj++)
      bfr[nj] = *(const bf16x8*)(Bs + (waveN*64 + nj*16 + cl)*32 + quad*8);
    #pragma unroll
    for (int mi = 0; mi < 4; mi++)
      #pragma unroll
      for (int nj = 0; nj < 4; nj++)
        accr[mi][nj] = __builtin_amdgcn_mfma_f32_16x16x32_bf16(af[mi], bfr[nj], accr[mi][nj], 0,0,0);
  }
  int colW = waveN*64;
  float bv[4];
  #pragma unroll
  for (int nj = 0; nj < 4; nj++)
    bv[nj] = bias ? b2f(bias[colW + nj*16 + cl]) : 0.0f;
  float hv[4][4][4];
  float psum[4][4], psq[4][4];
  #pragma unroll
  for (int mi = 0; mi < 4; mi++)
    #pragma unroll
    for (int r = 0; r < 4; r++){ psum[mi][r] = 0.f; psq[mi][r] = 0.f; }
  #pragma unroll
  for (int mi = 0; mi < 4; mi++){
    #pragma unroll
    for (int r = 0; r < 4; r++){
      int row = rowBase + waveM*64 + mi*16 + quad*4 + r;
      #pragma unroll
      for (int nj = 0; nj < 4; nj++){
        int col = colW + nj*16 + cl;
        size_t idx = (size_t)row*D_ + col;
        float v = hout[idx] + accr[mi][nj][r] + bv[nj];
        hout[idx] = v;
        hv[mi][nj][r] = v;
        psum[mi][r] += v; psq[mi][r] += v*v;
      }
    }
  }
  if (g){
    #pragma unroll
    for (int off = 1; off <= 8; off <<= 1)
      #pragma unroll
      for (int mi = 0; mi < 4; mi++)
        #pragma unroll
        for (int r = 0; r < 4; r++){
          psum[mi][r] += __shfl_xor(psum[mi][r], off, 64);
          psq[mi][r]  += __shfl_xor(psq[mi][r],  off, 64);
        }
    if (cl == 0){
      #pragma unroll
      for (int mi = 0; mi < 4; mi++)
        #pragma unroll
        for (int r = 0; r < 4; r++){
          int rl = waveM*64 + mi*16 + quad*4 + r;
          red[waveN][rl][0] = psum[mi][r];
          red[waveN][rl][1] = psq[mi][r];
        }
    }
    __syncthreads();
    float gv[4], btv[4];
    #pragma unroll
    for (int nj = 0; nj < 4; nj++){
      int col = colW + nj*16 + cl;
      gv[nj] = b2f(g[col]); btv[nj] = b2f(bta[col]);
    }
    #pragma unroll
    for (int mi = 0; mi < 4; mi++){
      #pragma unroll
      for (int r = 0; r < 4; r++){
        int rl = waveM*64 + mi*16 + quad*4 + r;
        float s = red[0][rl][0] + red[1][rl][0];
        float q = red[0][rl][1] + red[1][rl][1];
        float mean = s*(1.0f/128.0f);
        float var  = q*(1.0f/128.0f) - mean*mean;
        float rstd = rsqrtf(var + 1e-5f);
        int row = rowBase + rl;
        #pragma unroll
        for (int nj = 0; nj < 4; nj++){
          int col = colW + nj*16 + cl;
          xnb[(size_t)row*D_ + col] = f2b((hv[mi][nj][r]-mean)*rstd*gv[nj] + btv[nj]);
        }
      }
    }
  }
}

// ---- MFMA spatial attention: one block per (b,t,h); qkv packed [TOK][384] ----
// QK^T in bf16 MFMA; P stored as fp16 in LDS; PV via single f16 MFMA chain.
// LDS ~52.9 KB -> 3 blocks/CU.
__global__ __launch_bounds__(256,3) void sattn_k(const bf16* __restrict__ qkv,
    const u32* __restrict__ abg, bf16* __restrict__ ob){
  __shared__ __align__(16) bf16     Ks[NPAD*KQ2];   // 9984 B
  __shared__ __align__(16) _Float16 Vt[16*KVH];     // 7424 B
  __shared__ __align__(16) _Float16 Ps[4*16*KVH];   // 29696 B
  __shared__ u32 abs_[NPAD*7];                      // 5824 B
  int tid = threadIdx.x;
  int bid = blockIdx.x;
  int b = bid / (T_*H_); int rem = bid % (T_*H_); int t = rem / H_; int hh = rem % H_;
  // zero pad columns (read but never written)
  for (int i = tid; i < 16*25; i += 256){ int d = i/25, c = 207 + i%25; Vt[d*KVH + c] = (_Float16)0.0f; }
  for (int i = tid; i < 64*24; i += 256){ int row = i/24, c = 208 + i%24; Ps[row*KVH + c] = (_Float16)0.0f; }
  // stage K (bf16), V^T (fp16), adjacency bits
  for (int i = tid; i < N_*16; i += 256){
    int n = i >> 4, d = i & 15;
    size_t rowb = ((size_t)((b*N_ + n)*T_ + t))*384 + hh*HD_;
    Ks[n*KQ2 + d] = qkv[rowb + 128 + d];
    Vt[d*KVH + n] = (_Float16)b2f(qkv[rowb + 256 + d]);
  }
  for (int i = tid; i < NPAD*7; i += 256) abs_[i] = abg[i];
  __syncthreads();

  int w = tid >> 6, lane = tid & 63, quad = lane >> 4, cl = lane & 15;
  int nstripes = (w == 0) ? 4 : 3;
  for (int si = 0; si < nstripes; si++){
    int mi = w + si*4;          // 0..12
    // Q fragment direct from global (no reuse across stripes)
    bf16x8 aq = (bf16x8){0,0,0,0,0,0,0,0};
    {
      int n = mi*16 + cl; if (n > N_-1) n = N_-1;   // clamp pad row (never stored)
      size_t rowb = ((size_t)((b*N_ + n)*T_ + t))*384 + hh*HD_;
      if (quad < 2) aq = *(const bf16x8*)(qkv + rowb + quad*8);
    }
    // QK^T: S stripe [16 x 208] in registers
    f32x4 s[13];
    #pragma unroll
    for (int nj = 0; nj < 13; nj++){
      bf16x8 bk = (bf16x8){0,0,0,0,0,0,0,0};
      if (quad < 2) bk = *(const bf16x8*)(Ks + (nj*16 + cl)*KQ2 + quad*8);
      f32x4 z = {0.f,0.f,0.f,0.f};
      s[nj] = __builtin_amdgcn_mfma_f32_16x16x32_bf16(aq, bk, z, 0,0,0);
    }
    // mask + softmax per row; write fp16 P
    int row0 = mi*16 + quad*4;
    _Float16* Pw = Ps + w*16*KVH;
    #pragma unroll
    for (int r = 0; r < 4; r++){
      const u32* ab = abs_ + (row0 + r)*7;
      float mx = -3.4e38f;
      #pragma unroll
      for (int nj = 0; nj < 13; nj++){
        int cg = nj*16 + cl;
        float v = s[nj][r] * SCALE_;
        if (cg > 206) v = -3.4e38f;
        else if (!((ab[cg >> 5] >> (cg & 31)) & 1)) v = NEG_;
        s[nj][r] = v;
        mx = fmaxf(mx, v);
      }
      for (int off = 1; off < 16; off <<= 1) mx = fmaxf(mx, __shfl_xor(mx, off, 64));
      float sum = 0.0f;
      #pragma unroll
      for (int nj = 0; nj < 13; nj++){
        float e = __expf(s[nj][r] - mx);
        s[nj][r] = e; sum += e;
      }
      for (int off = 1; off < 16; off <<= 1) sum += __shfl_xor(sum, off, 64);
      float inv = 1.0f/sum;
      _Float16* Pr = Pw + (quad*4 + r)*KVH;
      #pragma unroll
      for (int nj = 0; nj < 13; nj++) Pr[nj*16 + cl] = (_Float16)(s[nj][r]*inv);
    }
    __threadfence_block();   // order P writes before same-wave PV reads
    // PV: O stripe [16 x 16], single f16 MFMA chain
    f32x4 o = {0.f,0.f,0.f,0.f};
    #pragma unroll
    for (int kt = 0; kt < 7; kt++){
      f16x8 ap = *(const f16x8*)(Pw + cl*KVH + kt*32 + quad*8);
      f16x8 bv = *(const f16x8*)(Vt + cl*KVH + kt*32 + quad*8);
      o = __builtin_amdgcn_mfma_f32_16x16x32_f16(ap, bv, o, 0,0,0);
    }
    #pragma unroll
    for (int r = 0; r < 4; r++){
      int rg = row0 + r;
      if (rg < N_)
        ob[((size_t)((b*N_ + rg)*T_ + t))*D_ + hh*HD_ + cl] = f2b(o[r]);
    }
    __threadfence_block();   // order PV reads before next stripe's P writes
  }
}

// ---- temporal attention: one block (128 thr) per (b,n); qkv rows of 384 ----
__global__ void tattn_k(const bf16* qkv, bf16* ob){
  int bid = blockIdx.x; int b = bid / N_, n = bid % N_;
  __shared__ float qs[T_*D_];
  __shared__ float ks[T_*D_];
  __shared__ float vs[T_*D_];
  size_t rowb = ((size_t)(b*N_+n)*T_)*384;
  const u32* src = (const u32*)(qkv + rowb);
  for (int idx = threadIdx.x; idx < T_*192; idx += 128){
    int tt = idx / 192, cw = idx - tt*192;
    u32 pr = src[tt*192 + cw];
    union { u32 u; bf16 b[2]; } cv; cv.u = pr;
    float v0 = b2f(cv.b[0]), v1 = b2f(cv.b[1]);
    int arr = cw >> 6, cp2 = (cw & 63)*2;
    float* dst = (arr == 0) ? qs : (arr == 1) ? ks : vs;
    dst[tt*128 + cp2] = v0; dst[tt*128 + cp2 + 1] = v1;
  }
  __syncthreads();
  int p = threadIdx.x;
  if (p < H_*T_){
    int hh = p / T_, t = p - hh*T_;
    float qreg[16];
    for (int d = 0; d < 16; d++) qreg[d] = qs[t*128 + hh*16 + d];
    float sc[12]; float mx = -3.4e38f;
    for (int s = 0; s < 12; s++){
      float a = 0.0f;
      for (int d = 0; d < 16; d++) a += qreg[d]*ks[s*128 + hh*16 + d];
      a = (s <= t) ? a*SCALE_ : -3.4e38f;
      sc[s] = a; mx = fmaxf(mx, a);
    }
    float ssum = 0.0f;
    for (int s = 0; s < 12; s++){
      float e = (s <= t) ? __expf(sc[s]-mx) : 0.0f;
      sc[s] = e; ssum += e;
    }
    float inv = 1.0f/ssum;
    size_t obase = ((size_t)(b*N_+n)*T_ + t)*D_ + hh*16;
    for (int d = 0; d < 16; d++){
      float acc = 0.0f;
      for (int s = 0; s < 12; s++) acc += sc[s]*vs[s*128 + hh*16 + d];
      ob[obase + d] = f2b(acc*inv);
    }
  }
}

// ---- VALU GEMM kept for the small head GEMMs ----
__global__ void gemm_k(const bf16* A, int lda, const bf16* W, const bf16* bias,
                       void* outp, int ldo, int M, int Ncols, int K, int relu, int acc){
  __shared__ float Ast[16*68];
  __shared__ float Ws [16*68];
  int tx = threadIdx.x & 15, ty = threadIdx.x >> 4;
  int rowBase = blockIdx.y * 64, colBase = blockIdx.x * 64;
  float accr[4][4];
  for (int i = 0; i < 4; i++) for (int j = 0; j < 4; j++) accr[i][j] = 0.0f;
  for (int kk = 0; kk < K; kk += 16){
    int kq = threadIdx.x & 15, r0 = threadIdx.x >> 4;
    for (int it = 0; it < 4; it++){
      int r = r0 + it*16, row = rowBase + r;
      float v = 0.0f;
      if (row < M) v = b2f(A[(size_t)row*lda + kk + kq]);
      Ast[kq*68 + r] = v;
    }
    int c = threadIdx.x & 63, w0 = threadIdx.x >> 6;
    for (int it = 0; it < 4; it++){
      int kr = w0 + it*4;
      Ws[kr*68 + c] = b2f(W[(size_t)(kk+kr)*Ncols + colBase + c]);
    }
    __syncthreads();
    for (int k = 0; k < 16; k++){
      float av[4], wv[4];
      for (int i = 0; i < 4; i++) av[i] = Ast[k*68 + ty*4 + i];
      for (int j = 0; j < 4; j++) wv[j] = Ws[k*68 + tx*4 + j];
      for (int i = 0; i < 4; i++)
        for (int j = 0; j < 4; j++) accr[i][j] += av[i]*wv[j];
    }
    __syncthreads();
  }
  for (int i = 0; i < 4; i++){
    int row = rowBase + ty*4 + i;
    if (row >= M) continue;
    for (int j = 0; j < 4; j++){
      int col = colBase + tx*4 + j;
      float v = accr[i][j];
      if (bias) v += b2f(bias[col]);
      if (relu) v = fmaxf(v, 0.0f);
      if (acc) ((float*)outp)[(size_t)row*ldo + col] += v;
      else     ((bf16*)outp)[(size_t)row*ldo + col] = f2b(v);
    }
  }
}

__global__ void gather_k(const float* h, bf16* hlb){
  int i = blockIdx.x*256 + threadIdx.x;
  if (i >= ROWS2*D_) return;
  int r = i >> 7, d = i & 127;
  hlb[i] = f2b(h[((size_t)r*T_ + (T_-1))*D_ + d]);
}

__global__ void head3_k(const bf16* z2, const bf16* P3, const bf16* Pb3,
                        void* out, int out_n, const int* flag){
  int i = blockIdx.x*256 + threadIdx.x;
  if (i >= out_n) return;
  int r = i / PL_, j = i - r*PL_;
  float acc = b2f(Pb3[j]);
  for (int d = 0; d < 128; d++) acc += b2f(z2[(size_t)r*128 + d]) * b2f(P3[d*PL_ + j]);
  if (*flag) ((bf16*)out)[i] = f2b(acc);
  else       ((float*)out)[i] = acc;
}

extern "C" void kernel_launch(void* const* d_in, const int* in_sizes, int n_in,
                              void* d_out, int out_size, void* d_ws, size_t ws_size,
                              hipStream_t stream){
  // ws layout
  size_t HB = (size_t)TOK*D_*4;      // fp32 residual h
  size_t XB = (size_t)TOK*D_*2;      // bf16 xn
  size_t RB = (size_t)TOK*D_*8;      // bf16 qkv(384)+ob(128), aliases ffb(512)
  float* h    = (float*)d_ws;
  bf16*  xnb  = (bf16*)((char*)d_ws + HB);
  bf16*  reg_ = (bf16*)((char*)d_ws + HB + XB);
  bf16*  cvt  = (bf16*)((char*)d_ws + HB + XB + RB);
  bf16*  wsb  = (bf16*)d_ws;         // element base for batched converters
  const int FIDX[34] = {0,2,3,4,5,6,7,8,9,10,11,12,13,14,15,16,17,18,19,20,
                        21,22,23,24,25,26,27,28,29,30,31,32,33,34};
  bf16* cp[34];
  size_t off = 0;
  for (int i = 0; i < 34; i++){ cp[i] = cvt + off; off += (size_t)in_sizes[FIDX[i]]; }
  char* tail   = (char*)d_ws + HB + XB + RB + ((off*2 + 255) & ~(size_t)255);
  u32*  abg    = (u32*)tail;                        // 208*7 u32
  bf16* qkvw   = (bf16*)(tail + 8192);              // packed QKV weights [L][384][128]
  int*  flag   = (int*)(tail + 8192 + (size_t)L_*384*128*2);

  const bf16 *x_c=cp[0], *Wi_c=cp[1], *bi_c=cp[2],
             *Wo_t=cp[6], *bo_c=cp[7], *sW1_t=cp[8], *sB1_c=cp[9], *sW2_t=cp[10], *sB2_c=cp[11],
             *sg1_c=cp[12], *sh1_c=cp[13], *sg2_c=cp[14], *sh2_c=cp[15], *Win_t=cp[16], *Bin_c=cp[17],
             *Wout_t=cp[18], *Bout_c=cp[19], *tW1_t=cp[20], *tB1_c=cp[21], *tW2_t=cp[22], *tB2_c=cp[23],
             *tg1_c=cp[24], *th1_c=cp[25], *tg2_c=cp[26], *th2_c=cp[27], *P1_c=cp[28], *Pb1_c=cp[29],
             *P2_c=cp[30], *Pb2_c=cp[31], *P3_c=cp[32], *Pb3_c=cp[33];
  const int* adj = (const int*)d_in[1];

  bf16* qkvb = reg_;                       // [TOK][384]
  bf16* ob   = reg_ + (size_t)TOK*384;     // [TOK][128]
  bf16* ffb  = reg_;                       // [TOK][512] (aliases qkvb+ob, disjoint lifetime)

  detect_k<<<1, 256, 0, stream>>>(d_in[0], flag);

  // batched flat conversions
  {
    const int FLAT[24] = {0,1,2,7,9,11,12,13,14,15,17,19,21,23,24,25,26,27,28,29,30,31,32,33};
    FlatArgs fa; int c = 0;
    for (int ii = 0; ii < 24; ii++){
      int ci = FLAT[ii];
      fa.src[ii] = d_in[FIDX[ci]];
      fa.dst[ii] = (long long)(cp[ci] - wsb);
      fa.cum[ii] = c;
      c += in_sizes[FIDX[ci]];
    }
    fa.cum[24] = c;
    cvt_flat_k<<<(c+255)/256, 256, 0, stream>>>(fa, wsb, flag, c);
  }
  // batched transpose conversions
  {
    TArgs ta; int c = 0;
    const void* srcs[10] = {d_in[4], d_in[5], d_in[6], d_in[7], d_in[9], d_in[11],
                            d_in[17], d_in[19], d_in[21], d_in[23]};
    bf16* dsts[10] = {qkvw, qkvw, qkvw, cp[6], cp[8], cp[10], cp[16], cp[18], cp[20], cp[22]};
    int Ks_[10]   = {128,128,128, 128, 128, 512, 128, 128, 128, 512};
    int Ncs[10]   = {128,128,128, 128, 512, 128, 384, 128, 512, 128};
    int Lst[10]   = {384*128,384*128,384*128, 128*128, 128*512, 512*128, 128*384, 128*128, 128*512, 512*128};
    int ros[10]   = {0,128,256, 0,0,0, 0,0,0, 0};
    for (int j = 0; j < 10; j++){
      ta.src[j] = srcs[j];
      ta.dst[j] = (long long)(dsts[j] - wsb);
      ta.K[j] = Ks_[j]; ta.Nc[j] = Ncs[j]; ta.Lstr[j] = Lst[j]; ta.ro[j] = ros[j];
      ta.cum[j] = c;
      c += L_*Ks_[j]*Ncs[j];
    }
    ta.cum[10] = c;
    cvt_t_k<<<(c+255)/256, 256, 0, stream>>>(ta, wsb, flag, c);
  }
  abits_k<<<(NPAD*7+255)/256, 256, 0, stream>>>(adj, abg);
  embed_ln_k<<<TOK/4, 256, 0, stream>>>(x_c, Wi_c, bi_c, sg1_c, sh1_c, h, xnb);

  const dim3 gP  (1, TOK/128);
  const dim3 gF1 (4, TOK/128);
  const dim3 gQKV(3, TOK/128);

  for (int l = 0; l < L_; l++){
    // spatial attention
    mgemm_k<<<gQKV, 256, 0, stream>>>(xnb, qkvw + (size_t)l*384*128, nullptr, qkvb, 384, D_, 0);
    sattn_k<<<B_*T_*H_, 256, 0, stream>>>(qkvb, abg, ob);
    mgemm_ln_k<<<gP, 256, 0, stream>>>(ob, Wo_t + (size_t)l*D_*D_, bo_c + l*D_, h, D_,
                                       sg2_c + l*D_, sh2_c + l*D_, xnb);
    // FFN 1
    mgemm_k<<<gF1, 256, 0, stream>>>(xnb, sW1_t + (size_t)l*D_*FF_, sB1_c + l*FF_, ffb, FF_, D_, 1);
    mgemm_ln_k<<<gP, 256, 0, stream>>>(ffb, sW2_t + (size_t)l*FF_*D_, sB2_c + l*D_, h, FF_,
                                       tg1_c + l*D_, th1_c + l*D_, xnb);
    // temporal attention
    mgemm_k<<<gQKV, 256, 0, stream>>>(xnb, Win_t + (size_t)l*D_*384, Bin_c + l*384, qkvb, 384, D_, 0);
    tattn_k<<<B_*N_, 128, 0, stream>>>(qkvb, ob);
    mgemm_ln_k<<<gP, 256, 0, stream>>>(ob, Wout_t + (size_t)l*D_*D_, Bout_c + l*D_, h, D_,
                                       tg2_c + l*D_, th2_c + l*D_, xnb);
    // FFN 2
    mgemm_k<<<gF1, 256, 0, stream>>>(xnb, tW1_t + (size_t)l*D_*FF_, tB1_c + l*FF_, ffb, FF_, D_, 1);
    const bf16* gnext = (l < L_-1) ? (sg1_c + (l+1)*D_) : nullptr;
    const bf16* bnext = (l < L_-1) ? (sh1_c + (l+1)*D_) : nullptr;
    mgemm_ln_k<<<gP, 256, 0, stream>>>(ffb, tW2_t + (size_t)l*FF_*D_, tB2_c + l*D_, h, FF_,
                                       gnext, bnext, xnb);
  }

  // head
  bf16* hlb = reg_;
  bf16* z1  = reg_ + (size_t)ROWS2*128;
  bf16* z2  = z1   + (size_t)ROWS2*256;
  gather_k<<<(ROWS2*D_)/256, 256, 0, stream>>>(h, hlb);
  gemm_k<<<dim3(256/64, (ROWS2+63)/64), 256, 0, stream>>>(hlb, 128, P1_c, Pb1_c, z1, 256, ROWS2, 256, 128, 1, 0);
  gemm_k<<<dim3(128/64, (ROWS2+63)/64), 256, 0, stream>>>(z1, 256, P2_c, Pb2_c, z2, 128, ROWS2, 128, 256, 1, 0);
  head3_k<<<(out_size+255)/256, 256, 0, stream>>>(z2, P3_c, Pb3_c, d_out, out_size, flag);
}

// Round 7
// 1751.168 us; speedup vs baseline: 4.5673x; 1.0090x over previous
//
#include <hip/hip_runtime.h>
#include <hip/hip_bf16.h>

#define B_   32
#define N_   207
#define T_   12
#define D_   128
#define H_   8
#define HD_  16
#define L_   4
#define FF_  512
#define PL_  12
#define TOK  (B_*N_*T_)      // 79488 = 621*128
#define ROWS2 (B_*N_)        // 6624
#define SCALE_ 0.25f
#define NEG_  -1e9f
#define NPAD 208             // 13*16
#define KQ2  24              // K LDS row stride (bf16): 16 data + 8 pad (quads>=2 predicated)
#define KVH  232             // Vt/P row stride (fp16): 0..206 data, 207..231 zero
#define SLAB 3312            // 207*16 elements per (b,t,h) slab

typedef __hip_bfloat16 bf16;
typedef unsigned int u32;
typedef __attribute__((ext_vector_type(8))) short bf16x8;     // 8 bf16 (MFMA A/B frag)
typedef __attribute__((ext_vector_type(8))) _Float16 f16x8;   // 8 fp16 (MFMA A/B frag)
typedef __attribute__((ext_vector_type(4))) float f32x4;      // MFMA C/D frag

__device__ __forceinline__ float b2f(bf16 x){ return __bfloat162float(x); }
__device__ __forceinline__ bf16  f2b(float x){ return __float2bfloat16(x); }

// async global->LDS 16B per lane (dest must be wave-uniform base + lane*16)
__device__ __forceinline__ void gll16(const bf16* g, bf16* l){
  __builtin_amdgcn_global_load_lds((const __attribute__((address_space(1))) void*)g,
                                   (__attribute__((address_space(3))) void*)l, 16, 0, 0);
}

// ---- dtype detection ----
__global__ void detect_k(const void* x, int* flag){
  __shared__ int cnt[256];
  const unsigned short* u = (const unsigned short*)x;
  int ok = 0;
  for (int i = threadIdx.x; i < 4096; i += 256){
    unsigned int bits = ((unsigned int)u[i]) << 16;
    float f = __uint_as_float(bits);
    float a = fabsf(f);
    if (f == 0.0f || (a > 1e-4f && a < 64.0f)) ok++;
  }
  cnt[threadIdx.x] = ok;
  __syncthreads();
  for (int s = 128; s > 0; s >>= 1){
    if (threadIdx.x < s) cnt[threadIdx.x] += cnt[threadIdx.x + s];
    __syncthreads();
  }
  if (threadIdx.x == 0) *flag = (cnt[0] > 3686) ? 1 : 0;
}

// ---- batched flat convert ----
struct FlatArgs {
  const void* src[24];
  long long dst[24];
  int cum[25];
};
__global__ void cvt_flat_k(FlatArgs a, bf16* base, const int* flag, int total){
  int i = blockIdx.x*256 + threadIdx.x;
  if (i >= total) return;
  int j = 0;
  while (i >= a.cum[j+1]) j++;
  int loc = i - a.cum[j];
  float v = (*flag) ? b2f(((const bf16*)a.src[j])[loc]) : ((const float*)a.src[j])[loc];
  base[a.dst[j] + loc] = f2b(v);
}

// ---- batched transpose convert (with per-segment scale) ----
struct TArgs {
  const void* src[10];
  long long dst[10];
  int K[10], Nc[10], Lstr[10], ro[10];
  float scale[10];
  int cum[11];
};
__global__ void cvt_t_k(TArgs a, bf16* base, const int* flag, int total){
  int i = blockIdx.x*256 + threadIdx.x;
  if (i >= total) return;
  int j = 0;
  while (i >= a.cum[j+1]) j++;
  int loc = i - a.cum[j];
  int KN = a.K[j]*a.Nc[j];
  int l = loc / KN; int rm = loc - l*KN; int k = rm / a.Nc[j]; int n = rm - k*a.Nc[j];
  float v = (*flag) ? b2f(((const bf16*)a.src[j])[loc]) : ((const float*)a.src[j])[loc];
  base[a.dst[j] + (long long)l*a.Lstr[j] + (long long)(a.ro[j]+n)*a.K[j] + k] = f2b(v*a.scale[j]);
}

// ---- pack adjacency to bitmask: out[208][7] u32 ----
__global__ void abits_k(const int* adj, u32* out){
  int i = blockIdx.x*256 + threadIdx.x;
  if (i >= NPAD*7) return;
  int n = i / 7, wj = i % 7;
  u32 v = 0;
  if (n < N_){
    for (int bit = 0; bit < 32; bit++){
      int m = wj*32 + bit;
      if (m < N_ && adj[n*N_ + m] != 0) v |= (1u << bit);
    }
  }
  out[i] = v;
}

// ---- embed + fused LN (layer 0) ----
__global__ void embed_ln_k(const bf16* x, const bf16* Wi, const bf16* bi,
                           const bf16* g, const bf16* bta, float* h, bf16* xnb){
  int wave = threadIdx.x >> 6, lane = threadIdx.x & 63;
  int tok = blockIdx.x*4 + wave;
  if (tok >= TOK) return;
  float xv = b2f(x[tok]);
  float v0 = xv*b2f(Wi[lane])    + b2f(bi[lane]);
  float v1 = xv*b2f(Wi[lane+64]) + b2f(bi[lane+64]);
  float* hp = h + (size_t)tok*D_;
  hp[lane] = v0; hp[lane+64] = v1;
  float s = v0 + v1;
  for (int off = 32; off >= 1; off >>= 1) s += __shfl_xor(s, off, 64);
  float m = s * (1.0f/128.0f);
  float d0 = v0 - m, d1 = v1 - m;
  float vv = d0*d0 + d1*d1;
  for (int off = 32; off >= 1; off >>= 1) vv += __shfl_xor(vv, off, 64);
  float r = rsqrtf(vv*(1.0f/128.0f) + 1e-5f);
  bf16* op = xnb + (size_t)tok*D_;
  op[lane]    = f2b(d0*r*b2f(g[lane])    + b2f(bta[lane]));
  op[lane+64] = f2b(d1*r*b2f(g[lane+64]) + b2f(bta[lane+64]));
}

// ---- MFMA GEMM (non-acc), global_load_lds staging ----
__global__ __launch_bounds__(256) void mgemm_k(const bf16* __restrict__ A,
    const bf16* __restrict__ Wt, const bf16* __restrict__ bias,
    bf16* __restrict__ outp, int ldo, int Ktot, int relu){
  __shared__ __align__(16) bf16 As[128*32];
  __shared__ __align__(16) bf16 Bs[128*32];
  int tid = threadIdx.x;
  int rowBase = blockIdx.y * 128, colBase = blockIdx.x * 128;
  int w = tid >> 6, lane = tid & 63, quad = lane >> 4, cl = lane & 15;
  int waveM = w >> 1, waveN = w & 1;
  f32x4 accr[4][4];
  #pragma unroll
  for (int i = 0; i < 4; i++)
    #pragma unroll
    for (int j = 0; j < 4; j++) accr[i][j] = (f32x4){0.f,0.f,0.f,0.f};
  int lr = tid >> 2, kc = tid & 3;
  const bf16* Ap = A  + (size_t)(rowBase + lr)*Ktot + kc*8;
  const bf16* Bp = Wt + (size_t)(colBase + lr)*Ktot + kc*8;
  bf16* AsW = As + tid*8;
  bf16* BsW = Bs + tid*8;
  for (int kk = 0; kk < Ktot; kk += 32){
    __syncthreads();
    gll16(Ap + kk, AsW);
    gll16(Ap + (size_t)64*Ktot + kk, AsW + 64*32);
    gll16(Bp + kk, BsW);
    gll16(Bp + (size_t)64*Ktot + kk, BsW + 64*32);
    __syncthreads();
    bf16x8 af[4], bfr[4];
    #pragma unroll
    for (int mi = 0; mi < 4; mi++)
      af[mi] = *(const bf16x8*)(As + (waveM*64 + mi*16 + cl)*32 + quad*8);
    #pragma unroll
    for (int nj = 0; nj < 4; nj++)
      bfr[nj] = *(const bf16x8*)(Bs + (waveN*64 + nj*16 + cl)*32 + quad*8);
    #pragma unroll
    for (int mi = 0; mi < 4; mi++)
      #pragma unroll
      for (int nj = 0; nj < 4; nj++)
        accr[mi][nj] = __builtin_amdgcn_mfma_f32_16x16x32_bf16(af[mi], bfr[nj], accr[mi][nj], 0,0,0);
  }
  float bv[4];
  #pragma unroll
  for (int nj = 0; nj < 4; nj++)
    bv[nj] = bias ? b2f(bias[colBase + waveN*64 + nj*16 + cl]) : 0.0f;
  #pragma unroll
  for (int mi = 0; mi < 4; mi++){
    int row0 = rowBase + waveM*64 + mi*16 + quad*4;
    #pragma unroll
    for (int nj = 0; nj < 4; nj++){
      int col = colBase + waveN*64 + nj*16 + cl;
      #pragma unroll
      for (int r = 0; r < 4; r++){
        float v = accr[mi][nj][r] + bv[nj];
        if (relu) v = fmaxf(v, 0.0f);
        outp[(size_t)(row0+r)*ldo + col] = f2b(v);
      }
    }
  }
}

// ---- MFMA GEMM writing spatial q/k/v in [slab=(b,t,h)][n][16] layout ----
// A[TOK][128] @ qkvw[384][128]^T. Ktot=128, grid (3, TOK/128). No bias.
__global__ __launch_bounds__(256) void mgemm_qkvT_k(const bf16* __restrict__ A,
    const bf16* __restrict__ Wt, bf16* __restrict__ sQ,
    bf16* __restrict__ sK, bf16* __restrict__ sV){
  __shared__ __align__(16) bf16 As[128*32];
  __shared__ __align__(16) bf16 Bs[128*32];
  const int Ktot = 128;
  int tid = threadIdx.x;
  int rowBase = blockIdx.y * 128, colBase = blockIdx.x * 128;
  int w = tid >> 6, lane = tid & 63, quad = lane >> 4, cl = lane & 15;
  int waveM = w >> 1, waveN = w & 1;
  f32x4 accr[4][4];
  #pragma unroll
  for (int i = 0; i < 4; i++)
    #pragma unroll
    for (int j = 0; j < 4; j++) accr[i][j] = (f32x4){0.f,0.f,0.f,0.f};
  int lr = tid >> 2, kc = tid & 3;
  const bf16* Ap = A  + (size_t)(rowBase + lr)*Ktot + kc*8;
  const bf16* Bp = Wt + (size_t)(colBase + lr)*Ktot + kc*8;
  bf16* AsW = As + tid*8;
  bf16* BsW = Bs + tid*8;
  for (int kk = 0; kk < Ktot; kk += 32){
    __syncthreads();
    gll16(Ap + kk, AsW);
    gll16(Ap + (size_t)64*Ktot + kk, AsW + 64*32);
    gll16(Bp + kk, BsW);
    gll16(Bp + (size_t)64*Ktot + kk, BsW + 64*32);
    __syncthreads();
    bf16x8 af[4], bfr[4];
    #pragma unroll
    for (int mi = 0; mi < 4; mi++)
      af[mi] = *(const bf16x8*)(As + (waveM*64 + mi*16 + cl)*32 + quad*8);
    #pragma unroll
    for (int nj = 0; nj < 4; nj++)
      bfr[nj] = *(const bf16x8*)(Bs + (waveN*64 + nj*16 + cl)*32 + quad*8);
    #pragma unroll
    for (int mi = 0; mi < 4; mi++)
      #pragma unroll
      for (int nj = 0; nj < 4; nj++)
        accr[mi][nj] = __builtin_amdgcn_mfma_f32_16x16x32_bf16(af[mi], bfr[nj], accr[mi][nj], 0,0,0);
  }
  #pragma unroll
  for (int mi = 0; mi < 4; mi++){
    #pragma unroll
    for (int r = 0; r < 4; r++){
      int tok = rowBase + waveM*64 + mi*16 + quad*4 + r;
      int bn = tok / T_; int t = tok - bn*T_;
      int b = bn / N_;  int n = bn - b*N_;
      size_t base = ((size_t)(b*T_ + t)*H_)*SLAB + n*16 + cl;
      #pragma unroll
      for (int nj = 0; nj < 4; nj++){
        int col = colBase + waveN*64 + nj*16;
        int part = col >> 7, hh = (col >> 4) & 7;
        bf16* dst = (part == 0) ? sQ : (part == 1) ? sK : sV;
        dst[base + (size_t)hh*SLAB] = f2b(accr[mi][nj][r]);
      }
    }
  }
}

// ---- MFMA GEMM + residual-acc + fused LayerNorm (N=128, grid.x=1) ----
__global__ __launch_bounds__(256) void mgemm_ln_k(const bf16* __restrict__ A,
    const bf16* __restrict__ Wt, const bf16* __restrict__ bias,
    float* __restrict__ hout, int Ktot,
    const bf16* __restrict__ g, const bf16* __restrict__ bta,
    bf16* __restrict__ xnb){
  __shared__ __align__(16) bf16 As[128*32];
  __shared__ __align__(16) bf16 Bs[128*32];
  __shared__ float red[2][128][2];
  int tid = threadIdx.x;
  int rowBase = blockIdx.y * 128;
  int w = tid >> 6, lane = tid & 63, quad = lane >> 4, cl = lane & 15;
  int waveM = w >> 1, waveN = w & 1;
  f32x4 accr[4][4];
  #pragma unroll
  for (int i = 0; i < 4; i++)
    #pragma unroll
    for (int j = 0; j < 4; j++) accr[i][j] = (f32x4){0.f,0.f,0.f,0.f};
  int lr = tid >> 2, kc = tid & 3;
  const bf16* Ap = A  + (size_t)(rowBase + lr)*Ktot + kc*8;
  const bf16* Bp = Wt + (size_t)lr*Ktot + kc*8;
  bf16* AsW = As + tid*8;
  bf16* BsW = Bs + tid*8;
  for (int kk = 0; kk < Ktot; kk += 32){
    __syncthreads();
    gll16(Ap + kk, AsW);
    gll16(Ap + (size_t)64*Ktot + kk, AsW + 64*32);
    gll16(Bp + kk, BsW);
    gll16(Bp + (size_t)64*Ktot + kk, BsW + 64*32);
    __syncthreads();
    bf16x8 af[4], bfr[4];
    #pragma unroll
    for (int mi = 0; mi < 4; mi++)
      af[mi] = *(const bf16x8*)(As + (waveM*64 + mi*16 + cl)*32 + quad*8);
    #pragma unroll
    for (int nj = 0; nj < 4; nj++)
      bfr[nj] = *(const bf16x8*)(Bs + (waveN*64 + nj*16 + cl)*32 + quad*8);
    #pragma unroll
    for (int mi = 0; mi < 4; mi++)
      #pragma unroll
      for (int nj = 0; nj < 4; nj++)
        accr[mi][nj] = __builtin_amdgcn_mfma_f32_16x16x32_bf16(af[mi], bfr[nj], accr[mi][nj], 0,0,0);
  }
  int colW = waveN*64;
  float bv[4];
  #pragma unroll
  for (int nj = 0; nj < 4; nj++)
    bv[nj] = bias ? b2f(bias[colW + nj*16 + cl]) : 0.0f;
  float hv[4][4][4];
  float psum[4][4], psq[4][4];
  #pragma unroll
  for (int mi = 0; mi < 4; mi++)
    #pragma unroll
    for (int r = 0; r < 4; r++){ psum[mi][r] = 0.f; psq[mi][r] = 0.f; }
  #pragma unroll
  for (int mi = 0; mi < 4; mi++){
    #pragma unroll
    for (int r = 0; r < 4; r++){
      int row = rowBase + waveM*64 + mi*16 + quad*4 + r;
      #pragma unroll
      for (int nj = 0; nj < 4; nj++){
        int col = colW + nj*16 + cl;
        size_t idx = (size_t)row*D_ + col;
        float v = hout[idx] + accr[mi][nj][r] + bv[nj];
        hout[idx] = v;
        hv[mi][nj][r] = v;
        psum[mi][r] += v; psq[mi][r] += v*v;
      }
    }
  }
  if (g){
    #pragma unroll
    for (int off = 1; off <= 8; off <<= 1)
      #pragma unroll
      for (int mi = 0; mi < 4; mi++)
        #pragma unroll
        for (int r = 0; r < 4; r++){
          psum[mi][r] += __shfl_xor(psum[mi][r], off, 64);
          psq[mi][r]  += __shfl_xor(psq[mi][r],  off, 64);
        }
    if (cl == 0){
      #pragma unroll
      for (int mi = 0; mi < 4; mi++)
        #pragma unroll
        for (int r = 0; r < 4; r++){
          int rl = waveM*64 + mi*16 + quad*4 + r;
          red[waveN][rl][0] = psum[mi][r];
          red[waveN][rl][1] = psq[mi][r];
        }
    }
    __syncthreads();
    float gv[4], btv[4];
    #pragma unroll
    for (int nj = 0; nj < 4; nj++){
      int col = colW + nj*16 + cl;
      gv[nj] = b2f(g[col]); btv[nj] = b2f(bta[col]);
    }
    #pragma unroll
    for (int mi = 0; mi < 4; mi++){
      #pragma unroll
      for (int r = 0; r < 4; r++){
        int rl = waveM*64 + mi*16 + quad*4 + r;
        float s = red[0][rl][0] + red[1][rl][0];
        float q = red[0][rl][1] + red[1][rl][1];
        float mean = s*(1.0f/128.0f);
        float var  = q*(1.0f/128.0f) - mean*mean;
        float rstd = rsqrtf(var + 1e-5f);
        int row = rowBase + rl;
        #pragma unroll
        for (int nj = 0; nj < 4; nj++){
          int col = colW + nj*16 + cl;
          xnb[(size_t)row*D_ + col] = f2b((hv[mi][nj][r]-mean)*rstd*gv[nj] + btv[nj]);
        }
      }
    }
  }
}

// ---- MFMA spatial attention: one block per slab (b,t,h); coalesced staging ----
// q pre-scaled by SCALE at weight-convert time. fp16 P; f16 MFMA PV. 3 blocks/CU.
__global__ __launch_bounds__(256,3) void sattn_k(const bf16* __restrict__ sQ,
    const bf16* __restrict__ sK, const bf16* __restrict__ sV,
    const u32* __restrict__ abg, bf16* __restrict__ ob){
  __shared__ __align__(16) bf16     Ks[NPAD*KQ2];   // 9984 B
  __shared__ __align__(16) _Float16 Vt[16*KVH];     // 7424 B
  __shared__ __align__(16) _Float16 Ps[4*16*KVH];   // 29696 B
  __shared__ u32 abs_[NPAD*7];                      // 5824 B
  int tid = threadIdx.x;
  int bid = blockIdx.x;                // slab = (b*T+t)*H + hh
  int hh = bid & 7; int bt = bid >> 3; int t = bt % T_; int b = bt / T_;
  const bf16* Kslab = sK + (size_t)bid*SLAB;
  const bf16* Vslab = sV + (size_t)bid*SLAB;
  const bf16* Qslab = sQ + (size_t)bid*SLAB;
  // zero pad columns (read but never written)
  for (int i = tid; i < 16*25; i += 256){ int d = i/25, c = 207 + i%25; Vt[d*KVH + c] = (_Float16)0.0f; }
  for (int i = tid; i < 64*24; i += 256){ int row = i/24, c = 208 + i%24; Ps[row*KVH + c] = (_Float16)0.0f; }
  // stage K: 414 contiguous b128 chunks -> [n][d] rows (stride KQ2)
  for (int c = tid; c < 414; c += 256){
    bf16x8 kv = *(const bf16x8*)(Kslab + c*8);
    int n = c >> 1, dh = (c & 1)*8;
    *(bf16x8*)(Ks + n*KQ2 + dh) = kv;
  }
  // stage V transposed to [d][n] fp16 (coalesced global reads)
  for (int i = tid; i < SLAB; i += 256){
    int n = i >> 4, d = i & 15;
    Vt[d*KVH + n] = (_Float16)b2f(Vslab[i]);
  }
  for (int i = tid; i < NPAD*7; i += 256) abs_[i] = abg[i];
  __syncthreads();

  int lane = tid & 63, w = tid >> 6, quad = lane >> 4, cl = lane & 15;
  int nstripes = (w == 0) ? 4 : 3;
  for (int si = 0; si < nstripes; si++){
    int mi = w + si*4;          // 0..12
    // Q fragment: coalesced from slab (pre-scaled)
    bf16x8 aq = (bf16x8){0,0,0,0,0,0,0,0};
    {
      int n = mi*16 + cl; if (n > N_-1) n = N_-1;   // clamp pad row (never stored)
      if (quad < 2) aq = *(const bf16x8*)(Qslab + n*16 + quad*8);
    }
    // QK^T: S stripe [16 x 208] in registers
    f32x4 s[13];
    #pragma unroll
    for (int nj = 0; nj < 13; nj++){
      bf16x8 bk = (bf16x8){0,0,0,0,0,0,0,0};
      if (quad < 2) bk = *(const bf16x8*)(Ks + (nj*16 + cl)*KQ2 + quad*8);
      f32x4 z = {0.f,0.f,0.f,0.f};
      s[nj] = __builtin_amdgcn_mfma_f32_16x16x32_bf16(aq, bk, z, 0,0,0);
    }
    // mask + softmax per row; write fp16 P
    int row0 = mi*16 + quad*4;
    _Float16* Pw = Ps + w*16*KVH;
    #pragma unroll
    for (int r = 0; r < 4; r++){
      const u32* ab = abs_ + (row0 + r)*7;
      float mx = -3.4e38f;
      #pragma unroll
      for (int nj = 0; nj < 13; nj++){
        int cg = nj*16 + cl;
        float v = s[nj][r];
        if (nj == 12 && cl == 15) v = -3.4e38f;
        else if (!((ab[cg >> 5] >> (cg & 31)) & 1)) v = NEG_;
        s[nj][r] = v;
        mx = fmaxf(mx, v);
      }
      for (int off = 1; off < 16; off <<= 1) mx = fmaxf(mx, __shfl_xor(mx, off, 64));
      float sum = 0.0f;
      #pragma unroll
      for (int nj = 0; nj < 13; nj++){
        float e = __expf(s[nj][r] - mx);
        s[nj][r] = e; sum += e;
      }
      for (int off = 1; off < 16; off <<= 1) sum += __shfl_xor(sum, off, 64);
      float inv = 1.0f/sum;
      _Float16* Pr = Pw + (quad*4 + r)*KVH;
      #pragma unroll
      for (int nj = 0; nj < 13; nj++) Pr[nj*16 + cl] = (_Float16)(s[nj][r]*inv);
    }
    __threadfence_block();   // order P writes before same-wave PV reads
    // PV: O stripe [16 x 16], f16 MFMA chain
    f32x4 o = {0.f,0.f,0.f,0.f};
    #pragma unroll
    for (int kt = 0; kt < 7; kt++){
      f16x8 ap = *(const f16x8*)(Pw + cl*KVH + kt*32 + quad*8);
      f16x8 bv = *(const f16x8*)(Vt + cl*KVH + kt*32 + quad*8);
      o = __builtin_amdgcn_mfma_f32_16x16x32_f16(ap, bv, o, 0,0,0);
    }
    #pragma unroll
    for (int r = 0; r < 4; r++){
      int rg = row0 + r;
      if (rg < N_)
        ob[((size_t)((b*N_ + rg)*T_ + t))*D_ + hh*HD_ + cl] = f2b(o[r]);
    }
    __threadfence_block();   // order PV reads before next stripe's P writes
  }
}

// ---- temporal attention: one block (128 thr) per (b,n); qkv rows of 384 ----
__global__ void tattn_k(const bf16* qkv, bf16* ob){
  int bid = blockIdx.x; int b = bid / N_, n = bid % N_;
  __shared__ float qs[T_*D_];
  __shared__ float ks[T_*D_];
  __shared__ float vs[T_*D_];
  size_t rowb = ((size_t)(b*N_+n)*T_)*384;
  const u32* src = (const u32*)(qkv + rowb);
  for (int idx = threadIdx.x; idx < T_*192; idx += 128){
    int tt = idx / 192, cw = idx - tt*192;
    u32 pr = src[tt*192 + cw];
    union { u32 u; bf16 b[2]; } cv; cv.u = pr;
    float v0 = b2f(cv.b[0]), v1 = b2f(cv.b[1]);
    int arr = cw >> 6, cp2 = (cw & 63)*2;
    float* dst = (arr == 0) ? qs : (arr == 1) ? ks : vs;
    dst[tt*128 + cp2] = v0; dst[tt*128 + cp2 + 1] = v1;
  }
  __syncthreads();
  int p = threadIdx.x;
  if (p < H_*T_){
    int hh = p / T_, t = p - hh*T_;
    float qreg[16];
    for (int d = 0; d < 16; d++) qreg[d] = qs[t*128 + hh*16 + d];
    float sc[12]; float mx = -3.4e38f;
    for (int s = 0; s < 12; s++){
      float a = 0.0f;
      for (int d = 0; d < 16; d++) a += qreg[d]*ks[s*128 + hh*16 + d];
      a = (s <= t) ? a*SCALE_ : -3.4e38f;
      sc[s] = a; mx = fmaxf(mx, a);
    }
    float ssum = 0.0f;
    for (int s = 0; s < 12; s++){
      float e = (s <= t) ? __expf(sc[s]-mx) : 0.0f;
      sc[s] = e; ssum += e;
    }
    float inv = 1.0f/ssum;
    size_t obase = ((size_t)(b*N_+n)*T_ + t)*D_ + hh*16;
    for (int d = 0; d < 16; d++){
      float acc = 0.0f;
      for (int s = 0; s < 12; s++) acc += sc[s]*vs[s*128 + hh*16 + d];
      ob[obase + d] = f2b(acc*inv);
    }
  }
}

// ---- VALU GEMM kept for the small head GEMMs ----
__global__ void gemm_k(const bf16* A, int lda, const bf16* W, const bf16* bias,
                       void* outp, int ldo, int M, int Ncols, int K, int relu, int acc){
  __shared__ float Ast[16*68];
  __shared__ float Ws [16*68];
  int tx = threadIdx.x & 15, ty = threadIdx.x >> 4;
  int rowBase = blockIdx.y * 64, colBase = blockIdx.x * 64;
  float accr[4][4];
  for (int i = 0; i < 4; i++) for (int j = 0; j < 4; j++) accr[i][j] = 0.0f;
  for (int kk = 0; kk < K; kk += 16){
    int kq = threadIdx.x & 15, r0 = threadIdx.x >> 4;
    for (int it = 0; it < 4; it++){
      int r = r0 + it*16, row = rowBase + r;
      float v = 0.0f;
      if (row < M) v = b2f(A[(size_t)row*lda + kk + kq]);
      Ast[kq*68 + r] = v;
    }
    int c = threadIdx.x & 63, w0 = threadIdx.x >> 6;
    for (int it = 0; it < 4; it++){
      int kr = w0 + it*4;
      Ws[kr*68 + c] = b2f(W[(size_t)(kk+kr)*Ncols + colBase + c]);
    }
    __syncthreads();
    for (int k = 0; k < 16; k++){
      float av[4], wv[4];
      for (int i = 0; i < 4; i++) av[i] = Ast[k*68 + ty*4 + i];
      for (int j = 0; j < 4; j++) wv[j] = Ws[k*68 + tx*4 + j];
      for (int i = 0; i < 4; i++)
        for (int j = 0; j < 4; j++) accr[i][j] += av[i]*wv[j];
    }
    __syncthreads();
  }
  for (int i = 0; i < 4; i++){
    int row = rowBase + ty*4 + i;
    if (row >= M) continue;
    for (int j = 0; j < 4; j++){
      int col = colBase + tx*4 + j;
      float v = accr[i][j];
      if (bias) v += b2f(bias[col]);
      if (relu) v = fmaxf(v, 0.0f);
      if (acc) ((float*)outp)[(size_t)row*ldo + col] += v;
      else     ((bf16*)outp)[(size_t)row*ldo + col] = f2b(v);
    }
  }
}

__global__ void gather_k(const float* h, bf16* hlb){
  int i = blockIdx.x*256 + threadIdx.x;
  if (i >= ROWS2*D_) return;
  int r = i >> 7, d = i & 127;
  hlb[i] = f2b(h[((size_t)r*T_ + (T_-1))*D_ + d]);
}

__global__ void head3_k(const bf16* z2, const bf16* P3, const bf16* Pb3,
                        void* out, int out_n, const int* flag){
  int i = blockIdx.x*256 + threadIdx.x;
  if (i >= out_n) return;
  int r = i / PL_, j = i - r*PL_;
  float acc = b2f(Pb3[j]);
  for (int d = 0; d < 128; d++) acc += b2f(z2[(size_t)r*128 + d]) * b2f(P3[d*PL_ + j]);
  if (*flag) ((bf16*)out)[i] = f2b(acc);
  else       ((float*)out)[i] = acc;
}

extern "C" void kernel_launch(void* const* d_in, const int* in_sizes, int n_in,
                              void* d_out, int out_size, void* d_ws, size_t ws_size,
                              hipStream_t stream){
  // ws layout
  size_t HB = (size_t)TOK*D_*4;      // fp32 residual h
  size_t XB = (size_t)TOK*D_*2;      // bf16 xn
  size_t RB = (size_t)TOK*D_*8;      // bf16 sQ|sK|sV|ob (each TOK*128), aliases ffb/qkvb
  float* h    = (float*)d_ws;
  bf16*  xnb  = (bf16*)((char*)d_ws + HB);
  bf16*  reg_ = (bf16*)((char*)d_ws + HB + XB);
  bf16*  cvt  = (bf16*)((char*)d_ws + HB + XB + RB);
  bf16*  wsb  = (bf16*)d_ws;
  const int FIDX[34] = {0,2,3,4,5,6,7,8,9,10,11,12,13,14,15,16,17,18,19,20,
                        21,22,23,24,25,26,27,28,29,30,31,32,33,34};
  bf16* cp[34];
  size_t off = 0;
  for (int i = 0; i < 34; i++){ cp[i] = cvt + off; off += (size_t)in_sizes[FIDX[i]]; }
  char* tail   = (char*)d_ws + HB + XB + RB + ((off*2 + 255) & ~(size_t)255);
  u32*  abg    = (u32*)tail;                        // 208*7 u32
  bf16* qkvw   = (bf16*)(tail + 8192);              // packed QKV weights [L][384][128]
  int*  flag   = (int*)(tail + 8192 + (size_t)L_*384*128*2);

  const bf16 *x_c=cp[0], *Wi_c=cp[1], *bi_c=cp[2],
             *Wo_t=cp[6], *bo_c=cp[7], *sW1_t=cp[8], *sB1_c=cp[9], *sW2_t=cp[10], *sB2_c=cp[11],
             *sg1_c=cp[12], *sh1_c=cp[13], *sg2_c=cp[14], *sh2_c=cp[15], *Win_t=cp[16], *Bin_c=cp[17],
             *Wout_t=cp[18], *Bout_c=cp[19], *tW1_t=cp[20], *tB1_c=cp[21], *tW2_t=cp[22], *tB2_c=cp[23],
             *tg1_c=cp[24], *th1_c=cp[25], *tg2_c=cp[26], *th2_c=cp[27], *P1_c=cp[28], *Pb1_c=cp[29],
             *P2_c=cp[30], *Pb2_c=cp[31], *P3_c=cp[32], *Pb3_c=cp[33];
  const int* adj = (const int*)d_in[1];

  bf16* sQ   = reg_;                          // [3072][SLAB]
  bf16* sK   = reg_ + (size_t)TOK*128;
  bf16* sV   = reg_ + (size_t)2*TOK*128;
  bf16* ob   = reg_ + (size_t)3*TOK*128;      // [TOK][128]
  bf16* qkvb = reg_;                          // [TOK][384] (temporal; aliases sQ..sV)
  bf16* ffb  = reg_;                          // [TOK][512]

  detect_k<<<1, 256, 0, stream>>>(d_in[0], flag);

  // batched flat conversions
  {
    const int FLAT[24] = {0,1,2,7,9,11,12,13,14,15,17,19,21,23,24,25,26,27,28,29,30,31,32,33};
    FlatArgs fa; int c = 0;
    for (int ii = 0; ii < 24; ii++){
      int ci = FLAT[ii];
      fa.src[ii] = d_in[FIDX[ci]];
      fa.dst[ii] = (long long)(cp[ci] - wsb);
      fa.cum[ii] = c;
      c += in_sizes[FIDX[ci]];
    }
    fa.cum[24] = c;
    cvt_flat_k<<<(c+255)/256, 256, 0, stream>>>(fa, wsb, flag, c);
  }
  // batched transpose conversions (Wq pre-scaled by SCALE)
  {
    TArgs ta; int c = 0;
    const void* srcs[10] = {d_in[4], d_in[5], d_in[6], d_in[7], d_in[9], d_in[11],
                            d_in[17], d_in[19], d_in[21], d_in[23]};
    bf16* dsts[10] = {qkvw, qkvw, qkvw, cp[6], cp[8], cp[10], cp[16], cp[18], cp[20], cp[22]};
    int Ks_[10]   = {128,128,128, 128, 128, 512, 128, 128, 128, 512};
    int Ncs[10]   = {128,128,128, 128, 512, 128, 384, 128, 512, 128};
    int Lst[10]   = {384*128,384*128,384*128, 128*128, 128*512, 512*128, 128*384, 128*128, 128*512, 512*128};
    int ros[10]   = {0,128,256, 0,0,0, 0,0,0, 0};
    for (int j = 0; j < 10; j++){
      ta.src[j] = srcs[j];
      ta.dst[j] = (long long)(dsts[j] - wsb);
      ta.K[j] = Ks_[j]; ta.Nc[j] = Ncs[j]; ta.Lstr[j] = Lst[j]; ta.ro[j] = ros[j];
      ta.scale[j] = (j == 0) ? SCALE_ : 1.0f;
      ta.cum[j] = c;
      c += L_*Ks_[j]*Ncs[j];
    }
    ta.cum[10] = c;
    cvt_t_k<<<(c+255)/256, 256, 0, stream>>>(ta, wsb, flag, c);
  }
  abits_k<<<(NPAD*7+255)/256, 256, 0, stream>>>(adj, abg);
  embed_ln_k<<<TOK/4, 256, 0, stream>>>(x_c, Wi_c, bi_c, sg1_c, sh1_c, h, xnb);

  const dim3 gP  (1, TOK/128);
  const dim3 gF1 (4, TOK/128);
  const dim3 gQKV(3, TOK/128);

  for (int l = 0; l < L_; l++){
    // spatial attention
    mgemm_qkvT_k<<<gQKV, 256, 0, stream>>>(xnb, qkvw + (size_t)l*384*128, sQ, sK, sV);
    sattn_k<<<B_*T_*H_, 256, 0, stream>>>(sQ, sK, sV, abg, ob);
    mgemm_ln_k<<<gP, 256, 0, stream>>>(ob, Wo_t + (size_t)l*D_*D_, bo_c + l*D_, h, D_,
                                       sg2_c + l*D_, sh2_c + l*D_, xnb);
    // FFN 1
    mgemm_k<<<gF1, 256, 0, stream>>>(xnb, sW1_t + (size_t)l*D_*FF_, sB1_c + l*FF_, ffb, FF_, D_, 1);
    mgemm_ln_k<<<gP, 256, 0, stream>>>(ffb, sW2_t + (size_t)l*FF_*D_, sB2_c + l*D_, h, FF_,
                                       tg1_c + l*D_, th1_c + l*D_, xnb);
    // temporal attention
    mgemm_k<<<gQKV, 256, 0, stream>>>(xnb, Win_t + (size_t)l*D_*384, Bin_c + l*384, qkvb, 384, D_, 0);
    tattn_k<<<B_*N_, 128, 0, stream>>>(qkvb, ob);
    mgemm_ln_k<<<gP, 256, 0, stream>>>(ob, Wout_t + (size_t)l*D_*D_, Bout_c + l*D_, h, D_,
                                       tg2_c + l*D_, th2_c + l*D_, xnb);
    // FFN 2
    mgemm_k<<<gF1, 256, 0, stream>>>(xnb, tW1_t + (size_t)l*D_*FF_, tB1_c + l*FF_, ffb, FF_, D_, 1);
    const bf16* gnext = (l < L_-1) ? (sg1_c + (l+1)*D_) : nullptr;
    const bf16* bnext = (l < L_-1) ? (sh1_c + (l+1)*D_) : nullptr;
    mgemm_ln_k<<<gP, 256, 0, stream>>>(ffb, tW2_t + (size_t)l*FF_*D_, tB2_c + l*D_, h, FF_,
                                       gnext, bnext, xnb);
  }

  // head
  bf16* hlb = reg_;
  bf16* z1  = reg_ + (size_t)ROWS2*128;
  bf16* z2  = z1   + (size_t)ROWS2*256;
  gather_k<<<(ROWS2*D_)/256, 256, 0, stream>>>(h, hlb);
  gemm_k<<<dim3(256/64, (ROWS2+63)/64), 256, 0, stream>>>(hlb, 128, P1_c, Pb1_c, z1, 256, ROWS2, 256, 128, 1, 0);
  gemm_k<<<dim3(128/64, (ROWS2+63)/64), 256, 0, stream>>>(z1, 256, P2_c, Pb2_c, z2, 128, ROWS2, 128, 256, 1, 0);
  head3_k<<<(out_size+255)/256, 256, 0, stream>>>(z2, P3_c, Pb3_c, d_out, out_size, flag);
}

// Round 8
// 1731.760 us; speedup vs baseline: 4.6185x; 1.0112x over previous
//
#include <hip/hip_runtime.h>
#include <hip/hip_bf16.h>

#define B_   32
#define N_   207
#define T_   12
#define D_   128
#define H_   8
#define HD_  16
#define L_   4
#define FF_  512
#define PL_  12
#define TOK  (B_*N_*T_)      // 79488 = 621*128
#define ROWS2 (B_*N_)        // 6624
#define SCALE_ 0.25f
#define NEG_  -1e9f
#define NPAD 208             // 13*16
#define KQ2  24              // K LDS row stride (bf16): 16 data + 8 pad (quads>=2 predicated)
#define KVH  232             // Vt/P row stride (fp16): 0..206 data, 207..231 zero
#define SLAB 3312            // 207*16 elements per (b,t,h) slab
#define MSK_N (13*13*256)    // mask elements in C-frag layout

typedef __hip_bfloat16 bf16;
typedef unsigned int u32;
typedef __attribute__((ext_vector_type(8))) short bf16x8;     // 8 bf16 (MFMA A/B frag)
typedef __attribute__((ext_vector_type(8))) _Float16 f16x8;   // 8 fp16 (MFMA A/B frag)
typedef __attribute__((ext_vector_type(4))) float f32x4;      // MFMA C/D frag

__device__ __forceinline__ float b2f(bf16 x){ return __bfloat162float(x); }
__device__ __forceinline__ bf16  f2b(float x){ return __float2bfloat16(x); }

// async global->LDS 16B per lane (dest must be wave-uniform base + lane*16)
__device__ __forceinline__ void gll16(const bf16* g, bf16* l){
  __builtin_amdgcn_global_load_lds((const __attribute__((address_space(1))) void*)g,
                                   (__attribute__((address_space(3))) void*)l, 16, 0, 0);
}

// ---- dtype detection ----
__global__ void detect_k(const void* x, int* flag){
  __shared__ int cnt[256];
  const unsigned short* u = (const unsigned short*)x;
  int ok = 0;
  for (int i = threadIdx.x; i < 4096; i += 256){
    unsigned int bits = ((unsigned int)u[i]) << 16;
    float f = __uint_as_float(bits);
    float a = fabsf(f);
    if (f == 0.0f || (a > 1e-4f && a < 64.0f)) ok++;
  }
  cnt[threadIdx.x] = ok;
  __syncthreads();
  for (int s = 128; s > 0; s >>= 1){
    if (threadIdx.x < s) cnt[threadIdx.x] += cnt[threadIdx.x + s];
    __syncthreads();
  }
  if (threadIdx.x == 0) *flag = (cnt[0] > 3686) ? 1 : 0;
}

// ---- batched flat convert ----
struct FlatArgs {
  const void* src[24];
  long long dst[24];
  int cum[25];
};
__global__ void cvt_flat_k(FlatArgs a, bf16* base, const int* flag, int total){
  int i = blockIdx.x*256 + threadIdx.x;
  if (i >= total) return;
  int j = 0;
  while (i >= a.cum[j+1]) j++;
  int loc = i - a.cum[j];
  float v = (*flag) ? b2f(((const bf16*)a.src[j])[loc]) : ((const float*)a.src[j])[loc];
  base[a.dst[j] + loc] = f2b(v);
}

// ---- batched transpose convert (with per-segment scale) ----
struct TArgs {
  const void* src[10];
  long long dst[10];
  int K[10], Nc[10], Lstr[10], ro[10];
  float scale[10];
  int cum[11];
};
__global__ void cvt_t_k(TArgs a, bf16* base, const int* flag, int total){
  int i = blockIdx.x*256 + threadIdx.x;
  if (i >= total) return;
  int j = 0;
  while (i >= a.cum[j+1]) j++;
  int loc = i - a.cum[j];
  int KN = a.K[j]*a.Nc[j];
  int l = loc / KN; int rm = loc - l*KN; int k = rm / a.Nc[j]; int n = rm - k*a.Nc[j];
  float v = (*flag) ? b2f(((const bf16*)a.src[j])[loc]) : ((const float*)a.src[j])[loc];
  base[a.dst[j] + (long long)l*a.Lstr[j] + (long long)(a.ro[j]+n)*a.K[j] + k] = f2b(v*a.scale[j]);
}

// ---- additive mask in MFMA C-fragment layout: maskg[(mi*13+nj)*256 + lane*4 + r] ----
// row = mi*16 + (lane>>4)*4 + r (clamped to 206 for pad row), col = nj*16 + (lane&15)
// value: col>206 -> -1e30 ; adj[row][col]==0 -> -1e9 ; else 0
__global__ void maskc_k(const int* adj, float* maskg){
  int i = blockIdx.x*256 + threadIdx.x;
  if (i >= MSK_N) return;
  int cell = i >> 8;             // mi*13+nj
  int mi = cell / 13, nj = cell - mi*13;
  int rem = i & 255;
  int lane = rem >> 2, r = rem & 3;
  int quad = lane >> 4, cl = lane & 15;
  int row = mi*16 + quad*4 + r; if (row > 206) row = 206;
  int col = nj*16 + cl;
  float v;
  if (col > 206) v = -1e30f;
  else v = adj[row*N_ + col] ? 0.0f : NEG_;
  maskg[i] = v;
}

// ---- embed + fused LN (layer 0) ----
__global__ void embed_ln_k(const bf16* x, const bf16* Wi, const bf16* bi,
                           const bf16* g, const bf16* bta, float* h, bf16* xnb){
  int wave = threadIdx.x >> 6, lane = threadIdx.x & 63;
  int tok = blockIdx.x*4 + wave;
  if (tok >= TOK) return;
  float xv = b2f(x[tok]);
  float v0 = xv*b2f(Wi[lane])    + b2f(bi[lane]);
  float v1 = xv*b2f(Wi[lane+64]) + b2f(bi[lane+64]);
  float* hp = h + (size_t)tok*D_;
  hp[lane] = v0; hp[lane+64] = v1;
  float s = v0 + v1;
  for (int off = 32; off >= 1; off >>= 1) s += __shfl_xor(s, off, 64);
  float m = s * (1.0f/128.0f);
  float d0 = v0 - m, d1 = v1 - m;
  float vv = d0*d0 + d1*d1;
  for (int off = 32; off >= 1; off >>= 1) vv += __shfl_xor(vv, off, 64);
  float r = rsqrtf(vv*(1.0f/128.0f) + 1e-5f);
  bf16* op = xnb + (size_t)tok*D_;
  op[lane]    = f2b(d0*r*b2f(g[lane])    + b2f(bta[lane]));
  op[lane+64] = f2b(d1*r*b2f(g[lane+64]) + b2f(bta[lane+64]));
}

// ---- MFMA GEMM (non-acc), global_load_lds staging ----
__global__ __launch_bounds__(256) void mgemm_k(const bf16* __restrict__ A,
    const bf16* __restrict__ Wt, const bf16* __restrict__ bias,
    bf16* __restrict__ outp, int ldo, int Ktot, int relu){
  __shared__ __align__(16) bf16 As[128*32];
  __shared__ __align__(16) bf16 Bs[128*32];
  int tid = threadIdx.x;
  int rowBase = blockIdx.y * 128, colBase = blockIdx.x * 128;
  int w = tid >> 6, lane = tid & 63, quad = lane >> 4, cl = lane & 15;
  int waveM = w >> 1, waveN = w & 1;
  f32x4 accr[4][4];
  #pragma unroll
  for (int i = 0; i < 4; i++)
    #pragma unroll
    for (int j = 0; j < 4; j++) accr[i][j] = (f32x4){0.f,0.f,0.f,0.f};
  int lr = tid >> 2, kc = tid & 3;
  const bf16* Ap = A  + (size_t)(rowBase + lr)*Ktot + kc*8;
  const bf16* Bp = Wt + (size_t)(colBase + lr)*Ktot + kc*8;
  bf16* AsW = As + tid*8;
  bf16* BsW = Bs + tid*8;
  for (int kk = 0; kk < Ktot; kk += 32){
    __syncthreads();
    gll16(Ap + kk, AsW);
    gll16(Ap + (size_t)64*Ktot + kk, AsW + 64*32);
    gll16(Bp + kk, BsW);
    gll16(Bp + (size_t)64*Ktot + kk, BsW + 64*32);
    __syncthreads();
    bf16x8 af[4], bfr[4];
    #pragma unroll
    for (int mi = 0; mi < 4; mi++)
      af[mi] = *(const bf16x8*)(As + (waveM*64 + mi*16 + cl)*32 + quad*8);
    #pragma unroll
    for (int nj = 0; nj < 4; nj++)
      bfr[nj] = *(const bf16x8*)(Bs + (waveN*64 + nj*16 + cl)*32 + quad*8);
    #pragma unroll
    for (int mi = 0; mi < 4; mi++)
      #pragma unroll
      for (int nj = 0; nj < 4; nj++)
        accr[mi][nj] = __builtin_amdgcn_mfma_f32_16x16x32_bf16(af[mi], bfr[nj], accr[mi][nj], 0,0,0);
  }
  float bv[4];
  #pragma unroll
  for (int nj = 0; nj < 4; nj++)
    bv[nj] = bias ? b2f(bias[colBase + waveN*64 + nj*16 + cl]) : 0.0f;
  #pragma unroll
  for (int mi = 0; mi < 4; mi++){
    int row0 = rowBase + waveM*64 + mi*16 + quad*4;
    #pragma unroll
    for (int nj = 0; nj < 4; nj++){
      int col = colBase + waveN*64 + nj*16 + cl;
      #pragma unroll
      for (int r = 0; r < 4; r++){
        float v = accr[mi][nj][r] + bv[nj];
        if (relu) v = fmaxf(v, 0.0f);
        outp[(size_t)(row0+r)*ldo + col] = f2b(v);
      }
    }
  }
}

// ---- MFMA GEMM writing spatial q/k/v in [slab=(b,t,h)][n][16] layout ----
__global__ __launch_bounds__(256) void mgemm_qkvT_k(const bf16* __restrict__ A,
    const bf16* __restrict__ Wt, bf16* __restrict__ sQ,
    bf16* __restrict__ sK, bf16* __restrict__ sV){
  __shared__ __align__(16) bf16 As[128*32];
  __shared__ __align__(16) bf16 Bs[128*32];
  const int Ktot = 128;
  int tid = threadIdx.x;
  int rowBase = blockIdx.y * 128, colBase = blockIdx.x * 128;
  int w = tid >> 6, lane = tid & 63, quad = lane >> 4, cl = lane & 15;
  int waveM = w >> 1, waveN = w & 1;
  f32x4 accr[4][4];
  #pragma unroll
  for (int i = 0; i < 4; i++)
    #pragma unroll
    for (int j = 0; j < 4; j++) accr[i][j] = (f32x4){0.f,0.f,0.f,0.f};
  int lr = tid >> 2, kc = tid & 3;
  const bf16* Ap = A  + (size_t)(rowBase + lr)*Ktot + kc*8;
  const bf16* Bp = Wt + (size_t)(colBase + lr)*Ktot + kc*8;
  bf16* AsW = As + tid*8;
  bf16* BsW = Bs + tid*8;
  for (int kk = 0; kk < Ktot; kk += 32){
    __syncthreads();
    gll16(Ap + kk, AsW);
    gll16(Ap + (size_t)64*Ktot + kk, AsW + 64*32);
    gll16(Bp + kk, BsW);
    gll16(Bp + (size_t)64*Ktot + kk, BsW + 64*32);
    __syncthreads();
    bf16x8 af[4], bfr[4];
    #pragma unroll
    for (int mi = 0; mi < 4; mi++)
      af[mi] = *(const bf16x8*)(As + (waveM*64 + mi*16 + cl)*32 + quad*8);
    #pragma unroll
    for (int nj = 0; nj < 4; nj++)
      bfr[nj] = *(const bf16x8*)(Bs + (waveN*64 + nj*16 + cl)*32 + quad*8);
    #pragma unroll
    for (int mi = 0; mi < 4; mi++)
      #pragma unroll
      for (int nj = 0; nj < 4; nj++)
        accr[mi][nj] = __builtin_amdgcn_mfma_f32_16x16x32_bf16(af[mi], bfr[nj], accr[mi][nj], 0,0,0);
  }
  #pragma unroll
  for (int mi = 0; mi < 4; mi++){
    #pragma unroll
    for (int r = 0; r < 4; r++){
      int tok = rowBase + waveM*64 + mi*16 + quad*4 + r;
      int bn = tok / T_; int t = tok - bn*T_;
      int b = bn / N_;  int n = bn - b*N_;
      size_t base = ((size_t)(b*T_ + t)*H_)*SLAB + n*16 + cl;
      #pragma unroll
      for (int nj = 0; nj < 4; nj++){
        int col = colBase + waveN*64 + nj*16;
        int part = col >> 7, hh = (col >> 4) & 7;
        bf16* dst = (part == 0) ? sQ : (part == 1) ? sK : sV;
        dst[base + (size_t)hh*SLAB] = f2b(accr[mi][nj][r]);
      }
    }
  }
}

// ---- MFMA GEMM + residual-acc + fused LayerNorm (N=128, grid.x=1) ----
__global__ __launch_bounds__(256) void mgemm_ln_k(const bf16* __restrict__ A,
    const bf16* __restrict__ Wt, const bf16* __restrict__ bias,
    float* __restrict__ hout, int Ktot,
    const bf16* __restrict__ g, const bf16* __restrict__ bta,
    bf16* __restrict__ xnb){
  __shared__ __align__(16) bf16 As[128*32];
  __shared__ __align__(16) bf16 Bs[128*32];
  __shared__ float red[2][128][2];
  int tid = threadIdx.x;
  int rowBase = blockIdx.y * 128;
  int w = tid >> 6, lane = tid & 63, quad = lane >> 4, cl = lane & 15;
  int waveM = w >> 1, waveN = w & 1;
  f32x4 accr[4][4];
  #pragma unroll
  for (int i = 0; i < 4; i++)
    #pragma unroll
    for (int j = 0; j < 4; j++) accr[i][j] = (f32x4){0.f,0.f,0.f,0.f};
  int lr = tid >> 2, kc = tid & 3;
  const bf16* Ap = A  + (size_t)(rowBase + lr)*Ktot + kc*8;
  const bf16* Bp = Wt + (size_t)lr*Ktot + kc*8;
  bf16* AsW = As + tid*8;
  bf16* BsW = Bs + tid*8;
  for (int kk = 0; kk < Ktot; kk += 32){
    __syncthreads();
    gll16(Ap + kk, AsW);
    gll16(Ap + (size_t)64*Ktot + kk, AsW + 64*32);
    gll16(Bp + kk, BsW);
    gll16(Bp + (size_t)64*Ktot + kk, BsW + 64*32);
    __syncthreads();
    bf16x8 af[4], bfr[4];
    #pragma unroll
    for (int mi = 0; mi < 4; mi++)
      af[mi] = *(const bf16x8*)(As + (waveM*64 + mi*16 + cl)*32 + quad*8);
    #pragma unroll
    for (int nj = 0; nj < 4; nj++)
      bfr[nj] = *(const bf16x8*)(Bs + (waveN*64 + nj*16 + cl)*32 + quad*8);
    #pragma unroll
    for (int mi = 0; mi < 4; mi++)
      #pragma unroll
      for (int nj = 0; nj < 4; nj++)
        accr[mi][nj] = __builtin_amdgcn_mfma_f32_16x16x32_bf16(af[mi], bfr[nj], accr[mi][nj], 0,0,0);
  }
  int colW = waveN*64;
  float bv[4];
  #pragma unroll
  for (int nj = 0; nj < 4; nj++)
    bv[nj] = bias ? b2f(bias[colW + nj*16 + cl]) : 0.0f;
  float hv[4][4][4];
  float psum[4][4], psq[4][4];
  #pragma unroll
  for (int mi = 0; mi < 4; mi++)
    #pragma unroll
    for (int r = 0; r < 4; r++){ psum[mi][r] = 0.f; psq[mi][r] = 0.f; }
  #pragma unroll
  for (int mi = 0; mi < 4; mi++){
    #pragma unroll
    for (int r = 0; r < 4; r++){
      int row = rowBase + waveM*64 + mi*16 + quad*4 + r;
      #pragma unroll
      for (int nj = 0; nj < 4; nj++){
        int col = colW + nj*16 + cl;
        size_t idx = (size_t)row*D_ + col;
        float v = hout[idx] + accr[mi][nj][r] + bv[nj];
        hout[idx] = v;
        hv[mi][nj][r] = v;
        psum[mi][r] += v; psq[mi][r] += v*v;
      }
    }
  }
  if (g){
    #pragma unroll
    for (int off = 1; off <= 8; off <<= 1)
      #pragma unroll
      for (int mi = 0; mi < 4; mi++)
        #pragma unroll
        for (int r = 0; r < 4; r++){
          psum[mi][r] += __shfl_xor(psum[mi][r], off, 64);
          psq[mi][r]  += __shfl_xor(psq[mi][r],  off, 64);
        }
    if (cl == 0){
      #pragma unroll
      for (int mi = 0; mi < 4; mi++)
        #pragma unroll
        for (int r = 0; r < 4; r++){
          int rl = waveM*64 + mi*16 + quad*4 + r;
          red[waveN][rl][0] = psum[mi][r];
          red[waveN][rl][1] = psq[mi][r];
        }
    }
    __syncthreads();
    float gv[4], btv[4];
    #pragma unroll
    for (int nj = 0; nj < 4; nj++){
      int col = colW + nj*16 + cl;
      gv[nj] = b2f(g[col]); btv[nj] = b2f(bta[col]);
    }
    #pragma unroll
    for (int mi = 0; mi < 4; mi++){
      #pragma unroll
      for (int r = 0; r < 4; r++){
        int rl = waveM*64 + mi*16 + quad*4 + r;
        float s = red[0][rl][0] + red[1][rl][0];
        float q = red[0][rl][1] + red[1][rl][1];
        float mean = s*(1.0f/128.0f);
        float var  = q*(1.0f/128.0f) - mean*mean;
        float rstd = rsqrtf(var + 1e-5f);
        int row = rowBase + rl;
        #pragma unroll
        for (int nj = 0; nj < 4; nj++){
          int col = colW + nj*16 + cl;
          xnb[(size_t)row*D_ + col] = f2b((hv[mi][nj][r]-mean)*rstd*gv[nj] + btv[nj]);
        }
      }
    }
  }
}

// ---- MFMA spatial attention: mask via MFMA C-operand, no-max softmax, ----
// ---- unnormalized fp16 P, inv applied to O. LDS 47KB -> 3 blocks/CU. ----
__global__ __launch_bounds__(256,3) void sattn_k(const bf16* __restrict__ sQ,
    const bf16* __restrict__ sK, const bf16* __restrict__ sV,
    const float* __restrict__ maskg, bf16* __restrict__ ob){
  __shared__ __align__(16) bf16     Ks[NPAD*KQ2];   // 9984 B
  __shared__ __align__(16) _Float16 Vt[16*KVH];     // 7424 B
  __shared__ __align__(16) _Float16 Ps[4*16*KVH];   // 29696 B
  int tid = threadIdx.x;
  int bid = blockIdx.x;                // slab = (b*T+t)*H + hh
  int hh = bid & 7; int bt = bid >> 3; int t = bt % T_; int b = bt / T_;
  const bf16* Kslab = sK + (size_t)bid*SLAB;
  const bf16* Vslab = sV + (size_t)bid*SLAB;
  const bf16* Qslab = sQ + (size_t)bid*SLAB;
  // zero pad columns (read but never written)
  for (int i = tid; i < 16*25; i += 256){ int d = i/25, c = 207 + i%25; Vt[d*KVH + c] = (_Float16)0.0f; }
  for (int i = tid; i < 64*24; i += 256){ int row = i/24, c = 208 + i%24; Ps[row*KVH + c] = (_Float16)0.0f; }
  // stage K: 414 contiguous b128 chunks -> [n][d] rows (stride KQ2)
  for (int c = tid; c < 414; c += 256){
    bf16x8 kv = *(const bf16x8*)(Kslab + c*8);
    int n = c >> 1, dh = (c & 1)*8;
    *(bf16x8*)(Ks + n*KQ2 + dh) = kv;
  }
  // stage V transposed to [d][n] fp16
  for (int i = tid; i < SLAB; i += 256){
    int n = i >> 4, d = i & 15;
    Vt[d*KVH + n] = (_Float16)b2f(Vslab[i]);
  }
  __syncthreads();

  int lane = tid & 63, w = tid >> 6, quad = lane >> 4, cl = lane & 15;
  int nstripes = (w == 0) ? 4 : 3;
  for (int si = 0; si < nstripes; si++){
    int mi = w + si*4;          // 0..12
    // Q fragment: coalesced from slab (pre-scaled by SCALE via Wq)
    bf16x8 aq = (bf16x8){0,0,0,0,0,0,0,0};
    {
      int n = mi*16 + cl; if (n > N_-1) n = N_-1;   // clamp pad row (never stored)
      if (quad < 2) aq = *(const bf16x8*)(Qslab + n*16 + quad*8);
    }
    // QK^T with additive mask as the MFMA C operand
    const float* mrow = maskg + ((size_t)mi*13)*256 + lane*4;
    f32x4 s[13];
    #pragma unroll
    for (int nj = 0; nj < 13; nj++){
      bf16x8 bk = (bf16x8){0,0,0,0,0,0,0,0};
      if (quad < 2) bk = *(const bf16x8*)(Ks + (nj*16 + cl)*KQ2 + quad*8);
      f32x4 c0 = *(const f32x4*)(mrow + nj*256);
      s[nj] = __builtin_amdgcn_mfma_f32_16x16x32_bf16(aq, bk, c0, 0,0,0);
    }
    // softmax (scores tiny by construction -> no max subtraction);
    // P stored unnormalized fp16, 1/sum applied to O.
    int row0 = mi*16 + quad*4;
    _Float16* Pw = Ps + w*16*KVH;
    float invr[4];
    #pragma unroll
    for (int r = 0; r < 4; r++){
      float sum = 0.0f;
      #pragma unroll
      for (int nj = 0; nj < 13; nj++){
        float e = __expf(s[nj][r]);
        s[nj][r] = e; sum += e;
      }
      for (int off = 1; off < 16; off <<= 1) sum += __shfl_xor(sum, off, 64);
      invr[r] = 1.0f/sum;
      _Float16* Pr = Pw + (quad*4 + r)*KVH;
      #pragma unroll
      for (int nj = 0; nj < 13; nj++) Pr[nj*16 + cl] = (_Float16)s[nj][r];
    }
    __threadfence_block();   // order P writes before same-wave PV reads
    // PV: O stripe [16 x 16], f16 MFMA chain
    f32x4 o = {0.f,0.f,0.f,0.f};
    #pragma unroll
    for (int kt = 0; kt < 7; kt++){
      f16x8 ap = *(const f16x8*)(Pw + cl*KVH + kt*32 + quad*8);
      f16x8 bv = *(const f16x8*)(Vt + cl*KVH + kt*32 + quad*8);
      o = __builtin_amdgcn_mfma_f32_16x16x32_f16(ap, bv, o, 0,0,0);
    }
    #pragma unroll
    for (int r = 0; r < 4; r++){
      int rg = row0 + r;
      if (rg < N_)
        ob[((size_t)((b*N_ + rg)*T_ + t))*D_ + hh*HD_ + cl] = f2b(o[r]*invr[r]);
    }
    __threadfence_block();   // order PV reads before next stripe's P writes
  }
}

// ---- temporal attention: one block (128 thr) per (b,n); qkv rows of 384 ----
__global__ void tattn_k(const bf16* qkv, bf16* ob){
  int bid = blockIdx.x; int b = bid / N_, n = bid % N_;
  __shared__ float qs[T_*D_];
  __shared__ float ks[T_*D_];
  __shared__ float vs[T_*D_];
  size_t rowb = ((size_t)(b*N_+n)*T_)*384;
  const u32* src = (const u32*)(qkv + rowb);
  for (int idx = threadIdx.x; idx < T_*192; idx += 128){
    int tt = idx / 192, cw = idx - tt*192;
    u32 pr = src[tt*192 + cw];
    union { u32 u; bf16 b[2]; } cv; cv.u = pr;
    float v0 = b2f(cv.b[0]), v1 = b2f(cv.b[1]);
    int arr = cw >> 6, cp2 = (cw & 63)*2;
    float* dst = (arr == 0) ? qs : (arr == 1) ? ks : vs;
    dst[tt*128 + cp2] = v0; dst[tt*128 + cp2 + 1] = v1;
  }
  __syncthreads();
  int p = threadIdx.x;
  if (p < H_*T_){
    int hh = p / T_, t = p - hh*T_;
    float qreg[16];
    for (int d = 0; d < 16; d++) qreg[d] = qs[t*128 + hh*16 + d];
    float sc[12]; float mx = -3.4e38f;
    for (int s = 0; s < 12; s++){
      float a = 0.0f;
      for (int d = 0; d < 16; d++) a += qreg[d]*ks[s*128 + hh*16 + d];
      a = (s <= t) ? a*SCALE_ : -3.4e38f;
      sc[s] = a; mx = fmaxf(mx, a);
    }
    float ssum = 0.0f;
    for (int s = 0; s < 12; s++){
      float e = (s <= t) ? __expf(sc[s]-mx) : 0.0f;
      sc[s] = e; ssum += e;
    }
    float inv = 1.0f/ssum;
    size_t obase = ((size_t)(b*N_+n)*T_ + t)*D_ + hh*16;
    for (int d = 0; d < 16; d++){
      float acc = 0.0f;
      for (int s = 0; s < 12; s++) acc += sc[s]*vs[s*128 + hh*16 + d];
      ob[obase + d] = f2b(acc*inv);
    }
  }
}

// ---- VALU GEMM kept for the small head GEMMs ----
__global__ void gemm_k(const bf16* A, int lda, const bf16* W, const bf16* bias,
                       void* outp, int ldo, int M, int Ncols, int K, int relu, int acc){
  __shared__ float Ast[16*68];
  __shared__ float Ws [16*68];
  int tx = threadIdx.x & 15, ty = threadIdx.x >> 4;
  int rowBase = blockIdx.y * 64, colBase = blockIdx.x * 64;
  float accr[4][4];
  for (int i = 0; i < 4; i++) for (int j = 0; j < 4; j++) accr[i][j] = 0.0f;
  for (int kk = 0; kk < K; kk += 16){
    int kq = threadIdx.x & 15, r0 = threadIdx.x >> 4;
    for (int it = 0; it < 4; it++){
      int r = r0 + it*16, row = rowBase + r;
      float v = 0.0f;
      if (row < M) v = b2f(A[(size_t)row*lda + kk + kq]);
      Ast[kq*68 + r] = v;
    }
    int c = threadIdx.x & 63, w0 = threadIdx.x >> 6;
    for (int it = 0; it < 4; it++){
      int kr = w0 + it*4;
      Ws[kr*68 + c] = b2f(W[(size_t)(kk+kr)*Ncols + colBase + c]);
    }
    __syncthreads();
    for (int k = 0; k < 16; k++){
      float av[4], wv[4];
      for (int i = 0; i < 4; i++) av[i] = Ast[k*68 + ty*4 + i];
      for (int j = 0; j < 4; j++) wv[j] = Ws[k*68 + tx*4 + j];
      for (int i = 0; i < 4; i++)
        for (int j = 0; j < 4; j++) accr[i][j] += av[i]*wv[j];
    }
    __syncthreads();
  }
  for (int i = 0; i < 4; i++){
    int row = rowBase + ty*4 + i;
    if (row >= M) continue;
    for (int j = 0; j < 4; j++){
      int col = colBase + tx*4 + j;
      float v = accr[i][j];
      if (bias) v += b2f(bias[col]);
      if (relu) v = fmaxf(v, 0.0f);
      if (acc) ((float*)outp)[(size_t)row*ldo + col] += v;
      else     ((bf16*)outp)[(size_t)row*ldo + col] = f2b(v);
    }
  }
}

__global__ void gather_k(const float* h, bf16* hlb){
  int i = blockIdx.x*256 + threadIdx.x;
  if (i >= ROWS2*D_) return;
  int r = i >> 7, d = i & 127;
  hlb[i] = f2b(h[((size_t)r*T_ + (T_-1))*D_ + d]);
}

__global__ void head3_k(const bf16* z2, const bf16* P3, const bf16* Pb3,
                        void* out, int out_n, const int* flag){
  int i = blockIdx.x*256 + threadIdx.x;
  if (i >= out_n) return;
  int r = i / PL_, j = i - r*PL_;
  float acc = b2f(Pb3[j]);
  for (int d = 0; d < 128; d++) acc += b2f(z2[(size_t)r*128 + d]) * b2f(P3[d*PL_ + j]);
  if (*flag) ((bf16*)out)[i] = f2b(acc);
  else       ((float*)out)[i] = acc;
}

extern "C" void kernel_launch(void* const* d_in, const int* in_sizes, int n_in,
                              void* d_out, int out_size, void* d_ws, size_t ws_size,
                              hipStream_t stream){
  // ws layout
  size_t HB = (size_t)TOK*D_*4;      // fp32 residual h
  size_t XB = (size_t)TOK*D_*2;      // bf16 xn
  size_t RB = (size_t)TOK*D_*8;      // bf16 sQ|sK|sV|ob, aliases ffb/qkvb
  float* h    = (float*)d_ws;
  bf16*  xnb  = (bf16*)((char*)d_ws + HB);
  bf16*  reg_ = (bf16*)((char*)d_ws + HB + XB);
  bf16*  cvt  = (bf16*)((char*)d_ws + HB + XB + RB);
  bf16*  wsb  = (bf16*)d_ws;
  const int FIDX[34] = {0,2,3,4,5,6,7,8,9,10,11,12,13,14,15,16,17,18,19,20,
                        21,22,23,24,25,26,27,28,29,30,31,32,33,34};
  bf16* cp[34];
  size_t off = 0;
  for (int i = 0; i < 34; i++){ cp[i] = cvt + off; off += (size_t)in_sizes[FIDX[i]]; }
  char* tail   = (char*)d_ws + HB + XB + RB + ((off*2 + 255) & ~(size_t)255);
  float* maskg = (float*)tail;                       // MSK_N f32 (C-frag layout)
  bf16* qkvw   = (bf16*)(tail + (size_t)MSK_N*4);    // packed QKV weights [L][384][128]
  int*  flag   = (int*)(tail + (size_t)MSK_N*4 + (size_t)L_*384*128*2);

  const bf16 *x_c=cp[0], *Wi_c=cp[1], *bi_c=cp[2],
             *Wo_t=cp[6], *bo_c=cp[7], *sW1_t=cp[8], *sB1_c=cp[9], *sW2_t=cp[10], *sB2_c=cp[11],
             *sg1_c=cp[12], *sh1_c=cp[13], *sg2_c=cp[14], *sh2_c=cp[15], *Win_t=cp[16], *Bin_c=cp[17],
             *Wout_t=cp[18], *Bout_c=cp[19], *tW1_t=cp[20], *tB1_c=cp[21], *tW2_t=cp[22], *tB2_c=cp[23],
             *tg1_c=cp[24], *th1_c=cp[25], *tg2_c=cp[26], *th2_c=cp[27], *P1_c=cp[28], *Pb1_c=cp[29],
             *P2_c=cp[30], *Pb2_c=cp[31], *P3_c=cp[32], *Pb3_c=cp[33];
  const int* adj = (const int*)d_in[1];

  bf16* sQ   = reg_;                          // [3072][SLAB]
  bf16* sK   = reg_ + (size_t)TOK*128;
  bf16* sV   = reg_ + (size_t)2*TOK*128;
  bf16* ob   = reg_ + (size_t)3*TOK*128;      // [TOK][128]
  bf16* qkvb = reg_;                          // [TOK][384] (temporal; aliases sQ..sV)
  bf16* ffb  = reg_;                          // [TOK][512]

  detect_k<<<1, 256, 0, stream>>>(d_in[0], flag);

  // batched flat conversions
  {
    const int FLAT[24] = {0,1,2,7,9,11,12,13,14,15,17,19,21,23,24,25,26,27,28,29,30,31,32,33};
    FlatArgs fa; int c = 0;
    for (int ii = 0; ii < 24; ii++){
      int ci = FLAT[ii];
      fa.src[ii] = d_in[FIDX[ci]];
      fa.dst[ii] = (long long)(cp[ci] - wsb);
      fa.cum[ii] = c;
      c += in_sizes[FIDX[ci]];
    }
    fa.cum[24] = c;
    cvt_flat_k<<<(c+255)/256, 256, 0, stream>>>(fa, wsb, flag, c);
  }
  // batched transpose conversions (Wq pre-scaled by SCALE)
  {
    TArgs ta; int c = 0;
    const void* srcs[10] = {d_in[4], d_in[5], d_in[6], d_in[7], d_in[9], d_in[11],
                            d_in[17], d_in[19], d_in[21], d_in[23]};
    bf16* dsts[10] = {qkvw, qkvw, qkvw, cp[6], cp[8], cp[10], cp[16], cp[18], cp[20], cp[22]};
    int Ks_[10]   = {128,128,128, 128, 128, 512, 128, 128, 128, 512};
    int Ncs[10]   = {128,128,128, 128, 512, 128, 384, 128, 512, 128};
    int Lst[10]   = {384*128,384*128,384*128, 128*128, 128*512, 512*128, 128*384, 128*128, 128*512, 512*128};
    int ros[10]   = {0,128,256, 0,0,0, 0,0,0, 0};
    for (int j = 0; j < 10; j++){
      ta.src[j] = srcs[j];
      ta.dst[j] = (long long)(dsts[j] - wsb);
      ta.K[j] = Ks_[j]; ta.Nc[j] = Ncs[j]; ta.Lstr[j] = Lst[j]; ta.ro[j] = ros[j];
      ta.scale[j] = (j == 0) ? SCALE_ : 1.0f;
      ta.cum[j] = c;
      c += L_*Ks_[j]*Ncs[j];
    }
    ta.cum[10] = c;
    cvt_t_k<<<(c+255)/256, 256, 0, stream>>>(ta, wsb, flag, c);
  }
  maskc_k<<<(MSK_N+255)/256, 256, 0, stream>>>(adj, maskg);
  embed_ln_k<<<TOK/4, 256, 0, stream>>>(x_c, Wi_c, bi_c, sg1_c, sh1_c, h, xnb);

  const dim3 gP  (1, TOK/128);
  const dim3 gF1 (4, TOK/128);
  const dim3 gQKV(3, TOK/128);

  for (int l = 0; l < L_; l++){
    // spatial attention
    mgemm_qkvT_k<<<gQKV, 256, 0, stream>>>(xnb, qkvw + (size_t)l*384*128, sQ, sK, sV);
    sattn_k<<<B_*T_*H_, 256, 0, stream>>>(sQ, sK, sV, maskg, ob);
    mgemm_ln_k<<<gP, 256, 0, stream>>>(ob, Wo_t + (size_t)l*D_*D_, bo_c + l*D_, h, D_,
                                       sg2_c + l*D_, sh2_c + l*D_, xnb);
    // FFN 1
    mgemm_k<<<gF1, 256, 0, stream>>>(xnb, sW1_t + (size_t)l*D_*FF_, sB1_c + l*FF_, ffb, FF_, D_, 1);
    mgemm_ln_k<<<gP, 256, 0, stream>>>(ffb, sW2_t + (size_t)l*FF_*D_, sB2_c + l*D_, h, FF_,
                                       tg1_c + l*D_, th1_c + l*D_, xnb);
    // temporal attention
    mgemm_k<<<gQKV, 256, 0, stream>>>(xnb, Win_t + (size_t)l*D_*384, Bin_c + l*384, qkvb, 384, D_, 0);
    tattn_k<<<B_*N_, 128, 0, stream>>>(qkvb, ob);
    mgemm_ln_k<<<gP, 256, 0, stream>>>(ob, Wout_t + (size_t)l*D_*D_, Bout_c + l*D_, h, D_,
                                       tg2_c + l*D_, th2_c + l*D_, xnb);
    // FFN 2
    mgemm_k<<<gF1, 256, 0, stream>>>(xnb, tW1_t + (size_t)l*D_*FF_, tB1_c + l*FF_, ffb, FF_, D_, 1);
    const bf16* gnext = (l < L_-1) ? (sg1_c + (l+1)*D_) : nullptr;
    const bf16* bnext = (l < L_-1) ? (sh1_c + (l+1)*D_) : nullptr;
    mgemm_ln_k<<<gP, 256, 0, stream>>>(ffb, tW2_t + (size_t)l*FF_*D_, tB2_c + l*D_, h, FF_,
                                       gnext, bnext, xnb);
  }

  // head
  bf16* hlb = reg_;
  bf16* z1  = reg_ + (size_t)ROWS2*128;
  bf16* z2  = z1   + (size_t)ROWS2*256;
  gather_k<<<(ROWS2*D_)/256, 256, 0, stream>>>(h, hlb);
  gemm_k<<<dim3(256/64, (ROWS2+63)/64), 256, 0, stream>>>(hlb, 128, P1_c, Pb1_c, z1, 256, ROWS2, 256, 128, 1, 0);
  gemm_k<<<dim3(128/64, (ROWS2+63)/64), 256, 0, stream>>>(z1, 256, P2_c, Pb2_c, z2, 128, ROWS2, 128, 256, 1, 0);
  head3_k<<<(out_size+255)/256, 256, 0, stream>>>(z2, P3_c, Pb3_c, d_out, out_size, flag);
}

// Round 9
// 1619.125 us; speedup vs baseline: 4.9398x; 1.0696x over previous
//
#include <hip/hip_runtime.h>
#include <hip/hip_bf16.h>

#define B_   32
#define N_   207
#define T_   12
#define D_   128
#define H_   8
#define HD_  16
#define L_   4
#define FF_  512
#define PL_  12
#define TOK  (B_*N_*T_)      // 79488 = 621*128
#define ROWS2 (B_*N_)        // 6624
#define SCALE_ 0.25f
#define NEG_  -1e9f
#define NPAD 208             // 13*16
#define KQ2  24              // K LDS row stride (bf16)
#define KVH  232             // Vt/P row stride (fp16)
#define SLAB 3312            // 207*16 elements per (b,t,h) slab
#define MSK_N (13*13*256)    // mask elements in C-frag layout

typedef __hip_bfloat16 bf16;
typedef unsigned int u32;
typedef __attribute__((ext_vector_type(4))) unsigned int u32x4;
typedef __attribute__((ext_vector_type(8))) short bf16x8;     // 8 bf16 (MFMA A/B frag)
typedef __attribute__((ext_vector_type(8))) _Float16 f16x8;   // 8 fp16 (MFMA A/B frag)
typedef __attribute__((ext_vector_type(4))) float f32x4;      // MFMA C/D frag

__device__ __forceinline__ float b2f(bf16 x){ return __bfloat162float(x); }
__device__ __forceinline__ bf16  f2b(float x){ return __float2bfloat16(x); }

// async global->LDS 16B per lane (dest must be wave-uniform base + lane*16)
__device__ __forceinline__ void gll16(const bf16* g, bf16* l){
  __builtin_amdgcn_global_load_lds((const __attribute__((address_space(1))) void*)g,
                                   (__attribute__((address_space(3))) void*)l, 16, 0, 0);
}

// ---- dtype detection ----
__global__ void detect_k(const void* x, int* flag){
  __shared__ int cnt[256];
  const unsigned short* u = (const unsigned short*)x;
  int ok = 0;
  for (int i = threadIdx.x; i < 4096; i += 256){
    unsigned int bits = ((unsigned int)u[i]) << 16;
    float f = __uint_as_float(bits);
    float a = fabsf(f);
    if (f == 0.0f || (a > 1e-4f && a < 64.0f)) ok++;
  }
  cnt[threadIdx.x] = ok;
  __syncthreads();
  for (int s = 128; s > 0; s >>= 1){
    if (threadIdx.x < s) cnt[threadIdx.x] += cnt[threadIdx.x + s];
    __syncthreads();
  }
  if (threadIdx.x == 0) *flag = (cnt[0] > 3686) ? 1 : 0;
}

// ---- batched flat convert ----
struct FlatArgs {
  const void* src[24];
  long long dst[24];
  int cum[25];
};
__global__ void cvt_flat_k(FlatArgs a, bf16* base, const int* flag, int total){
  int i = blockIdx.x*256 + threadIdx.x;
  if (i >= total) return;
  int j = 0;
  while (i >= a.cum[j+1]) j++;
  int loc = i - a.cum[j];
  float v = (*flag) ? b2f(((const bf16*)a.src[j])[loc]) : ((const float*)a.src[j])[loc];
  base[a.dst[j] + loc] = f2b(v);
}

// ---- batched transpose convert (with per-segment scale) ----
struct TArgs {
  const void* src[10];
  long long dst[10];
  int K[10], Nc[10], Lstr[10], ro[10];
  float scale[10];
  int cum[11];
};
__global__ void cvt_t_k(TArgs a, bf16* base, const int* flag, int total){
  int i = blockIdx.x*256 + threadIdx.x;
  if (i >= total) return;
  int j = 0;
  while (i >= a.cum[j+1]) j++;
  int loc = i - a.cum[j];
  int KN = a.K[j]*a.Nc[j];
  int l = loc / KN; int rm = loc - l*KN; int k = rm / a.Nc[j]; int n = rm - k*a.Nc[j];
  float v = (*flag) ? b2f(((const bf16*)a.src[j])[loc]) : ((const float*)a.src[j])[loc];
  base[a.dst[j] + (long long)l*a.Lstr[j] + (long long)(a.ro[j]+n)*a.K[j] + k] = f2b(v*a.scale[j]);
}

// ---- additive mask in MFMA C-fragment layout ----
__global__ void maskc_k(const int* adj, float* maskg){
  int i = blockIdx.x*256 + threadIdx.x;
  if (i >= MSK_N) return;
  int cell = i >> 8;             // mi*13+nj
  int mi = cell / 13, nj = cell - mi*13;
  int rem = i & 255;
  int lane = rem >> 2, r = rem & 3;
  int quad = lane >> 4, cl = lane & 15;
  int row = mi*16 + quad*4 + r; if (row > 206) row = 206;
  int col = nj*16 + cl;
  float v;
  if (col > 206) v = -1e30f;
  else v = adj[row*N_ + col] ? 0.0f : NEG_;
  maskg[i] = v;
}

// ---- embed + fused LN (layer 0) ----
__global__ void embed_ln_k(const bf16* x, const bf16* Wi, const bf16* bi,
                           const bf16* g, const bf16* bta, float* h, bf16* xnb){
  int wave = threadIdx.x >> 6, lane = threadIdx.x & 63;
  int tok = blockIdx.x*4 + wave;
  if (tok >= TOK) return;
  float xv = b2f(x[tok]);
  float v0 = xv*b2f(Wi[lane])    + b2f(bi[lane]);
  float v1 = xv*b2f(Wi[lane+64]) + b2f(bi[lane+64]);
  float* hp = h + (size_t)tok*D_;
  hp[lane] = v0; hp[lane+64] = v1;
  float s = v0 + v1;
  for (int off = 32; off >= 1; off >>= 1) s += __shfl_xor(s, off, 64);
  float m = s * (1.0f/128.0f);
  float d0 = v0 - m, d1 = v1 - m;
  float vv = d0*d0 + d1*d1;
  for (int off = 32; off >= 1; off >>= 1) vv += __shfl_xor(vv, off, 64);
  float r = rsqrtf(vv*(1.0f/128.0f) + 1e-5f);
  bf16* op = xnb + (size_t)tok*D_;
  op[lane]    = f2b(d0*r*b2f(g[lane])    + b2f(bta[lane]));
  op[lane+64] = f2b(d1*r*b2f(g[lane+64]) + b2f(bta[lane+64]));
}

// ---- MFMA GEMM (non-acc), global_load_lds staging ----
__global__ __launch_bounds__(256) void mgemm_k(const bf16* __restrict__ A,
    const bf16* __restrict__ Wt, const bf16* __restrict__ bias,
    bf16* __restrict__ outp, int ldo, int Ktot, int relu){
  __shared__ __align__(16) bf16 As[128*32];
  __shared__ __align__(16) bf16 Bs[128*32];
  int tid = threadIdx.x;
  int rowBase = blockIdx.y * 128, colBase = blockIdx.x * 128;
  int w = tid >> 6, lane = tid & 63, quad = lane >> 4, cl = lane & 15;
  int waveM = w >> 1, waveN = w & 1;
  f32x4 accr[4][4];
  #pragma unroll
  for (int i = 0; i < 4; i++)
    #pragma unroll
    for (int j = 0; j < 4; j++) accr[i][j] = (f32x4){0.f,0.f,0.f,0.f};
  int lr = tid >> 2, kc = tid & 3;
  const bf16* Ap = A  + (size_t)(rowBase + lr)*Ktot + kc*8;
  const bf16* Bp = Wt + (size_t)(colBase + lr)*Ktot + kc*8;
  bf16* AsW = As + tid*8;
  bf16* BsW = Bs + tid*8;
  for (int kk = 0; kk < Ktot; kk += 32){
    __syncthreads();
    gll16(Ap + kk, AsW);
    gll16(Ap + (size_t)64*Ktot + kk, AsW + 64*32);
    gll16(Bp + kk, BsW);
    gll16(Bp + (size_t)64*Ktot + kk, BsW + 64*32);
    __syncthreads();
    bf16x8 af[4], bfr[4];
    #pragma unroll
    for (int mi = 0; mi < 4; mi++)
      af[mi] = *(const bf16x8*)(As + (waveM*64 + mi*16 + cl)*32 + quad*8);
    #pragma unroll
    for (int nj = 0; nj < 4; nj++)
      bfr[nj] = *(const bf16x8*)(Bs + (waveN*64 + nj*16 + cl)*32 + quad*8);
    #pragma unroll
    for (int mi = 0; mi < 4; mi++)
      #pragma unroll
      for (int nj = 0; nj < 4; nj++)
        accr[mi][nj] = __builtin_amdgcn_mfma_f32_16x16x32_bf16(af[mi], bfr[nj], accr[mi][nj], 0,0,0);
  }
  float bv[4];
  #pragma unroll
  for (int nj = 0; nj < 4; nj++)
    bv[nj] = bias ? b2f(bias[colBase + waveN*64 + nj*16 + cl]) : 0.0f;
  #pragma unroll
  for (int mi = 0; mi < 4; mi++){
    int row0 = rowBase + waveM*64 + mi*16 + quad*4;
    #pragma unroll
    for (int nj = 0; nj < 4; nj++){
      int col = colBase + waveN*64 + nj*16 + cl;
      #pragma unroll
      for (int r = 0; r < 4; r++){
        float v = accr[mi][nj][r] + bv[nj];
        if (relu) v = fmaxf(v, 0.0f);
        outp[(size_t)(row0+r)*ldo + col] = f2b(v);
      }
    }
  }
}

// ---- MFMA GEMM writing spatial q/k/v in [slab=(b,t,h)][n][16] layout ----
__global__ __launch_bounds__(256) void mgemm_qkvT_k(const bf16* __restrict__ A,
    const bf16* __restrict__ Wt, bf16* __restrict__ sQ,
    bf16* __restrict__ sK, bf16* __restrict__ sV){
  __shared__ __align__(16) bf16 As[128*32];
  __shared__ __align__(16) bf16 Bs[128*32];
  const int Ktot = 128;
  int tid = threadIdx.x;
  int rowBase = blockIdx.y * 128, colBase = blockIdx.x * 128;
  int w = tid >> 6, lane = tid & 63, quad = lane >> 4, cl = lane & 15;
  int waveM = w >> 1, waveN = w & 1;
  f32x4 accr[4][4];
  #pragma unroll
  for (int i = 0; i < 4; i++)
    #pragma unroll
    for (int j = 0; j < 4; j++) accr[i][j] = (f32x4){0.f,0.f,0.f,0.f};
  int lr = tid >> 2, kc = tid & 3;
  const bf16* Ap = A  + (size_t)(rowBase + lr)*Ktot + kc*8;
  const bf16* Bp = Wt + (size_t)(colBase + lr)*Ktot + kc*8;
  bf16* AsW = As + tid*8;
  bf16* BsW = Bs + tid*8;
  for (int kk = 0; kk < Ktot; kk += 32){
    __syncthreads();
    gll16(Ap + kk, AsW);
    gll16(Ap + (size_t)64*Ktot + kk, AsW + 64*32);
    gll16(Bp + kk, BsW);
    gll16(Bp + (size_t)64*Ktot + kk, BsW + 64*32);
    __syncthreads();
    bf16x8 af[4], bfr[4];
    #pragma unroll
    for (int mi = 0; mi < 4; mi++)
      af[mi] = *(const bf16x8*)(As + (waveM*64 + mi*16 + cl)*32 + quad*8);
    #pragma unroll
    for (int nj = 0; nj < 4; nj++)
      bfr[nj] = *(const bf16x8*)(Bs + (waveN*64 + nj*16 + cl)*32 + quad*8);
    #pragma unroll
    for (int mi = 0; mi < 4; mi++)
      #pragma unroll
      for (int nj = 0; nj < 4; nj++)
        accr[mi][nj] = __builtin_amdgcn_mfma_f32_16x16x32_bf16(af[mi], bfr[nj], accr[mi][nj], 0,0,0);
  }
  #pragma unroll
  for (int mi = 0; mi < 4; mi++){
    #pragma unroll
    for (int r = 0; r < 4; r++){
      int tok = rowBase + waveM*64 + mi*16 + quad*4 + r;
      int bn = tok / T_; int t = tok - bn*T_;
      int b = bn / N_;  int n = bn - b*N_;
      size_t base = ((size_t)(b*T_ + t)*H_)*SLAB + n*16 + cl;
      #pragma unroll
      for (int nj = 0; nj < 4; nj++){
        int col = colBase + waveN*64 + nj*16;
        int part = col >> 7, hh = (col >> 4) & 7;
        bf16* dst = (part == 0) ? sQ : (part == 1) ? sK : sV;
        dst[base + (size_t)hh*SLAB] = f2b(accr[mi][nj][r]);
      }
    }
  }
}

// ---- MFMA GEMM + residual-acc + fused LayerNorm (N=128, grid.x=1) ----
__global__ __launch_bounds__(256) void mgemm_ln_k(const bf16* __restrict__ A,
    const bf16* __restrict__ Wt, const bf16* __restrict__ bias,
    float* __restrict__ hout, int Ktot,
    const bf16* __restrict__ g, const bf16* __restrict__ bta,
    bf16* __restrict__ xnb){
  __shared__ __align__(16) bf16 As[128*32];
  __shared__ __align__(16) bf16 Bs[128*32];
  __shared__ float red[2][128][2];
  int tid = threadIdx.x;
  int rowBase = blockIdx.y * 128;
  int w = tid >> 6, lane = tid & 63, quad = lane >> 4, cl = lane & 15;
  int waveM = w >> 1, waveN = w & 1;
  f32x4 accr[4][4];
  #pragma unroll
  for (int i = 0; i < 4; i++)
    #pragma unroll
    for (int j = 0; j < 4; j++) accr[i][j] = (f32x4){0.f,0.f,0.f,0.f};
  int lr = tid >> 2, kc = tid & 3;
  const bf16* Ap = A  + (size_t)(rowBase + lr)*Ktot + kc*8;
  const bf16* Bp = Wt + (size_t)lr*Ktot + kc*8;
  bf16* AsW = As + tid*8;
  bf16* BsW = Bs + tid*8;
  for (int kk = 0; kk < Ktot; kk += 32){
    __syncthreads();
    gll16(Ap + kk, AsW);
    gll16(Ap + (size_t)64*Ktot + kk, AsW + 64*32);
    gll16(Bp + kk, BsW);
    gll16(Bp + (size_t)64*Ktot + kk, BsW + 64*32);
    __syncthreads();
    bf16x8 af[4], bfr[4];
    #pragma unroll
    for (int mi = 0; mi < 4; mi++)
      af[mi] = *(const bf16x8*)(As + (waveM*64 + mi*16 + cl)*32 + quad*8);
    #pragma unroll
    for (int nj = 0; nj < 4; nj++)
      bfr[nj] = *(const bf16x8*)(Bs + (waveN*64 + nj*16 + cl)*32 + quad*8);
    #pragma unroll
    for (int mi = 0; mi < 4; mi++)
      #pragma unroll
      for (int nj = 0; nj < 4; nj++)
        accr[mi][nj] = __builtin_amdgcn_mfma_f32_16x16x32_bf16(af[mi], bfr[nj], accr[mi][nj], 0,0,0);
  }
  int colW = waveN*64;
  float bv[4];
  #pragma unroll
  for (int nj = 0; nj < 4; nj++)
    bv[nj] = bias ? b2f(bias[colW + nj*16 + cl]) : 0.0f;
  float hv[4][4][4];
  float psum[4][4], psq[4][4];
  #pragma unroll
  for (int mi = 0; mi < 4; mi++)
    #pragma unroll
    for (int r = 0; r < 4; r++){ psum[mi][r] = 0.f; psq[mi][r] = 0.f; }
  #pragma unroll
  for (int mi = 0; mi < 4; mi++){
    #pragma unroll
    for (int r = 0; r < 4; r++){
      int row = rowBase + waveM*64 + mi*16 + quad*4 + r;
      #pragma unroll
      for (int nj = 0; nj < 4; nj++){
        int col = colW + nj*16 + cl;
        size_t idx = (size_t)row*D_ + col;
        float v = hout[idx] + accr[mi][nj][r] + bv[nj];
        hout[idx] = v;
        hv[mi][nj][r] = v;
        psum[mi][r] += v; psq[mi][r] += v*v;
      }
    }
  }
  if (g){
    #pragma unroll
    for (int off = 1; off <= 8; off <<= 1)
      #pragma unroll
      for (int mi = 0; mi < 4; mi++)
        #pragma unroll
        for (int r = 0; r < 4; r++){
          psum[mi][r] += __shfl_xor(psum[mi][r], off, 64);
          psq[mi][r]  += __shfl_xor(psq[mi][r],  off, 64);
        }
    if (cl == 0){
      #pragma unroll
      for (int mi = 0; mi < 4; mi++)
        #pragma unroll
        for (int r = 0; r < 4; r++){
          int rl = waveM*64 + mi*16 + quad*4 + r;
          red[waveN][rl][0] = psum[mi][r];
          red[waveN][rl][1] = psq[mi][r];
        }
    }
    __syncthreads();
    float gv[4], btv[4];
    #pragma unroll
    for (int nj = 0; nj < 4; nj++){
      int col = colW + nj*16 + cl;
      gv[nj] = b2f(g[col]); btv[nj] = b2f(bta[col]);
    }
    #pragma unroll
    for (int mi = 0; mi < 4; mi++){
      #pragma unroll
      for (int r = 0; r < 4; r++){
        int rl = waveM*64 + mi*16 + quad*4 + r;
        float s = red[0][rl][0] + red[1][rl][0];
        float q = red[0][rl][1] + red[1][rl][1];
        float mean = s*(1.0f/128.0f);
        float var  = q*(1.0f/128.0f) - mean*mean;
        float rstd = rsqrtf(var + 1e-5f);
        int row = rowBase + rl;
        #pragma unroll
        for (int nj = 0; nj < 4; nj++){
          int col = colW + nj*16 + cl;
          xnb[(size_t)row*D_ + col] = f2b((hv[mi][nj][r]-mean)*rstd*gv[nj] + btv[nj]);
        }
      }
    }
  }
}

// ---- fused FFN: h += relu(xn@W1+b1)@W2 + b2; xnb = LN(h) ----
// One block per 128 token rows. Hidden (512) processed in 4 chunks of 128,
// chunk kept in LDS (never touches HBM). Saves ~163 MB HBM per FFN.
__global__ __launch_bounds__(256,2) void mffn_ln_k(const bf16* __restrict__ A,
    const bf16* __restrict__ W1t, const bf16* __restrict__ b1,
    const bf16* __restrict__ W2t, const bf16* __restrict__ b2,
    float* __restrict__ hout,
    const bf16* __restrict__ g, const bf16* __restrict__ bta,
    bf16* __restrict__ xnb){
  __shared__ __align__(16) bf16 As[128*136];   // xn tile, staged once (pad 8)
  __shared__ __align__(16) bf16 Hs[128*136];   // hidden chunk (pad 8)
  __shared__ __align__(16) bf16 Bs[128*32];    // weight k-step tile
  __shared__ float red[2][128][2];
  int tid = threadIdx.x;
  int rowBase = blockIdx.x * 128;
  int w = tid >> 6, lane = tid & 63, quad = lane >> 4, cl = lane & 15;
  int waveM = w >> 1, waveN = w & 1;
  // stage A once (coalesced u32x4)
  for (int i = tid; i < 128*16; i += 256){
    int row = i >> 4, ch = i & 15;
    u32x4 v = *(const u32x4*)(A + (size_t)(rowBase + row)*128 + ch*8);
    *(u32x4*)(As + row*136 + ch*8) = v;
  }
  f32x4 acc2[4][4];
  #pragma unroll
  for (int i = 0; i < 4; i++)
    #pragma unroll
    for (int j = 0; j < 4; j++) acc2[i][j] = (f32x4){0.f,0.f,0.f,0.f};
  int lr = tid >> 2, kc = tid & 3;
  bf16* BsW = Bs + tid*8;
  int aRow0 = waveM*64;
  for (int kt = 0; kt < 4; kt++){
    // ---- FFN1 chunk: hidden[:,kt*128 .. +128) ----
    f32x4 acc1[4][4];
    #pragma unroll
    for (int i = 0; i < 4; i++)
      #pragma unroll
      for (int j = 0; j < 4; j++) acc1[i][j] = (f32x4){0.f,0.f,0.f,0.f};
    for (int ks = 0; ks < 4; ks++){
      __syncthreads();
      gll16(W1t + (size_t)(kt*128 + lr)*128 + ks*32 + kc*8, BsW);
      gll16(W1t + (size_t)(kt*128 + 64 + lr)*128 + ks*32 + kc*8, BsW + 64*32);
      __syncthreads();
      bf16x8 af[4], bfr[4];
      #pragma unroll
      for (int mi = 0; mi < 4; mi++)
        af[mi] = *(const bf16x8*)(As + (aRow0 + mi*16 + cl)*136 + ks*32 + quad*8);
      #pragma unroll
      for (int nj = 0; nj < 4; nj++)
        bfr[nj] = *(const bf16x8*)(Bs + (waveN*64 + nj*16 + cl)*32 + quad*8);
      #pragma unroll
      for (int mi = 0; mi < 4; mi++)
        #pragma unroll
        for (int nj = 0; nj < 4; nj++)
          acc1[mi][nj] = __builtin_amdgcn_mfma_f32_16x16x32_bf16(af[mi], bfr[nj], acc1[mi][nj], 0,0,0);
    }
    // bias + relu -> Hs (bf16)
    float b1v[4];
    #pragma unroll
    for (int nj = 0; nj < 4; nj++)
      b1v[nj] = b2f(b1[kt*128 + waveN*64 + nj*16 + cl]);
    #pragma unroll
    for (int mi = 0; mi < 4; mi++){
      #pragma unroll
      for (int r = 0; r < 4; r++){
        int row = aRow0 + mi*16 + quad*4 + r;
        #pragma unroll
        for (int nj = 0; nj < 4; nj++){
          int col = waveN*64 + nj*16 + cl;
          Hs[row*136 + col] = f2b(fmaxf(acc1[mi][nj][r] + b1v[nj], 0.0f));
        }
      }
    }
    // ---- FFN2 partial: out += hidden_chunk @ W2[kt*128.., :] ----
    for (int ks = 0; ks < 4; ks++){
      __syncthreads();   // Hs visible (first iter) / Bs WAR
      gll16(W2t + (size_t)lr*512 + kt*128 + ks*32 + kc*8, BsW);
      gll16(W2t + (size_t)(64 + lr)*512 + kt*128 + ks*32 + kc*8, BsW + 64*32);
      __syncthreads();
      bf16x8 af[4], bfr[4];
      #pragma unroll
      for (int mi = 0; mi < 4; mi++)
        af[mi] = *(const bf16x8*)(Hs + (aRow0 + mi*16 + cl)*136 + ks*32 + quad*8);
      #pragma unroll
      for (int nj = 0; nj < 4; nj++)
        bfr[nj] = *(const bf16x8*)(Bs + (waveN*64 + nj*16 + cl)*32 + quad*8);
      #pragma unroll
      for (int mi = 0; mi < 4; mi++)
        #pragma unroll
        for (int nj = 0; nj < 4; nj++)
          acc2[mi][nj] = __builtin_amdgcn_mfma_f32_16x16x32_bf16(af[mi], bfr[nj], acc2[mi][nj], 0,0,0);
    }
    __syncthreads();    // Hs WAR before next kt overwrites
  }
  // ---- epilogue: bias2 + residual-acc + fused LN ----
  int colW = waveN*64;
  float bv[4];
  #pragma unroll
  for (int nj = 0; nj < 4; nj++)
    bv[nj] = b2f(b2[colW + nj*16 + cl]);
  float hv[4][4][4];
  float psum[4][4], psq[4][4];
  #pragma unroll
  for (int mi = 0; mi < 4; mi++)
    #pragma unroll
    for (int r = 0; r < 4; r++){ psum[mi][r] = 0.f; psq[mi][r] = 0.f; }
  #pragma unroll
  for (int mi = 0; mi < 4; mi++){
    #pragma unroll
    for (int r = 0; r < 4; r++){
      int row = rowBase + aRow0 + mi*16 + quad*4 + r;
      #pragma unroll
      for (int nj = 0; nj < 4; nj++){
        int col = colW + nj*16 + cl;
        size_t idx = (size_t)row*D_ + col;
        float v = hout[idx] + acc2[mi][nj][r] + bv[nj];
        hout[idx] = v;
        hv[mi][nj][r] = v;
        psum[mi][r] += v; psq[mi][r] += v*v;
      }
    }
  }
  if (g){
    #pragma unroll
    for (int off = 1; off <= 8; off <<= 1)
      #pragma unroll
      for (int mi = 0; mi < 4; mi++)
        #pragma unroll
        for (int r = 0; r < 4; r++){
          psum[mi][r] += __shfl_xor(psum[mi][r], off, 64);
          psq[mi][r]  += __shfl_xor(psq[mi][r],  off, 64);
        }
    if (cl == 0){
      #pragma unroll
      for (int mi = 0; mi < 4; mi++)
        #pragma unroll
        for (int r = 0; r < 4; r++){
          int rl = aRow0 + mi*16 + quad*4 + r;
          red[waveN][rl][0] = psum[mi][r];
          red[waveN][rl][1] = psq[mi][r];
        }
    }
    __syncthreads();
    float gv[4], btv[4];
    #pragma unroll
    for (int nj = 0; nj < 4; nj++){
      int col = colW + nj*16 + cl;
      gv[nj] = b2f(g[col]); btv[nj] = b2f(bta[col]);
    }
    #pragma unroll
    for (int mi = 0; mi < 4; mi++){
      #pragma unroll
      for (int r = 0; r < 4; r++){
        int rl = aRow0 + mi*16 + quad*4 + r;
        float s = red[0][rl][0] + red[1][rl][0];
        float q = red[0][rl][1] + red[1][rl][1];
        float mean = s*(1.0f/128.0f);
        float var  = q*(1.0f/128.0f) - mean*mean;
        float rstd = rsqrtf(var + 1e-5f);
        int row = rowBase + rl;
        #pragma unroll
        for (int nj = 0; nj < 4; nj++){
          int col = colW + nj*16 + cl;
          xnb[(size_t)row*D_ + col] = f2b((hv[mi][nj][r]-mean)*rstd*gv[nj] + btv[nj]);
        }
      }
    }
  }
}

// ---- MFMA spatial attention (unchanged from round 8) ----
__global__ __launch_bounds__(256,3) void sattn_k(const bf16* __restrict__ sQ,
    const bf16* __restrict__ sK, const bf16* __restrict__ sV,
    const float* __restrict__ maskg, bf16* __restrict__ ob){
  __shared__ __align__(16) bf16     Ks[NPAD*KQ2];
  __shared__ __align__(16) _Float16 Vt[16*KVH];
  __shared__ __align__(16) _Float16 Ps[4*16*KVH];
  int tid = threadIdx.x;
  int bid = blockIdx.x;                // slab = (b*T+t)*H + hh
  int hh = bid & 7; int bt = bid >> 3; int t = bt % T_; int b = bt / T_;
  const bf16* Kslab = sK + (size_t)bid*SLAB;
  const bf16* Vslab = sV + (size_t)bid*SLAB;
  const bf16* Qslab = sQ + (size_t)bid*SLAB;
  for (int i = tid; i < 16*25; i += 256){ int d = i/25, c = 207 + i%25; Vt[d*KVH + c] = (_Float16)0.0f; }
  for (int i = tid; i < 64*24; i += 256){ int row = i/24, c = 208 + i%24; Ps[row*KVH + c] = (_Float16)0.0f; }
  for (int c = tid; c < 414; c += 256){
    bf16x8 kv = *(const bf16x8*)(Kslab + c*8);
    int n = c >> 1, dh = (c & 1)*8;
    *(bf16x8*)(Ks + n*KQ2 + dh) = kv;
  }
  for (int i = tid; i < SLAB; i += 256){
    int n = i >> 4, d = i & 15;
    Vt[d*KVH + n] = (_Float16)b2f(Vslab[i]);
  }
  __syncthreads();

  int lane = tid & 63, w = tid >> 6, quad = lane >> 4, cl = lane & 15;
  int nstripes = (w == 0) ? 4 : 3;
  for (int si = 0; si < nstripes; si++){
    int mi = w + si*4;
    bf16x8 aq = (bf16x8){0,0,0,0,0,0,0,0};
    {
      int n = mi*16 + cl; if (n > N_-1) n = N_-1;
      if (quad < 2) aq = *(const bf16x8*)(Qslab + n*16 + quad*8);
    }
    const float* mrow = maskg + ((size_t)mi*13)*256 + lane*4;
    f32x4 s[13];
    #pragma unroll
    for (int nj = 0; nj < 13; nj++){
      bf16x8 bk = (bf16x8){0,0,0,0,0,0,0,0};
      if (quad < 2) bk = *(const bf16x8*)(Ks + (nj*16 + cl)*KQ2 + quad*8);
      f32x4 c0 = *(const f32x4*)(mrow + nj*256);
      s[nj] = __builtin_amdgcn_mfma_f32_16x16x32_bf16(aq, bk, c0, 0,0,0);
    }
    int row0 = mi*16 + quad*4;
    _Float16* Pw = Ps + w*16*KVH;
    float invr[4];
    #pragma unroll
    for (int r = 0; r < 4; r++){
      float sum = 0.0f;
      #pragma unroll
      for (int nj = 0; nj < 13; nj++){
        float e = __expf(s[nj][r]);
        s[nj][r] = e; sum += e;
      }
      for (int off = 1; off < 16; off <<= 1) sum += __shfl_xor(sum, off, 64);
      invr[r] = 1.0f/sum;
      _Float16* Pr = Pw + (quad*4 + r)*KVH;
      #pragma unroll
      for (int nj = 0; nj < 13; nj++) Pr[nj*16 + cl] = (_Float16)s[nj][r];
    }
    __threadfence_block();
    f32x4 o = {0.f,0.f,0.f,0.f};
    #pragma unroll
    for (int kt = 0; kt < 7; kt++){
      f16x8 ap = *(const f16x8*)(Pw + cl*KVH + kt*32 + quad*8);
      f16x8 bv = *(const f16x8*)(Vt + cl*KVH + kt*32 + quad*8);
      o = __builtin_amdgcn_mfma_f32_16x16x32_f16(ap, bv, o, 0,0,0);
    }
    #pragma unroll
    for (int r = 0; r < 4; r++){
      int rg = row0 + r;
      if (rg < N_)
        ob[((size_t)((b*N_ + rg)*T_ + t))*D_ + hh*HD_ + cl] = f2b(o[r]*invr[r]);
    }
    __threadfence_block();
  }
}

// ---- temporal attention ----
__global__ void tattn_k(const bf16* qkv, bf16* ob){
  int bid = blockIdx.x; int b = bid / N_, n = bid % N_;
  __shared__ float qs[T_*D_];
  __shared__ float ks[T_*D_];
  __shared__ float vs[T_*D_];
  size_t rowb = ((size_t)(b*N_+n)*T_)*384;
  const u32* src = (const u32*)(qkv + rowb);
  for (int idx = threadIdx.x; idx < T_*192; idx += 128){
    int tt = idx / 192, cw = idx - tt*192;
    u32 pr = src[tt*192 + cw];
    union { u32 u; bf16 b[2]; } cv; cv.u = pr;
    float v0 = b2f(cv.b[0]), v1 = b2f(cv.b[1]);
    int arr = cw >> 6, cp2 = (cw & 63)*2;
    float* dst = (arr == 0) ? qs : (arr == 1) ? ks : vs;
    dst[tt*128 + cp2] = v0; dst[tt*128 + cp2 + 1] = v1;
  }
  __syncthreads();
  int p = threadIdx.x;
  if (p < H_*T_){
    int hh = p / T_, t = p - hh*T_;
    float qreg[16];
    for (int d = 0; d < 16; d++) qreg[d] = qs[t*128 + hh*16 + d];
    float sc[12]; float mx = -3.4e38f;
    for (int s = 0; s < 12; s++){
      float a = 0.0f;
      for (int d = 0; d < 16; d++) a += qreg[d]*ks[s*128 + hh*16 + d];
      a = (s <= t) ? a*SCALE_ : -3.4e38f;
      sc[s] = a; mx = fmaxf(mx, a);
    }
    float ssum = 0.0f;
    for (int s = 0; s < 12; s++){
      float e = (s <= t) ? __expf(sc[s]-mx) : 0.0f;
      sc[s] = e; ssum += e;
    }
    float inv = 1.0f/ssum;
    size_t obase = ((size_t)(b*N_+n)*T_ + t)*D_ + hh*16;
    for (int d = 0; d < 16; d++){
      float acc = 0.0f;
      for (int s = 0; s < 12; s++) acc += sc[s]*vs[s*128 + hh*16 + d];
      ob[obase + d] = f2b(acc*inv);
    }
  }
}

// ---- VALU GEMM for small head GEMMs ----
__global__ void gemm_k(const bf16* A, int lda, const bf16* W, const bf16* bias,
                       void* outp, int ldo, int M, int Ncols, int K, int relu, int acc){
  __shared__ float Ast[16*68];
  __shared__ float Ws [16*68];
  int tx = threadIdx.x & 15, ty = threadIdx.x >> 4;
  int rowBase = blockIdx.y * 64, colBase = blockIdx.x * 64;
  float accr[4][4];
  for (int i = 0; i < 4; i++) for (int j = 0; j < 4; j++) accr[i][j] = 0.0f;
  for (int kk = 0; kk < K; kk += 16){
    int kq = threadIdx.x & 15, r0 = threadIdx.x >> 4;
    for (int it = 0; it < 4; it++){
      int r = r0 + it*16, row = rowBase + r;
      float v = 0.0f;
      if (row < M) v = b2f(A[(size_t)row*lda + kk + kq]);
      Ast[kq*68 + r] = v;
    }
    int c = threadIdx.x & 63, w0 = threadIdx.x >> 6;
    for (int it = 0; it < 4; it++){
      int kr = w0 + it*4;
      Ws[kr*68 + c] = b2f(W[(size_t)(kk+kr)*Ncols + colBase + c]);
    }
    __syncthreads();
    for (int k = 0; k < 16; k++){
      float av[4], wv[4];
      for (int i = 0; i < 4; i++) av[i] = Ast[k*68 + ty*4 + i];
      for (int j = 0; j < 4; j++) wv[j] = Ws[k*68 + tx*4 + j];
      for (int i = 0; i < 4; i++)
        for (int j = 0; j < 4; j++) accr[i][j] += av[i]*wv[j];
    }
    __syncthreads();
  }
  for (int i = 0; i < 4; i++){
    int row = rowBase + ty*4 + i;
    if (row >= M) continue;
    for (int j = 0; j < 4; j++){
      int col = colBase + tx*4 + j;
      float v = accr[i][j];
      if (bias) v += b2f(bias[col]);
      if (relu) v = fmaxf(v, 0.0f);
      if (acc) ((float*)outp)[(size_t)row*ldo + col] += v;
      else     ((bf16*)outp)[(size_t)row*ldo + col] = f2b(v);
    }
  }
}

__global__ void gather_k(const float* h, bf16* hlb){
  int i = blockIdx.x*256 + threadIdx.x;
  if (i >= ROWS2*D_) return;
  int r = i >> 7, d = i & 127;
  hlb[i] = f2b(h[((size_t)r*T_ + (T_-1))*D_ + d]);
}

__global__ void head3_k(const bf16* z2, const bf16* P3, const bf16* Pb3,
                        void* out, int out_n, const int* flag){
  int i = blockIdx.x*256 + threadIdx.x;
  if (i >= out_n) return;
  int r = i / PL_, j = i - r*PL_;
  float acc = b2f(Pb3[j]);
  for (int d = 0; d < 128; d++) acc += b2f(z2[(size_t)r*128 + d]) * b2f(P3[d*PL_ + j]);
  if (*flag) ((bf16*)out)[i] = f2b(acc);
  else       ((float*)out)[i] = acc;
}

extern "C" void kernel_launch(void* const* d_in, const int* in_sizes, int n_in,
                              void* d_out, int out_size, void* d_ws, size_t ws_size,
                              hipStream_t stream){
  size_t HB = (size_t)TOK*D_*4;
  size_t XB = (size_t)TOK*D_*2;
  size_t RB = (size_t)TOK*D_*8;
  float* h    = (float*)d_ws;
  bf16*  xnb  = (bf16*)((char*)d_ws + HB);
  bf16*  reg_ = (bf16*)((char*)d_ws + HB + XB);
  bf16*  cvt  = (bf16*)((char*)d_ws + HB + XB + RB);
  bf16*  wsb  = (bf16*)d_ws;
  const int FIDX[34] = {0,2,3,4,5,6,7,8,9,10,11,12,13,14,15,16,17,18,19,20,
                        21,22,23,24,25,26,27,28,29,30,31,32,33,34};
  bf16* cp[34];
  size_t off = 0;
  for (int i = 0; i < 34; i++){ cp[i] = cvt + off; off += (size_t)in_sizes[FIDX[i]]; }
  char* tail   = (char*)d_ws + HB + XB + RB + ((off*2 + 255) & ~(size_t)255);
  float* maskg = (float*)tail;
  bf16* qkvw   = (bf16*)(tail + (size_t)MSK_N*4);
  int*  flag   = (int*)(tail + (size_t)MSK_N*4 + (size_t)L_*384*128*2);

  const bf16 *x_c=cp[0], *Wi_c=cp[1], *bi_c=cp[2],
             *Wo_t=cp[6], *bo_c=cp[7], *sW1_t=cp[8], *sB1_c=cp[9], *sW2_t=cp[10], *sB2_c=cp[11],
             *sg1_c=cp[12], *sh1_c=cp[13], *sg2_c=cp[14], *sh2_c=cp[15], *Win_t=cp[16], *Bin_c=cp[17],
             *Wout_t=cp[18], *Bout_c=cp[19], *tW1_t=cp[20], *tB1_c=cp[21], *tW2_t=cp[22], *tB2_c=cp[23],
             *tg1_c=cp[24], *th1_c=cp[25], *tg2_c=cp[26], *th2_c=cp[27], *P1_c=cp[28], *Pb1_c=cp[29],
             *P2_c=cp[30], *Pb2_c=cp[31], *P3_c=cp[32], *Pb3_c=cp[33];
  const int* adj = (const int*)d_in[1];

  bf16* sQ   = reg_;
  bf16* sK   = reg_ + (size_t)TOK*128;
  bf16* sV   = reg_ + (size_t)2*TOK*128;
  bf16* ob   = reg_ + (size_t)3*TOK*128;
  bf16* qkvb = reg_;

  detect_k<<<1, 256, 0, stream>>>(d_in[0], flag);

  {
    const int FLAT[24] = {0,1,2,7,9,11,12,13,14,15,17,19,21,23,24,25,26,27,28,29,30,31,32,33};
    FlatArgs fa; int c = 0;
    for (int ii = 0; ii < 24; ii++){
      int ci = FLAT[ii];
      fa.src[ii] = d_in[FIDX[ci]];
      fa.dst[ii] = (long long)(cp[ci] - wsb);
      fa.cum[ii] = c;
      c += in_sizes[FIDX[ci]];
    }
    fa.cum[24] = c;
    cvt_flat_k<<<(c+255)/256, 256, 0, stream>>>(fa, wsb, flag, c);
  }
  {
    TArgs ta; int c = 0;
    const void* srcs[10] = {d_in[4], d_in[5], d_in[6], d_in[7], d_in[9], d_in[11],
                            d_in[17], d_in[19], d_in[21], d_in[23]};
    bf16* dsts[10] = {qkvw, qkvw, qkvw, cp[6], cp[8], cp[10], cp[16], cp[18], cp[20], cp[22]};
    int Ks_[10]   = {128,128,128, 128, 128, 512, 128, 128, 128, 512};
    int Ncs[10]   = {128,128,128, 128, 512, 128, 384, 128, 512, 128};
    int Lst[10]   = {384*128,384*128,384*128, 128*128, 128*512, 512*128, 128*384, 128*128, 128*512, 512*128};
    int ros[10]   = {0,128,256, 0,0,0, 0,0,0, 0};
    for (int j = 0; j < 10; j++){
      ta.src[j] = srcs[j];
      ta.dst[j] = (long long)(dsts[j] - wsb);
      ta.K[j] = Ks_[j]; ta.Nc[j] = Ncs[j]; ta.Lstr[j] = Lst[j]; ta.ro[j] = ros[j];
      ta.scale[j] = (j == 0) ? SCALE_ : 1.0f;
      ta.cum[j] = c;
      c += L_*Ks_[j]*Ncs[j];
    }
    ta.cum[10] = c;
    cvt_t_k<<<(c+255)/256, 256, 0, stream>>>(ta, wsb, flag, c);
  }
  maskc_k<<<(MSK_N+255)/256, 256, 0, stream>>>(adj, maskg);
  embed_ln_k<<<TOK/4, 256, 0, stream>>>(x_c, Wi_c, bi_c, sg1_c, sh1_c, h, xnb);

  const dim3 gP  (1, TOK/128);
  const dim3 gQKV(3, TOK/128);

  for (int l = 0; l < L_; l++){
    // spatial attention
    mgemm_qkvT_k<<<gQKV, 256, 0, stream>>>(xnb, qkvw + (size_t)l*384*128, sQ, sK, sV);
    sattn_k<<<B_*T_*H_, 256, 0, stream>>>(sQ, sK, sV, maskg, ob);
    mgemm_ln_k<<<gP, 256, 0, stream>>>(ob, Wo_t + (size_t)l*D_*D_, bo_c + l*D_, h, D_,
                                       sg2_c + l*D_, sh2_c + l*D_, xnb);
    // fused FFN 1 (-> LN tg1)
    mffn_ln_k<<<TOK/128, 256, 0, stream>>>(xnb, sW1_t + (size_t)l*D_*FF_, sB1_c + l*FF_,
                                           sW2_t + (size_t)l*FF_*D_, sB2_c + l*D_, h,
                                           tg1_c + l*D_, th1_c + l*D_, xnb);
    // temporal attention
    mgemm_k<<<gQKV, 256, 0, stream>>>(xnb, Win_t + (size_t)l*D_*384, Bin_c + l*384, qkvb, 384, D_, 0);
    tattn_k<<<B_*N_, 128, 0, stream>>>(qkvb, ob);
    mgemm_ln_k<<<gP, 256, 0, stream>>>(ob, Wout_t + (size_t)l*D_*D_, Bout_c + l*D_, h, D_,
                                       tg2_c + l*D_, th2_c + l*D_, xnb);
    // fused FFN 2 (-> LN next sg1 or none)
    const bf16* gnext = (l < L_-1) ? (sg1_c + (l+1)*D_) : nullptr;
    const bf16* bnext = (l < L_-1) ? (sh1_c + (l+1)*D_) : nullptr;
    mffn_ln_k<<<TOK/128, 256, 0, stream>>>(xnb, tW1_t + (size_t)l*D_*FF_, tB1_c + l*FF_,
                                           tW2_t + (size_t)l*FF_*D_, tB2_c + l*D_, h,
                                           gnext, bnext, xnb);
  }

  // head
  bf16* hlb = reg_;
  bf16* z1  = reg_ + (size_t)ROWS2*128;
  bf16* z2  = z1   + (size_t)ROWS2*256;
  gather_k<<<(ROWS2*D_)/256, 256, 0, stream>>>(h, hlb);
  gemm_k<<<dim3(256/64, (ROWS2+63)/64), 256, 0, stream>>>(hlb, 128, P1_c, Pb1_c, z1, 256, ROWS2, 256, 128, 1, 0);
  gemm_k<<<dim3(128/64, (ROWS2+63)/64), 256, 0, stream>>>(z1, 256, P2_c, Pb2_c, z2, 128, ROWS2, 128, 256, 1, 0);
  head3_k<<<(out_size+255)/256, 256, 0, stream>>>(z2, P3_c, Pb3_c, d_out, out_size, flag);
}

// Round 10
// 1576.334 us; speedup vs baseline: 5.0739x; 1.0271x over previous
//
#include <hip/hip_runtime.h>
#include <hip/hip_bf16.h>

#define B_   32
#define N_   207
#define T_   12
#define D_   128
#define H_   8
#define HD_  16
#define L_   4
#define FF_  512
#define PL_  12
#define TOK  (B_*N_*T_)      // 79488 = 621*128
#define ROWS2 (B_*N_)        // 6624
#define SCALE_ 0.25f
#define LOG2E_ 1.4426950408889634f
#define NEG2_ -1.4426950409e9f   // -1e9 in log2 domain
#define KVH  232             // Vt/P row stride (fp16)
#define SLAB 3312            // 207*16 elements per (b,t,h) slab
#define MSK_N (13*13*256)    // mask elements in C-frag layout

typedef __hip_bfloat16 bf16;
typedef unsigned int u32;
typedef __attribute__((ext_vector_type(4))) unsigned int u32x4;
typedef __attribute__((ext_vector_type(8))) short bf16x8;     // 8 bf16 (MFMA A/B frag)
typedef __attribute__((ext_vector_type(8))) _Float16 f16x8;   // 8 fp16 (MFMA A/B frag)
typedef __attribute__((ext_vector_type(4))) float f32x4;      // MFMA C/D frag

__device__ __forceinline__ float b2f(bf16 x){ return __bfloat162float(x); }
__device__ __forceinline__ bf16  f2b(float x){ return __float2bfloat16(x); }

// async global->LDS 16B per lane (dest must be wave-uniform base + lane*16)
__device__ __forceinline__ void gll16(const bf16* g, bf16* l){
  __builtin_amdgcn_global_load_lds((const __attribute__((address_space(1))) void*)g,
                                   (__attribute__((address_space(3))) void*)l, 16, 0, 0);
}

// ---- dtype detection ----
__global__ void detect_k(const void* x, int* flag){
  __shared__ int cnt[256];
  const unsigned short* u = (const unsigned short*)x;
  int ok = 0;
  for (int i = threadIdx.x; i < 4096; i += 256){
    unsigned int bits = ((unsigned int)u[i]) << 16;
    float f = __uint_as_float(bits);
    float a = fabsf(f);
    if (f == 0.0f || (a > 1e-4f && a < 64.0f)) ok++;
  }
  cnt[threadIdx.x] = ok;
  __syncthreads();
  for (int s = 128; s > 0; s >>= 1){
    if (threadIdx.x < s) cnt[threadIdx.x] += cnt[threadIdx.x + s];
    __syncthreads();
  }
  if (threadIdx.x == 0) *flag = (cnt[0] > 3686) ? 1 : 0;
}

// ---- batched flat convert ----
struct FlatArgs {
  const void* src[24];
  long long dst[24];
  int cum[25];
};
__global__ void cvt_flat_k(FlatArgs a, bf16* base, const int* flag, int total){
  int i = blockIdx.x*256 + threadIdx.x;
  if (i >= total) return;
  int j = 0;
  while (i >= a.cum[j+1]) j++;
  int loc = i - a.cum[j];
  float v = (*flag) ? b2f(((const bf16*)a.src[j])[loc]) : ((const float*)a.src[j])[loc];
  base[a.dst[j] + loc] = f2b(v);
}

// ---- batched transpose convert (with per-segment scale) ----
struct TArgs {
  const void* src[10];
  long long dst[10];
  int K[10], Nc[10], Lstr[10], ro[10];
  float scale[10];
  int cum[11];
};
__global__ void cvt_t_k(TArgs a, bf16* base, const int* flag, int total){
  int i = blockIdx.x*256 + threadIdx.x;
  if (i >= total) return;
  int j = 0;
  while (i >= a.cum[j+1]) j++;
  int loc = i - a.cum[j];
  int KN = a.K[j]*a.Nc[j];
  int l = loc / KN; int rm = loc - l*KN; int k = rm / a.Nc[j]; int n = rm - k*a.Nc[j];
  float v = (*flag) ? b2f(((const bf16*)a.src[j])[loc]) : ((const float*)a.src[j])[loc];
  base[a.dst[j] + (long long)l*a.Lstr[j] + (long long)(a.ro[j]+n)*a.K[j] + k] = f2b(v*a.scale[j]);
}

// ---- additive mask in MFMA C-fragment layout (log2 domain) ----
__global__ void maskc_k(const int* adj, float* maskg){
  int i = blockIdx.x*256 + threadIdx.x;
  if (i >= MSK_N) return;
  int cell = i >> 8;             // mi*13+nj
  int mi = cell / 13, nj = cell - mi*13;
  int rem = i & 255;
  int lane = rem >> 2, r = rem & 3;
  int quad = lane >> 4, cl = lane & 15;
  int row = mi*16 + quad*4 + r; if (row > 206) row = 206;
  int col = nj*16 + cl;
  float v;
  if (col > 206) v = -1e30f;
  else v = adj[row*N_ + col] ? 0.0f : NEG2_;
  maskg[i] = v;
}

// ---- embed + fused LN (layer 0) ----
__global__ void embed_ln_k(const bf16* x, const bf16* Wi, const bf16* bi,
                           const bf16* g, const bf16* bta, float* h, bf16* xnb){
  int wave = threadIdx.x >> 6, lane = threadIdx.x & 63;
  int tok = blockIdx.x*4 + wave;
  if (tok >= TOK) return;
  float xv = b2f(x[tok]);
  float v0 = xv*b2f(Wi[lane])    + b2f(bi[lane]);
  float v1 = xv*b2f(Wi[lane+64]) + b2f(bi[lane+64]);
  float* hp = h + (size_t)tok*D_;
  hp[lane] = v0; hp[lane+64] = v1;
  float s = v0 + v1;
  for (int off = 32; off >= 1; off >>= 1) s += __shfl_xor(s, off, 64);
  float m = s * (1.0f/128.0f);
  float d0 = v0 - m, d1 = v1 - m;
  float vv = d0*d0 + d1*d1;
  for (int off = 32; off >= 1; off >>= 1) vv += __shfl_xor(vv, off, 64);
  float r = rsqrtf(vv*(1.0f/128.0f) + 1e-5f);
  bf16* op = xnb + (size_t)tok*D_;
  op[lane]    = f2b(d0*r*b2f(g[lane])    + b2f(bta[lane]));
  op[lane+64] = f2b(d1*r*b2f(g[lane+64]) + b2f(bta[lane+64]));
}

// ---- MFMA GEMM (non-acc), global_load_lds staging ----
__global__ __launch_bounds__(256) void mgemm_k(const bf16* __restrict__ A,
    const bf16* __restrict__ Wt, const bf16* __restrict__ bias,
    bf16* __restrict__ outp, int ldo, int Ktot, int relu){
  __shared__ __align__(16) bf16 As[128*32];
  __shared__ __align__(16) bf16 Bs[128*32];
  int tid = threadIdx.x;
  int rowBase = blockIdx.y * 128, colBase = blockIdx.x * 128;
  int w = tid >> 6, lane = tid & 63, quad = lane >> 4, cl = lane & 15;
  int waveM = w >> 1, waveN = w & 1;
  f32x4 accr[4][4];
  #pragma unroll
  for (int i = 0; i < 4; i++)
    #pragma unroll
    for (int j = 0; j < 4; j++) accr[i][j] = (f32x4){0.f,0.f,0.f,0.f};
  int lr = tid >> 2, kc = tid & 3;
  const bf16* Ap = A  + (size_t)(rowBase + lr)*Ktot + kc*8;
  const bf16* Bp = Wt + (size_t)(colBase + lr)*Ktot + kc*8;
  bf16* AsW = As + tid*8;
  bf16* BsW = Bs + tid*8;
  for (int kk = 0; kk < Ktot; kk += 32){
    __syncthreads();
    gll16(Ap + kk, AsW);
    gll16(Ap + (size_t)64*Ktot + kk, AsW + 64*32);
    gll16(Bp + kk, BsW);
    gll16(Bp + (size_t)64*Ktot + kk, BsW + 64*32);
    __syncthreads();
    bf16x8 af[4], bfr[4];
    #pragma unroll
    for (int mi = 0; mi < 4; mi++)
      af[mi] = *(const bf16x8*)(As + (waveM*64 + mi*16 + cl)*32 + quad*8);
    #pragma unroll
    for (int nj = 0; nj < 4; nj++)
      bfr[nj] = *(const bf16x8*)(Bs + (waveN*64 + nj*16 + cl)*32 + quad*8);
    #pragma unroll
    for (int mi = 0; mi < 4; mi++)
      #pragma unroll
      for (int nj = 0; nj < 4; nj++)
        accr[mi][nj] = __builtin_amdgcn_mfma_f32_16x16x32_bf16(af[mi], bfr[nj], accr[mi][nj], 0,0,0);
  }
  float bv[4];
  #pragma unroll
  for (int nj = 0; nj < 4; nj++)
    bv[nj] = bias ? b2f(bias[colBase + waveN*64 + nj*16 + cl]) : 0.0f;
  #pragma unroll
  for (int mi = 0; mi < 4; mi++){
    int row0 = rowBase + waveM*64 + mi*16 + quad*4;
    #pragma unroll
    for (int nj = 0; nj < 4; nj++){
      int col = colBase + waveN*64 + nj*16 + cl;
      #pragma unroll
      for (int r = 0; r < 4; r++){
        float v = accr[mi][nj][r] + bv[nj];
        if (relu) v = fmaxf(v, 0.0f);
        outp[(size_t)(row0+r)*ldo + col] = f2b(v);
      }
    }
  }
}

// ---- MFMA GEMM writing spatial q/k/v in [slab=(b,t,h)][n][16] layout ----
__global__ __launch_bounds__(256) void mgemm_qkvT_k(const bf16* __restrict__ A,
    const bf16* __restrict__ Wt, bf16* __restrict__ sQ,
    bf16* __restrict__ sK, bf16* __restrict__ sV){
  __shared__ __align__(16) bf16 As[128*32];
  __shared__ __align__(16) bf16 Bs[128*32];
  const int Ktot = 128;
  int tid = threadIdx.x;
  int rowBase = blockIdx.y * 128, colBase = blockIdx.x * 128;
  int w = tid >> 6, lane = tid & 63, quad = lane >> 4, cl = lane & 15;
  int waveM = w >> 1, waveN = w & 1;
  f32x4 accr[4][4];
  #pragma unroll
  for (int i = 0; i < 4; i++)
    #pragma unroll
    for (int j = 0; j < 4; j++) accr[i][j] = (f32x4){0.f,0.f,0.f,0.f};
  int lr = tid >> 2, kc = tid & 3;
  const bf16* Ap = A  + (size_t)(rowBase + lr)*Ktot + kc*8;
  const bf16* Bp = Wt + (size_t)(colBase + lr)*Ktot + kc*8;
  bf16* AsW = As + tid*8;
  bf16* BsW = Bs + tid*8;
  for (int kk = 0; kk < Ktot; kk += 32){
    __syncthreads();
    gll16(Ap + kk, AsW);
    gll16(Ap + (size_t)64*Ktot + kk, AsW + 64*32);
    gll16(Bp + kk, BsW);
    gll16(Bp + (size_t)64*Ktot + kk, BsW + 64*32);
    __syncthreads();
    bf16x8 af[4], bfr[4];
    #pragma unroll
    for (int mi = 0; mi < 4; mi++)
      af[mi] = *(const bf16x8*)(As + (waveM*64 + mi*16 + cl)*32 + quad*8);
    #pragma unroll
    for (int nj = 0; nj < 4; nj++)
      bfr[nj] = *(const bf16x8*)(Bs + (waveN*64 + nj*16 + cl)*32 + quad*8);
    #pragma unroll
    for (int mi = 0; mi < 4; mi++)
      #pragma unroll
      for (int nj = 0; nj < 4; nj++)
        accr[mi][nj] = __builtin_amdgcn_mfma_f32_16x16x32_bf16(af[mi], bfr[nj], accr[mi][nj], 0,0,0);
  }
  #pragma unroll
  for (int mi = 0; mi < 4; mi++){
    #pragma unroll
    for (int r = 0; r < 4; r++){
      int tok = rowBase + waveM*64 + mi*16 + quad*4 + r;
      int bn = tok / T_; int t = tok - bn*T_;
      int b = bn / N_;  int n = bn - b*N_;
      size_t base = ((size_t)(b*T_ + t)*H_)*SLAB + n*16 + cl;
      #pragma unroll
      for (int nj = 0; nj < 4; nj++){
        int col = colBase + waveN*64 + nj*16;
        int part = col >> 7, hh = (col >> 4) & 7;
        bf16* dst = (part == 0) ? sQ : (part == 1) ? sK : sV;
        dst[base + (size_t)hh*SLAB] = f2b(accr[mi][nj][r]);
      }
    }
  }
}

// ---- MFMA GEMM + residual-acc + fused LayerNorm (N=128, grid.x=1) ----
__global__ __launch_bounds__(256) void mgemm_ln_k(const bf16* __restrict__ A,
    const bf16* __restrict__ Wt, const bf16* __restrict__ bias,
    float* __restrict__ hout, int Ktot,
    const bf16* __restrict__ g, const bf16* __restrict__ bta,
    bf16* __restrict__ xnb){
  __shared__ __align__(16) bf16 As[128*32];
  __shared__ __align__(16) bf16 Bs[128*32];
  __shared__ float red[2][128][2];
  int tid = threadIdx.x;
  int rowBase = blockIdx.y * 128;
  int w = tid >> 6, lane = tid & 63, quad = lane >> 4, cl = lane & 15;
  int waveM = w >> 1, waveN = w & 1;
  f32x4 accr[4][4];
  #pragma unroll
  for (int i = 0; i < 4; i++)
    #pragma unroll
    for (int j = 0; j < 4; j++) accr[i][j] = (f32x4){0.f,0.f,0.f,0.f};
  int lr = tid >> 2, kc = tid & 3;
  const bf16* Ap = A  + (size_t)(rowBase + lr)*Ktot + kc*8;
  const bf16* Bp = Wt + (size_t)lr*Ktot + kc*8;
  bf16* AsW = As + tid*8;
  bf16* BsW = Bs + tid*8;
  for (int kk = 0; kk < Ktot; kk += 32){
    __syncthreads();
    gll16(Ap + kk, AsW);
    gll16(Ap + (size_t)64*Ktot + kk, AsW + 64*32);
    gll16(Bp + kk, BsW);
    gll16(Bp + (size_t)64*Ktot + kk, BsW + 64*32);
    __syncthreads();
    bf16x8 af[4], bfr[4];
    #pragma unroll
    for (int mi = 0; mi < 4; mi++)
      af[mi] = *(const bf16x8*)(As + (waveM*64 + mi*16 + cl)*32 + quad*8);
    #pragma unroll
    for (int nj = 0; nj < 4; nj++)
      bfr[nj] = *(const bf16x8*)(Bs + (waveN*64 + nj*16 + cl)*32 + quad*8);
    #pragma unroll
    for (int mi = 0; mi < 4; mi++)
      #pragma unroll
      for (int nj = 0; nj < 4; nj++)
        accr[mi][nj] = __builtin_amdgcn_mfma_f32_16x16x32_bf16(af[mi], bfr[nj], accr[mi][nj], 0,0,0);
  }
  int colW = waveN*64;
  float bv[4];
  #pragma unroll
  for (int nj = 0; nj < 4; nj++)
    bv[nj] = bias ? b2f(bias[colW + nj*16 + cl]) : 0.0f;
  float hv[4][4][4];
  float psum[4][4], psq[4][4];
  #pragma unroll
  for (int mi = 0; mi < 4; mi++)
    #pragma unroll
    for (int r = 0; r < 4; r++){ psum[mi][r] = 0.f; psq[mi][r] = 0.f; }
  #pragma unroll
  for (int mi = 0; mi < 4; mi++){
    #pragma unroll
    for (int r = 0; r < 4; r++){
      int row = rowBase + waveM*64 + mi*16 + quad*4 + r;
      #pragma unroll
      for (int nj = 0; nj < 4; nj++){
        int col = colW + nj*16 + cl;
        size_t idx = (size_t)row*D_ + col;
        float v = hout[idx] + accr[mi][nj][r] + bv[nj];
        hout[idx] = v;
        hv[mi][nj][r] = v;
        psum[mi][r] += v; psq[mi][r] += v*v;
      }
    }
  }
  if (g){
    #pragma unroll
    for (int off = 1; off <= 8; off <<= 1)
      #pragma unroll
      for (int mi = 0; mi < 4; mi++)
        #pragma unroll
        for (int r = 0; r < 4; r++){
          psum[mi][r] += __shfl_xor(psum[mi][r], off, 64);
          psq[mi][r]  += __shfl_xor(psq[mi][r],  off, 64);
        }
    if (cl == 0){
      #pragma unroll
      for (int mi = 0; mi < 4; mi++)
        #pragma unroll
        for (int r = 0; r < 4; r++){
          int rl = waveM*64 + mi*16 + quad*4 + r;
          red[waveN][rl][0] = psum[mi][r];
          red[waveN][rl][1] = psq[mi][r];
        }
    }
    __syncthreads();
    float gv[4], btv[4];
    #pragma unroll
    for (int nj = 0; nj < 4; nj++){
      int col = colW + nj*16 + cl;
      gv[nj] = b2f(g[col]); btv[nj] = b2f(bta[col]);
    }
    #pragma unroll
    for (int mi = 0; mi < 4; mi++){
      #pragma unroll
      for (int r = 0; r < 4; r++){
        int rl = waveM*64 + mi*16 + quad*4 + r;
        float s = red[0][rl][0] + red[1][rl][0];
        float q = red[0][rl][1] + red[1][rl][1];
        float mean = s*(1.0f/128.0f);
        float var  = q*(1.0f/128.0f) - mean*mean;
        float rstd = rsqrtf(var + 1e-5f);
        int row = rowBase + rl;
        #pragma unroll
        for (int nj = 0; nj < 4; nj++){
          int col = colW + nj*16 + cl;
          xnb[(size_t)row*D_ + col] = f2b((hv[mi][nj][r]-mean)*rstd*gv[nj] + btv[nj]);
        }
      }
    }
  }
}

// ---- fused FFN: h += relu(xn@W1+b1)@W2 + b2; xnb = LN(h) ----
__global__ __launch_bounds__(256,2) void mffn_ln_k(const bf16* __restrict__ A,
    const bf16* __restrict__ W1t, const bf16* __restrict__ b1,
    const bf16* __restrict__ W2t, const bf16* __restrict__ b2,
    float* __restrict__ hout,
    const bf16* __restrict__ g, const bf16* __restrict__ bta,
    bf16* __restrict__ xnb){
  __shared__ __align__(16) bf16 As[128*136];
  __shared__ __align__(16) bf16 Hs[128*136];
  __shared__ __align__(16) bf16 Bs[128*32];
  __shared__ float red[2][128][2];
  int tid = threadIdx.x;
  int rowBase = blockIdx.x * 128;
  int w = tid >> 6, lane = tid & 63, quad = lane >> 4, cl = lane & 15;
  int waveM = w >> 1, waveN = w & 1;
  for (int i = tid; i < 128*16; i += 256){
    int row = i >> 4, ch = i & 15;
    u32x4 v = *(const u32x4*)(A + (size_t)(rowBase + row)*128 + ch*8);
    *(u32x4*)(As + row*136 + ch*8) = v;
  }
  f32x4 acc2[4][4];
  #pragma unroll
  for (int i = 0; i < 4; i++)
    #pragma unroll
    for (int j = 0; j < 4; j++) acc2[i][j] = (f32x4){0.f,0.f,0.f,0.f};
  int lr = tid >> 2, kc = tid & 3;
  bf16* BsW = Bs + tid*8;
  int aRow0 = waveM*64;
  for (int kt = 0; kt < 4; kt++){
    f32x4 acc1[4][4];
    #pragma unroll
    for (int i = 0; i < 4; i++)
      #pragma unroll
      for (int j = 0; j < 4; j++) acc1[i][j] = (f32x4){0.f,0.f,0.f,0.f};
    for (int ks = 0; ks < 4; ks++){
      __syncthreads();
      gll16(W1t + (size_t)(kt*128 + lr)*128 + ks*32 + kc*8, BsW);
      gll16(W1t + (size_t)(kt*128 + 64 + lr)*128 + ks*32 + kc*8, BsW + 64*32);
      __syncthreads();
      bf16x8 af[4], bfr[4];
      #pragma unroll
      for (int mi = 0; mi < 4; mi++)
        af[mi] = *(const bf16x8*)(As + (aRow0 + mi*16 + cl)*136 + ks*32 + quad*8);
      #pragma unroll
      for (int nj = 0; nj < 4; nj++)
        bfr[nj] = *(const bf16x8*)(Bs + (waveN*64 + nj*16 + cl)*32 + quad*8);
      #pragma unroll
      for (int mi = 0; mi < 4; mi++)
        #pragma unroll
        for (int nj = 0; nj < 4; nj++)
          acc1[mi][nj] = __builtin_amdgcn_mfma_f32_16x16x32_bf16(af[mi], bfr[nj], acc1[mi][nj], 0,0,0);
    }
    float b1v[4];
    #pragma unroll
    for (int nj = 0; nj < 4; nj++)
      b1v[nj] = b2f(b1[kt*128 + waveN*64 + nj*16 + cl]);
    #pragma unroll
    for (int mi = 0; mi < 4; mi++){
      #pragma unroll
      for (int r = 0; r < 4; r++){
        int row = aRow0 + mi*16 + quad*4 + r;
        #pragma unroll
        for (int nj = 0; nj < 4; nj++){
          int col = waveN*64 + nj*16 + cl;
          Hs[row*136 + col] = f2b(fmaxf(acc1[mi][nj][r] + b1v[nj], 0.0f));
        }
      }
    }
    for (int ks = 0; ks < 4; ks++){
      __syncthreads();
      gll16(W2t + (size_t)lr*512 + kt*128 + ks*32 + kc*8, BsW);
      gll16(W2t + (size_t)(64 + lr)*512 + kt*128 + ks*32 + kc*8, BsW + 64*32);
      __syncthreads();
      bf16x8 af[4], bfr[4];
      #pragma unroll
      for (int mi = 0; mi < 4; mi++)
        af[mi] = *(const bf16x8*)(Hs + (aRow0 + mi*16 + cl)*136 + ks*32 + quad*8);
      #pragma unroll
      for (int nj = 0; nj < 4; nj++)
        bfr[nj] = *(const bf16x8*)(Bs + (waveN*64 + nj*16 + cl)*32 + quad*8);
      #pragma unroll
      for (int mi = 0; mi < 4; mi++)
        #pragma unroll
        for (int nj = 0; nj < 4; nj++)
          acc2[mi][nj] = __builtin_amdgcn_mfma_f32_16x16x32_bf16(af[mi], bfr[nj], acc2[mi][nj], 0,0,0);
    }
    __syncthreads();
  }
  int colW = waveN*64;
  float bv[4];
  #pragma unroll
  for (int nj = 0; nj < 4; nj++)
    bv[nj] = b2f(b2[colW + nj*16 + cl]);
  float hv[4][4][4];
  float psum[4][4], psq[4][4];
  #pragma unroll
  for (int mi = 0; mi < 4; mi++)
    #pragma unroll
    for (int r = 0; r < 4; r++){ psum[mi][r] = 0.f; psq[mi][r] = 0.f; }
  #pragma unroll
  for (int mi = 0; mi < 4; mi++){
    #pragma unroll
    for (int r = 0; r < 4; r++){
      int row = rowBase + aRow0 + mi*16 + quad*4 + r;
      #pragma unroll
      for (int nj = 0; nj < 4; nj++){
        int col = colW + nj*16 + cl;
        size_t idx = (size_t)row*D_ + col;
        float v = hout[idx] + acc2[mi][nj][r] + bv[nj];
        hout[idx] = v;
        hv[mi][nj][r] = v;
        psum[mi][r] += v; psq[mi][r] += v*v;
      }
    }
  }
  if (g){
    #pragma unroll
    for (int off = 1; off <= 8; off <<= 1)
      #pragma unroll
      for (int mi = 0; mi < 4; mi++)
        #pragma unroll
        for (int r = 0; r < 4; r++){
          psum[mi][r] += __shfl_xor(psum[mi][r], off, 64);
          psq[mi][r]  += __shfl_xor(psq[mi][r],  off, 64);
        }
    if (cl == 0){
      #pragma unroll
      for (int mi = 0; mi < 4; mi++)
        #pragma unroll
        for (int r = 0; r < 4; r++){
          int rl = aRow0 + mi*16 + quad*4 + r;
          red[waveN][rl][0] = psum[mi][r];
          red[waveN][rl][1] = psq[mi][r];
        }
    }
    __syncthreads();
    float gv[4], btv[4];
    #pragma unroll
    for (int nj = 0; nj < 4; nj++){
      int col = colW + nj*16 + cl;
      gv[nj] = b2f(g[col]); btv[nj] = b2f(bta[col]);
    }
    #pragma unroll
    for (int mi = 0; mi < 4; mi++){
      #pragma unroll
      for (int r = 0; r < 4; r++){
        int rl = aRow0 + mi*16 + quad*4 + r;
        float s = red[0][rl][0] + red[1][rl][0];
        float q = red[0][rl][1] + red[1][rl][1];
        float mean = s*(1.0f/128.0f);
        float var  = q*(1.0f/128.0f) - mean*mean;
        float rstd = rsqrtf(var + 1e-5f);
        int row = rowBase + rl;
        #pragma unroll
        for (int nj = 0; nj < 4; nj++){
          int col = colW + nj*16 + cl;
          xnb[(size_t)row*D_ + col] = f2b((hv[mi][nj][r]-mean)*rstd*gv[nj] + btv[nj]);
        }
      }
    }
  }
}

// ---- MFMA spatial attention v4: K from global (L1-resident), MFMA row-sum ----
// (no shuffles), exp2 softmax (log2e folded into Wq/mask). LDS 37KB -> 4 blocks/CU.
__global__ __launch_bounds__(256,4) void sattn_k(const bf16* __restrict__ sQ,
    const bf16* __restrict__ sK, const bf16* __restrict__ sV,
    const float* __restrict__ maskg, bf16* __restrict__ ob){
  __shared__ __align__(16) _Float16 Vt[16*KVH];     // 7424 B
  __shared__ __align__(16) _Float16 Ps[4*16*KVH];   // 29696 B
  int tid = threadIdx.x;
  int bid = blockIdx.x;                // slab = (b*T+t)*H + hh
  int hh = bid & 7; int bt = bid >> 3; int t = bt % T_; int b = bt / T_;
  const bf16* Kslab = sK + (size_t)bid*SLAB;
  const bf16* Vslab = sV + (size_t)bid*SLAB;
  const bf16* Qslab = sQ + (size_t)bid*SLAB;
  // zero pad columns (read but never written)
  for (int i = tid; i < 16*25; i += 256){ int d = i/25, c = 207 + i%25; Vt[d*KVH + c] = (_Float16)0.0f; }
  for (int i = tid; i < 64*24; i += 256){ int row = i/24, c = 208 + i%24; Ps[row*KVH + c] = (_Float16)0.0f; }
  // stage V transposed to [d][n] fp16
  for (int i = tid; i < SLAB; i += 256){
    int n = i >> 4, d = i & 15;
    Vt[d*KVH + n] = (_Float16)b2f(Vslab[i]);
  }
  __syncthreads();

  int lane = tid & 63, w = tid >> 6, quad = lane >> 4, cl = lane & 15;
  f16x8 ones8;
  #pragma unroll
  for (int j = 0; j < 8; j++) ones8[j] = (_Float16)1.0f;
  int nstripes = (w == 0) ? 4 : 3;
  for (int si = 0; si < nstripes; si++){
    int mi = w + si*4;          // 0..12
    // Q fragment from global (pre-scaled by SCALE*log2e via Wq)
    bf16x8 aq = (bf16x8){0,0,0,0,0,0,0,0};
    {
      int n = mi*16 + cl; if (n > N_-1) n = N_-1;   // clamp pad row (never stored)
      if (quad < 2) aq = *(const bf16x8*)(Qslab + n*16 + quad*8);
    }
    // QK^T with additive mask (log2 domain) as the MFMA C operand.
    // K read directly from global: 6.6KB slab is L1-resident after first pass.
    const float* mrow = maskg + ((size_t)mi*13)*256 + lane*4;
    f32x4 s[13];
    #pragma unroll
    for (int nj = 0; nj < 13; nj++){
      bf16x8 bk = (bf16x8){0,0,0,0,0,0,0,0};
      if (quad < 2){
        int nb = nj*16 + cl; if (nb > N_-1) nb = N_-1;  // clamped col masked by -1e30
        bk = *(const bf16x8*)(Kslab + nb*16 + quad*8);
      }
      f32x4 c0 = *(const f32x4*)(mrow + nj*256);
      s[nj] = __builtin_amdgcn_mfma_f32_16x16x32_bf16(aq, bk, c0, 0,0,0);
    }
    // softmax numerator only (scores tiny -> no max subtraction); no shuffles.
    int row0 = mi*16 + quad*4;
    _Float16* Pw = Ps + w*16*KVH;
    #pragma unroll
    for (int r = 0; r < 4; r++){
      _Float16* Pr = Pw + (quad*4 + r)*KVH;
      #pragma unroll
      for (int nj = 0; nj < 13; nj++)
        Pr[nj*16 + cl] = (_Float16)exp2f(s[nj][r]);
    }
    __threadfence_block();   // order P writes before same-wave PV reads
    // PV + MFMA row-sum (B = ones): osum[r] = row sum replicated across cols
    f32x4 o = {0.f,0.f,0.f,0.f};
    f32x4 osum = {0.f,0.f,0.f,0.f};
    #pragma unroll
    for (int kt = 0; kt < 7; kt++){
      f16x8 ap = *(const f16x8*)(Pw + cl*KVH + kt*32 + quad*8);
      f16x8 bv = *(const f16x8*)(Vt + cl*KVH + kt*32 + quad*8);
      o    = __builtin_amdgcn_mfma_f32_16x16x32_f16(ap, bv,    o,    0,0,0);
      osum = __builtin_amdgcn_mfma_f32_16x16x32_f16(ap, ones8, osum, 0,0,0);
    }
    #pragma unroll
    for (int r = 0; r < 4; r++){
      int rg = row0 + r;
      if (rg < N_)
        ob[((size_t)((b*N_ + rg)*T_ + t))*D_ + hh*HD_ + cl] = f2b(o[r]/osum[r]);
    }
    __threadfence_block();   // order PV reads before next stripe's P writes
  }
}

// ---- temporal attention ----
__global__ void tattn_k(const bf16* qkv, bf16* ob){
  int bid = blockIdx.x; int b = bid / N_, n = bid % N_;
  __shared__ float qs[T_*D_];
  __shared__ float ks[T_*D_];
  __shared__ float vs[T_*D_];
  size_t rowb = ((size_t)(b*N_+n)*T_)*384;
  const u32* src = (const u32*)(qkv + rowb);
  for (int idx = threadIdx.x; idx < T_*192; idx += 128){
    int tt = idx / 192, cw = idx - tt*192;
    u32 pr = src[tt*192 + cw];
    union { u32 u; bf16 b[2]; } cv; cv.u = pr;
    float v0 = b2f(cv.b[0]), v1 = b2f(cv.b[1]);
    int arr = cw >> 6, cp2 = (cw & 63)*2;
    float* dst = (arr == 0) ? qs : (arr == 1) ? ks : vs;
    dst[tt*128 + cp2] = v0; dst[tt*128 + cp2 + 1] = v1;
  }
  __syncthreads();
  int p = threadIdx.x;
  if (p < H_*T_){
    int hh = p / T_, t = p - hh*T_;
    float qreg[16];
    for (int d = 0; d < 16; d++) qreg[d] = qs[t*128 + hh*16 + d];
    float sc[12]; float mx = -3.4e38f;
    for (int s = 0; s < 12; s++){
      float a = 0.0f;
      for (int d = 0; d < 16; d++) a += qreg[d]*ks[s*128 + hh*16 + d];
      a = (s <= t) ? a*SCALE_ : -3.4e38f;
      sc[s] = a; mx = fmaxf(mx, a);
    }
    float ssum = 0.0f;
    for (int s = 0; s < 12; s++){
      float e = (s <= t) ? __expf(sc[s]-mx) : 0.0f;
      sc[s] = e; ssum += e;
    }
    float inv = 1.0f/ssum;
    size_t obase = ((size_t)(b*N_+n)*T_ + t)*D_ + hh*16;
    for (int d = 0; d < 16; d++){
      float acc = 0.0f;
      for (int s = 0; s < 12; s++) acc += sc[s]*vs[s*128 + hh*16 + d];
      ob[obase + d] = f2b(acc*inv);
    }
  }
}

// ---- VALU GEMM for small head GEMMs ----
__global__ void gemm_k(const bf16* A, int lda, const bf16* W, const bf16* bias,
                       void* outp, int ldo, int M, int Ncols, int K, int relu, int acc){
  __shared__ float Ast[16*68];
  __shared__ float Ws [16*68];
  int tx = threadIdx.x & 15, ty = threadIdx.x >> 4;
  int rowBase = blockIdx.y * 64, colBase = blockIdx.x * 64;
  float accr[4][4];
  for (int i = 0; i < 4; i++) for (int j = 0; j < 4; j++) accr[i][j] = 0.0f;
  for (int kk = 0; kk < K; kk += 16){
    int kq = threadIdx.x & 15, r0 = threadIdx.x >> 4;
    for (int it = 0; it < 4; it++){
      int r = r0 + it*16, row = rowBase + r;
      float v = 0.0f;
      if (row < M) v = b2f(A[(size_t)row*lda + kk + kq]);
      Ast[kq*68 + r] = v;
    }
    int c = threadIdx.x & 63, w0 = threadIdx.x >> 6;
    for (int it = 0; it < 4; it++){
      int kr = w0 + it*4;
      Ws[kr*68 + c] = b2f(W[(size_t)(kk+kr)*Ncols + colBase + c]);
    }
    __syncthreads();
    for (int k = 0; k < 16; k++){
      float av[4], wv[4];
      for (int i = 0; i < 4; i++) av[i] = Ast[k*68 + ty*4 + i];
      for (int j = 0; j < 4; j++) wv[j] = Ws[k*68 + tx*4 + j];
      for (int i = 0; i < 4; i++)
        for (int j = 0; j < 4; j++) accr[i][j] += av[i]*wv[j];
    }
    __syncthreads();
  }
  for (int i = 0; i < 4; i++){
    int row = rowBase + ty*4 + i;
    if (row >= M) continue;
    for (int j = 0; j < 4; j++){
      int col = colBase + tx*4 + j;
      float v = accr[i][j];
      if (bias) v += b2f(bias[col]);
      if (relu) v = fmaxf(v, 0.0f);
      if (acc) ((float*)outp)[(size_t)row*ldo + col] += v;
      else     ((bf16*)outp)[(size_t)row*ldo + col] = f2b(v);
    }
  }
}

__global__ void gather_k(const float* h, bf16* hlb){
  int i = blockIdx.x*256 + threadIdx.x;
  if (i >= ROWS2*D_) return;
  int r = i >> 7, d = i & 127;
  hlb[i] = f2b(h[((size_t)r*T_ + (T_-1))*D_ + d]);
}

__global__ void head3_k(const bf16* z2, const bf16* P3, const bf16* Pb3,
                        void* out, int out_n, const int* flag){
  int i = blockIdx.x*256 + threadIdx.x;
  if (i >= out_n) return;
  int r = i / PL_, j = i - r*PL_;
  float acc = b2f(Pb3[j]);
  for (int d = 0; d < 128; d++) acc += b2f(z2[(size_t)r*128 + d]) * b2f(P3[d*PL_ + j]);
  if (*flag) ((bf16*)out)[i] = f2b(acc);
  else       ((float*)out)[i] = acc;
}

extern "C" void kernel_launch(void* const* d_in, const int* in_sizes, int n_in,
                              void* d_out, int out_size, void* d_ws, size_t ws_size,
                              hipStream_t stream){
  size_t HB = (size_t)TOK*D_*4;
  size_t XB = (size_t)TOK*D_*2;
  size_t RB = (size_t)TOK*D_*8;
  float* h    = (float*)d_ws;
  bf16*  xnb  = (bf16*)((char*)d_ws + HB);
  bf16*  reg_ = (bf16*)((char*)d_ws + HB + XB);
  bf16*  cvt  = (bf16*)((char*)d_ws + HB + XB + RB);
  bf16*  wsb  = (bf16*)d_ws;
  const int FIDX[34] = {0,2,3,4,5,6,7,8,9,10,11,12,13,14,15,16,17,18,19,20,
                        21,22,23,24,25,26,27,28,29,30,31,32,33,34};
  bf16* cp[34];
  size_t off = 0;
  for (int i = 0; i < 34; i++){ cp[i] = cvt + off; off += (size_t)in_sizes[FIDX[i]]; }
  char* tail   = (char*)d_ws + HB + XB + RB + ((off*2 + 255) & ~(size_t)255);
  float* maskg = (float*)tail;
  bf16* qkvw   = (bf16*)(tail + (size_t)MSK_N*4);
  int*  flag   = (int*)(tail + (size_t)MSK_N*4 + (size_t)L_*384*128*2);

  const bf16 *x_c=cp[0], *Wi_c=cp[1], *bi_c=cp[2],
             *Wo_t=cp[6], *bo_c=cp[7], *sW1_t=cp[8], *sB1_c=cp[9], *sW2_t=cp[10], *sB2_c=cp[11],
             *sg1_c=cp[12], *sh1_c=cp[13], *sg2_c=cp[14], *sh2_c=cp[15], *Win_t=cp[16], *Bin_c=cp[17],
             *Wout_t=cp[18], *Bout_c=cp[19], *tW1_t=cp[20], *tB1_c=cp[21], *tW2_t=cp[22], *tB2_c=cp[23],
             *tg1_c=cp[24], *th1_c=cp[25], *tg2_c=cp[26], *th2_c=cp[27], *P1_c=cp[28], *Pb1_c=cp[29],
             *P2_c=cp[30], *Pb2_c=cp[31], *P3_c=cp[32], *Pb3_c=cp[33];
  const int* adj = (const int*)d_in[1];

  bf16* sQ   = reg_;
  bf16* sK   = reg_ + (size_t)TOK*128;
  bf16* sV   = reg_ + (size_t)2*TOK*128;
  bf16* ob   = reg_ + (size_t)3*TOK*128;
  bf16* qkvb = reg_;

  detect_k<<<1, 256, 0, stream>>>(d_in[0], flag);

  {
    const int FLAT[24] = {0,1,2,7,9,11,12,13,14,15,17,19,21,23,24,25,26,27,28,29,30,31,32,33};
    FlatArgs fa; int c = 0;
    for (int ii = 0; ii < 24; ii++){
      int ci = FLAT[ii];
      fa.src[ii] = d_in[FIDX[ci]];
      fa.dst[ii] = (long long)(cp[ci] - wsb);
      fa.cum[ii] = c;
      c += in_sizes[FIDX[ci]];
    }
    fa.cum[24] = c;
    cvt_flat_k<<<(c+255)/256, 256, 0, stream>>>(fa, wsb, flag, c);
  }
  {
    TArgs ta; int c = 0;
    const void* srcs[10] = {d_in[4], d_in[5], d_in[6], d_in[7], d_in[9], d_in[11],
                            d_in[17], d_in[19], d_in[21], d_in[23]};
    bf16* dsts[10] = {qkvw, qkvw, qkvw, cp[6], cp[8], cp[10], cp[16], cp[18], cp[20], cp[22]};
    int Ks_[10]   = {128,128,128, 128, 128, 512, 128, 128, 128, 512};
    int Ncs[10]   = {128,128,128, 128, 512, 128, 384, 128, 512, 128};
    int Lst[10]   = {384*128,384*128,384*128, 128*128, 128*512, 512*128, 128*384, 128*128, 128*512, 512*128};
    int ros[10]   = {0,128,256, 0,0,0, 0,0,0, 0};
    for (int j = 0; j < 10; j++){
      ta.src[j] = srcs[j];
      ta.dst[j] = (long long)(dsts[j] - wsb);
      ta.K[j] = Ks_[j]; ta.Nc[j] = Ncs[j]; ta.Lstr[j] = Lst[j]; ta.ro[j] = ros[j];
      ta.scale[j] = (j == 0) ? SCALE_*LOG2E_ : 1.0f;   // fold softmax log2e into Wq
      ta.cum[j] = c;
      c += L_*Ks_[j]*Ncs[j];
    }
    ta.cum[10] = c;
    cvt_t_k<<<(c+255)/256, 256, 0, stream>>>(ta, wsb, flag, c);
  }
  maskc_k<<<(MSK_N+255)/256, 256, 0, stream>>>(adj, maskg);
  embed_ln_k<<<TOK/4, 256, 0, stream>>>(x_c, Wi_c, bi_c, sg1_c, sh1_c, h, xnb);

  const dim3 gP  (1, TOK/128);
  const dim3 gQKV(3, TOK/128);

  for (int l = 0; l < L_; l++){
    // spatial attention
    mgemm_qkvT_k<<<gQKV, 256, 0, stream>>>(xnb, qkvw + (size_t)l*384*128, sQ, sK, sV);
    sattn_k<<<B_*T_*H_, 256, 0, stream>>>(sQ, sK, sV, maskg, ob);
    mgemm_ln_k<<<gP, 256, 0, stream>>>(ob, Wo_t + (size_t)l*D_*D_, bo_c + l*D_, h, D_,
                                       sg2_c + l*D_, sh2_c + l*D_, xnb);
    // fused FFN 1 (-> LN tg1)
    mffn_ln_k<<<TOK/128, 256, 0, stream>>>(xnb, sW1_t + (size_t)l*D_*FF_, sB1_c + l*FF_,
                                           sW2_t + (size_t)l*FF_*D_, sB2_c + l*D_, h,
                                           tg1_c + l*D_, th1_c + l*D_, xnb);
    // temporal attention
    mgemm_k<<<gQKV, 256, 0, stream>>>(xnb, Win_t + (size_t)l*D_*384, Bin_c + l*384, qkvb, 384, D_, 0);
    tattn_k<<<B_*N_, 128, 0, stream>>>(qkvb, ob);
    mgemm_ln_k<<<gP, 256, 0, stream>>>(ob, Wout_t + (size_t)l*D_*D_, Bout_c + l*D_, h, D_,
                                       tg2_c + l*D_, th2_c + l*D_, xnb);
    // fused FFN 2 (-> LN next sg1 or none)
    const bf16* gnext = (l < L_-1) ? (sg1_c + (l+1)*D_) : nullptr;
    const bf16* bnext = (l < L_-1) ? (sh1_c + (l+1)*D_) : nullptr;
    mffn_ln_k<<<TOK/128, 256, 0, stream>>>(xnb, tW1_t + (size_t)l*D_*FF_, tB1_c + l*FF_,
                                           tW2_t + (size_t)l*FF_*D_, tB2_c + l*D_, h,
                                           gnext, bnext, xnb);
  }

  // head
  bf16* hlb = reg_;
  bf16* z1  = reg_ + (size_t)ROWS2*128;
  bf16* z2  = z1   + (size_t)ROWS2*256;
  gather_k<<<(ROWS2*D_)/256, 256, 0, stream>>>(h, hlb);
  gemm_k<<<dim3(256/64, (ROWS2+63)/64), 256, 0, stream>>>(hlb, 128, P1_c, Pb1_c, z1, 256, ROWS2, 256, 128, 1, 0);
  gemm_k<<<dim3(128/64, (ROWS2+63)/64), 256, 0, stream>>>(z1, 256, P2_c, Pb2_c, z2, 128, ROWS2, 128, 256, 1, 0);
  head3_k<<<(out_size+255)/256, 256, 0, stream>>>(z2, P3_c, Pb3_c, d_out, out_size, flag);
}